// Round 5
// baseline (810.706 us; speedup 1.0000x reference)
//
#include <hip/hip_runtime.h>
#include <hip/hip_bf16.h>
#include <stdint.h>

#define NPTS 50000
#define NPAD 50048   // 391 * 128 row tiles

typedef unsigned short u16;
typedef __attribute__((ext_vector_type(8))) __bf16 bf16x8;
typedef __attribute__((ext_vector_type(4))) float f32x4;

__device__ __forceinline__ float bf2f(__hip_bfloat16 v) { return __bfloat162float(v); }
__device__ __forceinline__ __hip_bfloat16 f2bf(float v) { return __float2bfloat16(v); }
__device__ __forceinline__ int clampi(int v) { return v < 0 ? 0 : (v >= NPTS ? NPTS - 1 : v); }

__device__ __forceinline__ unsigned enc_f32(float f) {
    unsigned b = __float_as_uint(f);
    return (b & 0x80000000u) ? ~b : (b | 0x80000000u);
}
__device__ __forceinline__ float dec_f32(unsigned u) {
    return (u & 0x80000000u) ? __uint_as_float(u & 0x7fffffffu) : __uint_as_float(~u);
}

__device__ __forceinline__ void gload_lds16(const void* g, void* l) {
    __builtin_amdgcn_global_load_lds((__attribute__((address_space(1))) void*)g,
                                     (__attribute__((address_space(3))) void*)l, 16, 0, 0);
}

// ---------------------------------------------------------------------------
// prep: zero-pad W_c1 (256x195)->fp32, W_a1 (256x131)->fp32; g_enc=-inf
// ---------------------------------------------------------------------------
__global__ __launch_bounds__(256) void prep(
    const float* __restrict__ W_c1, const float* __restrict__ W_a1,
    float* __restrict__ Wc1p, float* __restrict__ Wa1pf,
    unsigned* __restrict__ g_enc)
{
    int i = blockIdx.x * 256 + threadIdx.x;
    if (i < 65536) {
        int o = i >> 8, k = i & 255;
        Wc1p[i] = (k < 195) ? W_c1[o * 195 + k] : 0.f;
    } else if (i < 131072) {
        int t = i - 65536;
        int o = t >> 8, k = t & 255;
        Wa1pf[t] = (k < 131) ? W_a1[o * 131 + k] : 0.f;
    } else if (i < 132096) {
        g_enc[i - 131072] = 0x007FFFFFu;   // enc(-inf)
    }
}

// ---------------------------------------------------------------------------
// wgemm (fp32): C[i][j] = sum_k A[i*lda+k]*B[k*ldb+j] (+ D). 32x32 tiles.
// ---------------------------------------------------------------------------
__global__ __launch_bounds__(256) void wgemm(
    const float* __restrict__ A, int lda,
    const float* __restrict__ B, int ldb,
    const float* __restrict__ D, int ldd,
    float* __restrict__ Cf, __hip_bfloat16* __restrict__ Cb, int ldc,
    int K)
{
    __shared__ float sA[32][33], sB[32][33];
    const int bj = blockIdx.x, bi = blockIdx.y;
    const int t = threadIdx.x, tx = t & 31, ty = t >> 5;
    float acc[4] = {0.f, 0.f, 0.f, 0.f};
    for (int k0 = 0; k0 < K; k0 += 32) {
#pragma unroll
        for (int q = 0; q < 4; ++q) {
            int idx = q * 256 + t, r = idx >> 5, c = idx & 31;
            sA[r][c] = A[(long)(bi * 32 + r) * lda + k0 + c];
            sB[r][c] = B[(long)(k0 + r) * ldb + bj * 32 + c];
        }
        __syncthreads();
#pragma unroll 8
        for (int c = 0; c < 32; ++c) {
            float bv = sB[c][tx];
#pragma unroll
            for (int q = 0; q < 4; ++q) acc[q] += sA[ty + q * 8][c] * bv;
        }
        __syncthreads();
    }
#pragma unroll
    for (int q = 0; q < 4; ++q) {
        int r = bi * 32 + ty + q * 8, cidx = bj * 32 + tx;
        float v = acc[q];
        if (D)  v += D[(long)r * ldd + cidx];
        if (Cf) Cf[(long)r * ldc + cidx] = v;
        if (Cb) Cb[(long)r * ldc + cidx] = f2bf(v);
    }
}

// fp32 -> bf16 strided copy (rows x cols)
__global__ __launch_bounds__(256) void convcopy(
    const float* __restrict__ src, int lds, __hip_bfloat16* __restrict__ dst, int ldd,
    int rows, int cols)
{
    int i = blockIdx.x * 256 + threadIdx.x;
    if (i >= rows * cols) return;
    int r = i / cols, c = i % cols;
    dst[(long)r * ldd + c] = f2bf(src[(long)r * lds + c]);
}

// b_a1p[o] = b_a1[o] + sum_{h<64} Wa1pf[o][h] * b_fr4[h]
__global__ __launch_bounds__(256) void biasfold(
    const float* __restrict__ b_a1, const float* __restrict__ Wa1pf,
    const float* __restrict__ b_fr4, float* __restrict__ b_a1p)
{
    int o = threadIdx.x;
    float s = b_a1[o];
    for (int h = 0; h < 64; ++h) s += Wa1pf[o * 256 + h] * b_fr4[h];
    b_a1p[o] = s;
}

// cvec[i] = b_f@M3^T + b_c2@T3^T + b_a2@T4^T + b_c1@U1^T + b_a1@U2^T
//         + b_sp1@X1[:,0:64]^T + b_fr4@X1[:,64:128]^T + b_fr4@X2[:,0:64]^T
__global__ __launch_bounds__(256) void cvec_kernel(
    const float* __restrict__ W_m2,
    const float* __restrict__ T3f, const float* __restrict__ T4f,
    const float* __restrict__ U1f, const float* __restrict__ U2f,
    const float* __restrict__ X1f, const float* __restrict__ X2f,
    const float* __restrict__ b_f, const float* __restrict__ b_c2,
    const float* __restrict__ b_a2, const float* __restrict__ b_c1,
    const float* __restrict__ b_a1, const float* __restrict__ b_sp1,
    const float* __restrict__ b_fr4,
    float* __restrict__ cvec)
{
    int i = blockIdx.x * 256 + threadIdx.x;
    if (i >= 1024) return;
    float s = 0.f;
    for (int k = 0; k < 1024; ++k) s += b_f[k] * W_m2[(long)i * 1792 + 768 + k];
    for (int k = 0; k < 512;  ++k) s += b_c2[k] * T3f[i * 512 + k];
    for (int k = 0; k < 512;  ++k) s += b_a2[k] * T4f[i * 512 + k];
    for (int k = 0; k < 256;  ++k) s += b_c1[k] * U1f[i * 256 + k];
    for (int k = 0; k < 256;  ++k) s += b_a1[k] * U2f[i * 256 + k];
    for (int k = 0; k < 64;   ++k) s += b_sp1[k] * X1f[i * 256 + k];
    for (int k = 0; k < 64;   ++k) s += b_fr4[k] * X1f[i * 256 + 64 + k];
    for (int k = 0; k < 64;   ++k) s += b_fr4[k] * X2f[i * 256 + k];
    cvec[i] = s;
}

// ---------------------------------------------------------------------------
// featurize (light): cat1 row = [h1r | h3r | kc | nrm | 0]; Wsp1/Wfr4 deferred
// into the weight-fold. One wave per point, no __syncthreads in the loop.
// ---------------------------------------------------------------------------
__global__ __launch_bounds__(256) void featurize(
    const float* __restrict__ centre, const float* __restrict__ corner,
    const float* __restrict__ normal, const int* __restrict__ neighbour,
    const float* __restrict__ W_sp2, const float* __restrict__ b_sp2,
    const float* __restrict__ conv_w, const float* __restrict__ conv_b,
    const float* __restrict__ W_fr3, const float* __restrict__ b_fr3,
    const float* __restrict__ theta, const float* __restrict__ phi,
    __hip_bfloat16* __restrict__ cat1)
{
    __shared__ float sWsp2t[3][64];  __shared__ float sbsp2[64];
    __shared__ float sconvt[6][32];  __shared__ float sconvb[32];
    __shared__ float sWfr3t[32][64]; __shared__ float sbfr3[64];
    __shared__ float kt4x[4][64], kt4y[4][64], kt4z[4][64];  // [s][j]: conflict-free

    const int tid = threadIdx.x;
    for (int i = tid; i < 2048; i += 256) { int j = i >> 5, k = i & 31; sWfr3t[k][j] = W_fr3[i]; }
    for (int i = tid; i < 192; i += 256) { int j = i / 3, k = i % 3; sWsp2t[k][j] = W_sp2[i]; }
    for (int i = tid; i < 192; i += 256) { int o = i / 6, k = i % 6; sconvt[k][o] = conv_w[i]; }
    if (tid < 64) { sbsp2[tid] = b_sp2[tid]; sbfr3[tid] = b_fr3[tid]; }
    if (tid < 32) sconvb[tid] = conv_b[tid];
    {   // flat index j*4+s -> kt4*[s][j]
        int j = tid >> 2, s = tid & 3;
        float th = theta[tid], ph = phi[tid];
        float st = sinf(th), ct = cosf(th), sp = sinf(ph), cp = cosf(ph);
        kt4x[s][j] = st * sp; kt4y[s][j] = st * cp; kt4z[s][j] = ct;
    }
    __syncthreads();

    const int lane = tid & 63, wave = tid >> 6;
    for (long p = (long)blockIdx.x * 4 + wave; p < NPAD; p += (long)gridDim.x * 4) {
        __hip_bfloat16* row = cat1 + p * 256;
        if (p >= NPTS) {
            __hip_bfloat16 z = f2bf(0.f);
            row[lane] = z; row[64 + lane] = z; row[128 + lane] = z; row[192 + lane] = z;
            continue;
        }
        // h1r = relu(W_sp2 @ centre + b)
        float cx = centre[p * 3], cy = centre[p * 3 + 1], cz = centre[p * 3 + 2];
        float h1r = fmaxf(sbsp2[lane] + cx * sWsp2t[0][lane] + cy * sWsp2t[1][lane]
                          + cz * sWsp2t[2][lane], 0.f);
        // conv mean (32-dim), lanes < 32
        float mval = 0.f;
        if (lane < 32) {
            float c0 = corner[p*9+0], c1 = corner[p*9+1], c2 = corner[p*9+2];
            float c3 = corner[p*9+3], c4 = corner[p*9+4], c5 = corner[p*9+5];
            float c6 = corner[p*9+6], c7 = corner[p*9+7], c8 = corner[p*9+8];
            float s0 = c0 + c3 + c6, s1 = c1 + c4 + c7, s2 = c2 + c5 + c8;
            mval = sconvb[lane] + (1.f / 3.f) *
                ((sconvt[0][lane] + sconvt[3][lane]) * s0 +
                 (sconvt[1][lane] + sconvt[4][lane]) * s1 +
                 (sconvt[2][lane] + sconvt[5][lane]) * s2);
        }
        // h3r = relu(W_fr3 @ m + b), m broadcast via shfl (no LDS, no sync)
        float h3 = sbfr3[lane];
#pragma unroll 8
        for (int k = 0; k < 32; ++k) h3 += __shfl(mval, k) * sWfr3t[k][lane];
        float h3r = fmaxf(h3, 0.f);
        // kc
        int nb0 = clampi(neighbour[p * 3]), nb1 = clampi(neighbour[p * 3 + 1]), nb2 = clampi(neighbour[p * 3 + 2]);
        float nx[4], ny[4], nz[4];
        nx[0] = normal[p * 3];          ny[0] = normal[p * 3 + 1];          nz[0] = normal[p * 3 + 2];
        nx[1] = normal[(long)nb0 * 3];  ny[1] = normal[(long)nb0 * 3 + 1];  nz[1] = normal[(long)nb0 * 3 + 2];
        nx[2] = normal[(long)nb1 * 3];  ny[2] = normal[(long)nb1 * 3 + 1];  nz[2] = normal[(long)nb1 * 3 + 2];
        nx[3] = normal[(long)nb2 * 3];  ny[3] = normal[(long)nb2 * 3 + 1];  nz[3] = normal[(long)nb2 * 3 + 2];
        float kcs = 0.f;
#pragma unroll
        for (int s = 0; s < 4; ++s) {
            float kx = kt4x[s][lane], ky = kt4y[s][lane], kz = kt4z[s][lane];
#pragma unroll
            for (int t = 0; t < 4; ++t) {
                float dx = nx[t] - kx, dy = ny[t] - ky, dz = nz[t] - kz;
                kcs += __expf(-12.5f * (dx * dx + dy * dy + dz * dz));
            }
        }
        float kcv = kcs * (1.f / 16.f);
        float nrmv = (lane == 0) ? nx[0] : (lane == 1) ? ny[0] : (lane == 2) ? nz[0] : 0.f;
        row[lane] = f2bf(h1r); row[64 + lane] = f2bf(h3r);
        row[128 + lane] = f2bf(kcv); row[192 + lane] = f2bf(nrmv);
    }
}

// ---------------------------------------------------------------------------
// agg1 = 0.25*(f + 3 neighbors) over cat1 cols [64,195)  (h3r|kc|nrm)
// ---------------------------------------------------------------------------
__global__ __launch_bounds__(256) void gather_agg1(
    const __hip_bfloat16* __restrict__ cat1, const int* __restrict__ neighbour,
    __hip_bfloat16* __restrict__ agg1)
{
    long p = (long)blockIdx.x * 4 + (threadIdx.x >> 6);
    int lane = threadIdx.x & 63;
    if (p >= NPAD) return;
    __hip_bfloat16* o = agg1 + p * 256;
    if (p >= NPTS) {
        __hip_bfloat16 z = f2bf(0.f);
        o[lane] = z; o[64 + lane] = z; o[128 + lane] = z; o[192 + lane] = z;
        return;
    }
    int nb0 = clampi(neighbour[p * 3]), nb1 = clampi(neighbour[p * 3 + 1]), nb2 = clampi(neighbour[p * 3 + 2]);
    const __hip_bfloat16* r0 = cat1 + p * 256 + 64;
    const __hip_bfloat16* r1 = cat1 + (long)nb0 * 256 + 64;
    const __hip_bfloat16* r2 = cat1 + (long)nb1 * 256 + 64;
    const __hip_bfloat16* r3 = cat1 + (long)nb2 * 256 + 64;
    float a = (bf2f(r0[lane]) + bf2f(r1[lane]) + bf2f(r2[lane]) + bf2f(r3[lane])) * 0.25f;
    float b = (bf2f(r0[64 + lane]) + bf2f(r1[64 + lane]) + bf2f(r2[64 + lane]) + bf2f(r3[64 + lane])) * 0.25f;
    float c = (lane < 3) ? (bf2f(r0[128 + lane]) + bf2f(r1[128 + lane]) + bf2f(r2[128 + lane]) + bf2f(r3[128 + lane])) * 0.25f : 0.f;
    o[lane] = f2bf(a); o[64 + lane] = f2bf(b); o[128 + lane] = f2bf(c); o[192 + lane] = f2bf(0.f);
}

__global__ __launch_bounds__(256) void gather_agg2(
    const __hip_bfloat16* __restrict__ out2, const int* __restrict__ neighbour,
    __hip_bfloat16* __restrict__ agg2)
{
    long p = (long)blockIdx.x * 4 + (threadIdx.x >> 6);
    int lane = threadIdx.x & 63;
    if (p >= NPAD) return;
    __hip_bfloat16* o = agg2 + p * 256;
    if (p >= NPTS) {
        __hip_bfloat16 z = f2bf(0.f);
        o[lane] = z; o[64 + lane] = z; o[128 + lane] = z; o[192 + lane] = z;
        return;
    }
    int nb0 = clampi(neighbour[p * 3]), nb1 = clampi(neighbour[p * 3 + 1]), nb2 = clampi(neighbour[p * 3 + 2]);
    const __hip_bfloat16* r0 = out2 + p * 256;
    const __hip_bfloat16* r1 = out2 + (long)nb0 * 256;
    const __hip_bfloat16* r2 = out2 + (long)nb1 * 256;
    const __hip_bfloat16* r3 = out2 + (long)nb2 * 256;
#pragma unroll
    for (int q = 0; q < 4; ++q) {
        int c = q * 64 + lane;
        o[c] = f2bf((bf2f(r0[c]) + bf2f(r1[c]) + bf2f(r2[c]) + bf2f(r3[c])) * 0.25f);
    }
}

// ---------------------------------------------------------------------------
// 128x256-tile bf16 MFMA GEMM core, NT. A from up to 3 K-split sources.
// acc[4][8]: wave covers 64 rows x 128 cols.
// ---------------------------------------------------------------------------
__device__ __forceinline__ void gemm_core256(
    const __hip_bfloat16* A0, int lda0, int k0end,
    const __hip_bfloat16* A1, int lda1, int k1end,
    const __hip_bfloat16* A2, int lda2,
    const __hip_bfloat16* B, int K,
    u16* Asm, u16* Bsm, long rowbase, int colbase, int tid,
    f32x4 acc[4][8])
{
    const int lane = tid & 63, wave = tid >> 6;
    const int wr = wave >> 1, wc = wave & 1;
    const int m16 = lane & 15, kg = lane >> 4;
    for (int kt = 0; kt < K; kt += 32) {
        const __hip_bfloat16* Ap; long lda; int kl;
        if (kt < k0end)      { Ap = A0; lda = lda0; kl = kt; }
        else if (kt < k1end) { Ap = A1; lda = lda1; kl = kt - k0end; }
        else                 { Ap = A2; lda = lda2; kl = kt - k1end; }
#pragma unroll
        for (int i = 0; i < 2; ++i) {   // A tile: 128 rows x 32 cols
            int cid = i * 256 + tid;
            int row = cid >> 2, kc = cid & 3;
            gload_lds16(Ap + (rowbase + row) * lda + kl + kc * 8, Asm + cid * 8);
        }
#pragma unroll
        for (int i = 0; i < 4; ++i) {   // B tile: 256 weight rows x 32 cols
            int cid = i * 256 + tid;
            int row = cid >> 2, kc = cid & 3;
            gload_lds16(B + (long)(colbase + row) * K + kt + kc * 8, Bsm + cid * 8);
        }
        __syncthreads();
        bf16x8 af[4], bv[8];
#pragma unroll
        for (int i = 0; i < 4; ++i)
            af[i] = *(const bf16x8*)(Asm + ((wr * 64 + i * 16 + m16) * 32 + kg * 8));
#pragma unroll
        for (int j = 0; j < 8; ++j)
            bv[j] = *(const bf16x8*)(Bsm + ((wc * 128 + j * 16 + m16) * 32 + kg * 8));
#pragma unroll
        for (int i = 0; i < 4; ++i)
#pragma unroll
            for (int j = 0; j < 8; ++j)
                acc[i][j] = __builtin_amdgcn_mfma_f32_16x16x32_bf16(af[i], bv[j], acc[i][j], 0, 0, 0);
        __syncthreads();
    }
}

__global__ __launch_bounds__(256) void gemm_nt256(
    const __hip_bfloat16* __restrict__ A0, int lda0, int k0end,
    const __hip_bfloat16* __restrict__ A1, int lda1, int k1end,
    const __hip_bfloat16* __restrict__ A2, int lda2,
    const __hip_bfloat16* __restrict__ B, int K,
    const float* __restrict__ bias,
    __hip_bfloat16* __restrict__ C, int ldc)
{
    __shared__ __align__(16) u16 Asm[128 * 32];
    __shared__ __align__(16) u16 Bsm[256 * 32];
    const int tid = threadIdx.x;
    const long rowbase = (long)blockIdx.y * 128;
    const int colbase = blockIdx.x * 256;
    f32x4 acc[4][8] = {};
    gemm_core256(A0, lda0, k0end, A1, lda1, k1end, A2, lda2, B, K, Asm, Bsm, rowbase, colbase, tid, acc);
    const int lane = tid & 63, wave = tid >> 6;
    const int wr = wave >> 1, wc = wave & 1;
    const int m16 = lane & 15, q = lane >> 4;
#pragma unroll
    for (int j = 0; j < 8; ++j) {
        int col = colbase + wc * 128 + j * 16 + m16;
        float bvv = bias[col];
#pragma unroll
        for (int i = 0; i < 4; ++i)
#pragma unroll
            for (int r = 0; r < 4; ++r) {
                long rowg = rowbase + wr * 64 + i * 16 + q * 4 + r;
                C[rowg * ldc + col] = f2bf(acc[i][j][r] + bvv);
            }
    }
}

__global__ __launch_bounds__(256) void gemm_nt_max256(
    const __hip_bfloat16* __restrict__ A0, int lda0, int k0end,
    const __hip_bfloat16* __restrict__ A1, int lda1, int k1end,
    const __hip_bfloat16* __restrict__ A2, int lda2,
    const __hip_bfloat16* __restrict__ B, int K,
    unsigned* __restrict__ g_enc)
{
    __shared__ __align__(16) u16 Asm[128 * 32];
    __shared__ __align__(16) u16 Bsm[256 * 32];
    __shared__ float red[2][256];
    const int tid = threadIdx.x;
    const long rowbase = (long)blockIdx.y * 128;
    const int colbase = blockIdx.x * 256;
    f32x4 acc[4][8] = {};
    gemm_core256(A0, lda0, k0end, A1, lda1, k1end, A2, lda2, B, K, Asm, Bsm, rowbase, colbase, tid, acc);
    const int lane = tid & 63, wave = tid >> 6;
    const int wr = wave >> 1, wc = wave & 1;
    const int m16 = lane & 15, q = lane >> 4;
#pragma unroll
    for (int j = 0; j < 8; ++j) {
        float m = -INFINITY;
#pragma unroll
        for (int i = 0; i < 4; ++i)
#pragma unroll
            for (int r = 0; r < 4; ++r) {
                long rowg = rowbase + wr * 64 + i * 16 + q * 4 + r;
                m = (rowg < NPTS) ? fmaxf(m, acc[i][j][r]) : m;
            }
        m = fmaxf(m, __shfl_xor(m, 16));
        m = fmaxf(m, __shfl_xor(m, 32));
        if (lane < 16) red[wr][wc * 128 + j * 16 + m16] = m;
    }
    __syncthreads();
    if (tid < 256) {
        float v = fmaxf(red[0][tid], red[1][tid]);
        atomicMax(g_enc + colbase + tid, enc_f32(v));
    }
}

// ---------------------------------------------------------------------------
// parallel head
// ---------------------------------------------------------------------------
__global__ __launch_bounds__(256) void head_g(
    const unsigned* __restrict__ g_enc, const float* __restrict__ cvec,
    const float* __restrict__ b_m2, float* __restrict__ g)
{
    int i = blockIdx.x * 256 + threadIdx.x;
    if (i < 1024) g[i] = dec_f32(g_enc[i]) + cvec[i] + b_m2[i];
}

__global__ __launch_bounds__(256) void head_lin(
    const float* __restrict__ in, const float* __restrict__ W,
    const float* __restrict__ b, float* __restrict__ out,
    int In, int Out, int do_relu)
{
    int o = blockIdx.x * 4 + (threadIdx.x >> 6);
    int lane = threadIdx.x & 63;
    if (o >= Out) return;
    float a = 0.f;
    for (int k = lane; k < In; k += 64) a += in[k] * W[(long)o * In + k];
#pragma unroll
    for (int off = 32; off > 0; off >>= 1) a += __shfl_xor(a, off);
    if (lane == 0) {
        float v = a + b[o];
        out[o] = do_relu ? fmaxf(v, 0.f) : v;
    }
}

// ---------------------------------------------------------------------------
extern "C" void kernel_launch(void* const* d_in, const int* in_sizes, int n_in,
                              void* d_out, int out_size, void* d_ws, size_t ws_size,
                              hipStream_t stream)
{
    (void)in_sizes; (void)n_in; (void)out_size; (void)ws_size;
    const float* centre = (const float*)d_in[0];
    const float* corner = (const float*)d_in[1];
    const float* normal = (const float*)d_in[2];
    const int*   neighbour = (const int*)d_in[3];
    const float* W_sp2 = (const float*)d_in[4];
    const float* b_sp2 = (const float*)d_in[5];
    const float* W_sp1 = (const float*)d_in[6];
    const float* b_sp1 = (const float*)d_in[7];
    const float* conv_w = (const float*)d_in[8];
    const float* conv_b = (const float*)d_in[9];
    const float* W_fr3 = (const float*)d_in[10];
    const float* b_fr3 = (const float*)d_in[11];
    const float* W_fr4 = (const float*)d_in[12];
    const float* b_fr4 = (const float*)d_in[13];
    const float* theta = (const float*)d_in[14];
    const float* phi   = (const float*)d_in[15];
    const float* W_c1 = (const float*)d_in[16];
    const float* b_c1 = (const float*)d_in[17];
    const float* W_a1 = (const float*)d_in[18];
    const float* b_a1 = (const float*)d_in[19];
    const float* W_c2 = (const float*)d_in[20];
    const float* b_c2 = (const float*)d_in[21];
    const float* W_a2 = (const float*)d_in[22];
    const float* b_a2 = (const float*)d_in[23];
    const float* W_f  = (const float*)d_in[24];
    const float* b_f  = (const float*)d_in[25];
    const float* W_m2 = (const float*)d_in[26];
    const float* b_m2 = (const float*)d_in[27];
    const float* W_m31 = (const float*)d_in[28];
    const float* b_m31 = (const float*)d_in[29];
    const float* W_m32 = (const float*)d_in[30];
    const float* b_m32 = (const float*)d_in[31];
    const float* W_m33 = (const float*)d_in[32];
    const float* b_m33 = (const float*)d_in[33];

    char* ws = (char*)d_ws;
    size_t off = 0;
    auto alloc = [&](size_t bytes) { void* p = ws + off; off += (bytes + 255) & ~(size_t)255; return p; };
    __hip_bfloat16* cat1  = (__hip_bfloat16*)alloc((size_t)NPAD * 256 * 2);  // [h1r|h3r|kc|nrm]
    __hip_bfloat16* agg1  = (__hip_bfloat16*)alloc((size_t)NPAD * 256 * 2);  // avg [h3r|kc|nrm]
    __hip_bfloat16* out2  = (__hip_bfloat16*)alloc((size_t)NPAD * 256 * 2);
    __hip_bfloat16* agg2  = (__hip_bfloat16*)alloc((size_t)NPAD * 256 * 2);
    float* Wc1p  = (float*)alloc((size_t)65536 * 4);
    float* Wa1pf = (float*)alloc((size_t)65536 * 4);
    __hip_bfloat16* Wa1fb = (__hip_bfloat16*)alloc((size_t)65536 * 2);       // Wa1p folded w/ Wfr4
    __hip_bfloat16* Xw    = (__hip_bfloat16*)alloc((size_t)1024 * 768 * 2);  // [X1'|X2'|V]
    float* T3f  = (float*)alloc((size_t)1024 * 512 * 4);
    float* T4f  = (float*)alloc((size_t)1024 * 512 * 4);
    float* U1f  = (float*)alloc((size_t)1024 * 256 * 4);
    float* U2f  = (float*)alloc((size_t)1024 * 256 * 4);
    float* X1f  = (float*)alloc((size_t)1024 * 256 * 4);
    float* X2f  = (float*)alloc((size_t)1024 * 256 * 4);
    float* cvec = (float*)alloc(1024 * 4);
    float* b_a1p = (float*)alloc(256 * 4);
    unsigned* g_enc = (unsigned*)alloc(1024 * 4);
    float* gvec = (float*)alloc(1024 * 4);
    float* h1   = (float*)alloc(512 * 4);
    float* h2   = (float*)alloc(256 * 4);

    prep<<<516, 256, 0, stream>>>(W_c1, W_a1, Wc1p, Wa1pf, g_enc);

    // ---- weight collapse: T3/T4 -> U1/U2 -> X1/X2 -> fold Wsp1/Wfr4 ----
    wgemm<<<dim3(16, 32), 256, 0, stream>>>(W_m2 + 768, 1792, W_f, 1024,
        W_m2 + 256, 1792, T3f, (__hip_bfloat16*)nullptr, 512, 1024);
    wgemm<<<dim3(16, 32), 256, 0, stream>>>(W_m2 + 768, 1792, W_f + 512, 1024,
        (const float*)nullptr, 0, T4f, (__hip_bfloat16*)nullptr, 512, 1024);
    wgemm<<<dim3(8, 32), 256, 0, stream>>>(T3f, 512, W_c2, 512,
        W_m2, 1792, U1f, (__hip_bfloat16*)nullptr, 256, 512);
    wgemm<<<dim3(8, 32), 256, 0, stream>>>(T3f, 512, W_c2 + 256, 512,
        (const float*)nullptr, 0, U2f, (__hip_bfloat16*)nullptr, 256, 512);
    wgemm<<<dim3(8, 32), 256, 0, stream>>>(U1f, 256, Wc1p, 256,
        (const float*)nullptr, 0, X1f, (__hip_bfloat16*)nullptr, 256, 256);
    wgemm<<<dim3(8, 32), 256, 0, stream>>>(U2f, 256, Wa1pf, 256,
        (const float*)nullptr, 0, X2f, (__hip_bfloat16*)nullptr, 256, 256);
    // X1' = [X1[:,0:64]@Wsp1 | X1[:,64:128]@Wfr4 | X1[:,128:256]]
    wgemm<<<dim3(2, 32), 256, 0, stream>>>(X1f, 256, W_sp1, 64,
        (const float*)nullptr, 0, (float*)nullptr, Xw, 768, 64);
    wgemm<<<dim3(2, 32), 256, 0, stream>>>(X1f + 64, 256, W_fr4, 64,
        (const float*)nullptr, 0, (float*)nullptr, Xw + 64, 768, 64);
    convcopy<<<512, 256, 0, stream>>>(X1f + 128, 256, Xw + 128, 768, 1024, 128);
    // X2' = [X2[:,0:64]@Wfr4 | X2[:,64:256]]
    wgemm<<<dim3(2, 32), 256, 0, stream>>>(X2f, 256, W_fr4, 64,
        (const float*)nullptr, 0, (float*)nullptr, Xw + 256, 768, 64);
    convcopy<<<768, 256, 0, stream>>>(X2f + 64, 256, Xw + 320, 768, 1024, 192);
    // V = T4@W_a2
    wgemm<<<dim3(8, 32), 256, 0, stream>>>(T4f, 512, W_a2, 256,
        (const float*)nullptr, 0, (float*)nullptr, Xw + 512, 768, 512);
    // Wa1f = [Wa1p[:,0:64]@Wfr4 | Wa1p[:,64:256]] ; b_a1' = b_a1 + Wa1p[:,0:64]@b_fr4
    wgemm<<<dim3(2, 8), 256, 0, stream>>>(Wa1pf, 256, W_fr4, 64,
        (const float*)nullptr, 0, (float*)nullptr, Wa1fb, 256, 64);
    convcopy<<<192, 256, 0, stream>>>(Wa1pf + 64, 256, Wa1fb + 64, 256, 256, 192);
    biasfold<<<1, 256, 0, stream>>>(b_a1, Wa1pf, b_fr4, b_a1p);
    cvec_kernel<<<4, 256, 0, stream>>>(W_m2, T3f, T4f, U1f, U2f, X1f, X2f,
        b_f, b_c2, b_a2, b_c1, b_a1, b_sp1, b_fr4, cvec);

    // ---- per-point path ----
    featurize<<<2048, 256, 0, stream>>>(centre, corner, normal, neighbour,
        W_sp2, b_sp2, conv_w, conv_b, W_fr3, b_fr3, theta, phi, cat1);
    gather_agg1<<<NPAD / 4, 256, 0, stream>>>(cat1, neighbour, agg1);
    // out2 = agg1' @ Wa1f^T + b_a1'   (single 256-col pass)
    gemm_nt256<<<dim3(1, NPAD / 128), 256, 0, stream>>>(agg1, 256, 256, agg1, 256, 256, agg1, 256,
                                                        Wa1fb, 256, b_a1p, out2, 256);
    gather_agg2<<<NPAD / 4, 256, 0, stream>>>(out2, neighbour, agg2);
    // g = max_n([cat1'|agg1'|agg2] @ Xw^T)
    gemm_nt_max256<<<dim3(4, NPAD / 128), 256, 0, stream>>>(cat1, 256, 256, agg1, 256, 512, agg2, 256,
                                                            Xw, 768, g_enc);
    // ---- head ----
    head_g<<<4, 256, 0, stream>>>(g_enc, cvec, b_m2, gvec);
    head_lin<<<128, 256, 0, stream>>>(gvec, W_m31, b_m31, h1, 1024, 512, 1);
    head_lin<<<64, 256, 0, stream>>>(h1, W_m32, b_m32, h2, 512, 256, 1);
    head_lin<<<10, 256, 0, stream>>>(h2, W_m33, b_m33, (float*)d_out, 256, 40, 0);
}

// Round 6
// 615.262 us; speedup vs baseline: 1.3177x; 1.3177x over previous
//
#include <hip/hip_runtime.h>
#include <hip/hip_bf16.h>
#include <stdint.h>

#define NPTS 50000
#define NPAD 50048   // 391 * 128 row tiles

typedef unsigned short u16;
typedef __attribute__((ext_vector_type(8))) __bf16 bf16x8;
typedef __attribute__((ext_vector_type(4))) float f32x4;

__device__ __forceinline__ float bf2f(__hip_bfloat16 v) { return __bfloat162float(v); }
__device__ __forceinline__ __hip_bfloat16 f2bf(float v) { return __float2bfloat16(v); }
__device__ __forceinline__ int clampi(int v) { return v < 0 ? 0 : (v >= NPTS ? NPTS - 1 : v); }

__device__ __forceinline__ unsigned enc_f32(float f) {
    unsigned b = __float_as_uint(f);
    return (b & 0x80000000u) ? ~b : (b | 0x80000000u);
}
__device__ __forceinline__ float dec_f32(unsigned u) {
    return (u & 0x80000000u) ? __uint_as_float(u & 0x7fffffffu) : __uint_as_float(~u);
}

__device__ __forceinline__ void gload_lds16(const void* g, void* l) {
    __builtin_amdgcn_global_load_lds((__attribute__((address_space(1))) void*)g,
                                     (__attribute__((address_space(3))) void*)l, 16, 0, 0);
}

// ---------------------------------------------------------------------------
// prep: zero-pad W_c1 (256x195)->fp32, W_a1 (256x131)->fp32; g_enc=-inf
// ---------------------------------------------------------------------------
__global__ __launch_bounds__(256) void prep(
    const float* __restrict__ W_c1, const float* __restrict__ W_a1,
    float* __restrict__ Wc1p, float* __restrict__ Wa1pf,
    unsigned* __restrict__ g_enc)
{
    int i = blockIdx.x * 256 + threadIdx.x;
    if (i < 65536) {
        int o = i >> 8, k = i & 255;
        Wc1p[i] = (k < 195) ? W_c1[o * 195 + k] : 0.f;
    } else if (i < 131072) {
        int t = i - 65536;
        int o = t >> 8, k = t & 255;
        Wa1pf[t] = (k < 131) ? W_a1[o * 131 + k] : 0.f;
    } else if (i < 132096) {
        g_enc[i - 131072] = 0x007FFFFFu;   // enc(-inf)
    }
}

// ---------------------------------------------------------------------------
// wgemm64 (fp32): C[i][j] = sum_k A[i*lda+k]*B[k*ldb+j] (+ D for cols<dcols).
// 64x64 tile, 4x4 per thread, float4 LDS reads. M,N mult of 64; K mult of 16.
// ---------------------------------------------------------------------------
__global__ __launch_bounds__(256) void wgemm64(
    const float* __restrict__ A, int lda,
    const float* __restrict__ B, int ldb,
    const float* __restrict__ D, int ldd, int dcols,
    float* __restrict__ Cf, __hip_bfloat16* __restrict__ Cb, int ldc,
    int K)
{
    __shared__ float sA[16][68], sB[16][68];   // [k][m]/[k][n]; 68: 16B-aligned rows
    const int bj = blockIdx.x, bi = blockIdx.y;
    const int t = threadIdx.x, tx = t & 15, ty = t >> 4;
    float acc[4][4] = {};
    for (int k0 = 0; k0 < K; k0 += 16) {
        {
            int k = t & 15, m = t >> 4;
#pragma unroll
            for (int q = 0; q < 4; ++q)
                sA[k][m + q * 16] = A[(long)(bi * 64 + m + q * 16) * lda + k0 + k];
            int n = t & 63, kk = t >> 6;
#pragma unroll
            for (int q = 0; q < 4; ++q)
                sB[kk + q * 4][n] = B[(long)(k0 + kk + q * 4) * ldb + bj * 64 + n];
        }
        __syncthreads();
#pragma unroll
        for (int k = 0; k < 16; ++k) {
            f32x4 av = *(const f32x4*)&sA[k][ty * 4];
            f32x4 bv = *(const f32x4*)&sB[k][tx * 4];
#pragma unroll
            for (int i = 0; i < 4; ++i)
#pragma unroll
                for (int j = 0; j < 4; ++j)
                    acc[i][j] += av[i] * bv[j];
        }
        __syncthreads();
    }
#pragma unroll
    for (int i = 0; i < 4; ++i) {
        int r = bi * 64 + ty * 4 + i;
#pragma unroll
        for (int j = 0; j < 4; ++j) {
            int cidx = bj * 64 + tx * 4 + j;
            float v = acc[i][j];
            if (D && cidx < dcols) v += D[(long)r * ldd + cidx];
            if (Cf) Cf[(long)r * ldc + cidx] = v;
            if (Cb) Cb[(long)r * ldc + cidx] = f2bf(v);
        }
    }
}

// fp32 -> bf16 strided copy
__global__ __launch_bounds__(256) void convcopy(
    const float* __restrict__ src, int lds, __hip_bfloat16* __restrict__ dst, int ldd,
    int rows, int cols)
{
    int i = blockIdx.x * 256 + threadIdx.x;
    if (i >= rows * cols) return;
    int r = i / cols, c = i % cols;
    dst[(long)r * ldd + c] = f2bf(src[(long)r * lds + c]);
}

// b_a1p[o] = b_a1[o] + sum_{h<64} Wa1pf[o][h] * b_fr4[h]
__global__ __launch_bounds__(256) void biasfold(
    const float* __restrict__ b_a1, const float* __restrict__ Wa1pf,
    const float* __restrict__ b_fr4, float* __restrict__ b_a1p)
{
    int o = threadIdx.x;
    float s = b_a1[o];
    for (int h = 0; h < 64; ++h) s += Wa1pf[o * 256 + h] * b_fr4[h];
    b_a1p[o] = s;
}

// cvec: all bias contributions of the collapsed affine chain
__global__ __launch_bounds__(256) void cvec_kernel(
    const float* __restrict__ W_m2,
    const float* __restrict__ Tf, const float* __restrict__ Uf,
    const float* __restrict__ X1f, const float* __restrict__ X2f,
    const float* __restrict__ b_f, const float* __restrict__ b_c2,
    const float* __restrict__ b_a2, const float* __restrict__ b_c1,
    const float* __restrict__ b_a1, const float* __restrict__ b_sp1,
    const float* __restrict__ b_fr4,
    float* __restrict__ cvec)
{
    int i = blockIdx.x * 256 + threadIdx.x;
    if (i >= 1024) return;
    float s = 0.f;
    for (int k = 0; k < 1024; ++k) s += b_f[k] * W_m2[(long)i * 1792 + 768 + k];
    for (int k = 0; k < 512;  ++k) s += b_c2[k] * Tf[(long)i * 1024 + k];
    for (int k = 0; k < 512;  ++k) s += b_a2[k] * Tf[(long)i * 1024 + 512 + k];
    for (int k = 0; k < 256;  ++k) s += b_c1[k] * Uf[(long)i * 512 + k];
    for (int k = 0; k < 256;  ++k) s += b_a1[k] * Uf[(long)i * 512 + 256 + k];
    for (int k = 0; k < 64;   ++k) s += b_sp1[k] * X1f[(long)i * 256 + k];
    for (int k = 0; k < 64;   ++k) s += b_fr4[k] * X1f[(long)i * 256 + 64 + k];
    for (int k = 0; k < 64;   ++k) s += b_fr4[k] * X2f[(long)i * 256 + k];
    cvec[i] = s;
}

// ---------------------------------------------------------------------------
// featurize (light): cat1 row = [h1r | h3r | kc | nrm | 0]
// ---------------------------------------------------------------------------
__global__ __launch_bounds__(256) void featurize(
    const float* __restrict__ centre, const float* __restrict__ corner,
    const float* __restrict__ normal, const int* __restrict__ neighbour,
    const float* __restrict__ W_sp2, const float* __restrict__ b_sp2,
    const float* __restrict__ conv_w, const float* __restrict__ conv_b,
    const float* __restrict__ W_fr3, const float* __restrict__ b_fr3,
    const float* __restrict__ theta, const float* __restrict__ phi,
    __hip_bfloat16* __restrict__ cat1)
{
    __shared__ float sWsp2t[3][64];  __shared__ float sbsp2[64];
    __shared__ float sconvt[6][32];  __shared__ float sconvb[32];
    __shared__ float sWfr3t[32][64]; __shared__ float sbfr3[64];
    __shared__ float kt4x[4][64], kt4y[4][64], kt4z[4][64];

    const int tid = threadIdx.x;
    for (int i = tid; i < 2048; i += 256) { int j = i >> 5, k = i & 31; sWfr3t[k][j] = W_fr3[i]; }
    for (int i = tid; i < 192; i += 256) { int j = i / 3, k = i % 3; sWsp2t[k][j] = W_sp2[i]; }
    for (int i = tid; i < 192; i += 256) { int o = i / 6, k = i % 6; sconvt[k][o] = conv_w[i]; }
    if (tid < 64) { sbsp2[tid] = b_sp2[tid]; sbfr3[tid] = b_fr3[tid]; }
    if (tid < 32) sconvb[tid] = conv_b[tid];
    {
        int j = tid >> 2, s = tid & 3;
        float th = theta[tid], ph = phi[tid];
        float st = sinf(th), ct = cosf(th), sp = sinf(ph), cp = cosf(ph);
        kt4x[s][j] = st * sp; kt4y[s][j] = st * cp; kt4z[s][j] = ct;
    }
    __syncthreads();

    const int lane = tid & 63, wave = tid >> 6;
    for (long p = (long)blockIdx.x * 4 + wave; p < NPAD; p += (long)gridDim.x * 4) {
        __hip_bfloat16* row = cat1 + p * 256;
        if (p >= NPTS) {
            __hip_bfloat16 z = f2bf(0.f);
            row[lane] = z; row[64 + lane] = z; row[128 + lane] = z; row[192 + lane] = z;
            continue;
        }
        float cx = centre[p * 3], cy = centre[p * 3 + 1], cz = centre[p * 3 + 2];
        float h1r = fmaxf(sbsp2[lane] + cx * sWsp2t[0][lane] + cy * sWsp2t[1][lane]
                          + cz * sWsp2t[2][lane], 0.f);
        float mval = 0.f;
        if (lane < 32) {
            float c0 = corner[p*9+0], c1 = corner[p*9+1], c2 = corner[p*9+2];
            float c3 = corner[p*9+3], c4 = corner[p*9+4], c5 = corner[p*9+5];
            float c6 = corner[p*9+6], c7 = corner[p*9+7], c8 = corner[p*9+8];
            float s0 = c0 + c3 + c6, s1 = c1 + c4 + c7, s2 = c2 + c5 + c8;
            mval = sconvb[lane] + (1.f / 3.f) *
                ((sconvt[0][lane] + sconvt[3][lane]) * s0 +
                 (sconvt[1][lane] + sconvt[4][lane]) * s1 +
                 (sconvt[2][lane] + sconvt[5][lane]) * s2);
        }
        float h3 = sbfr3[lane];
#pragma unroll 8
        for (int k = 0; k < 32; ++k) h3 += __shfl(mval, k) * sWfr3t[k][lane];
        float h3r = fmaxf(h3, 0.f);
        int nb0 = clampi(neighbour[p * 3]), nb1 = clampi(neighbour[p * 3 + 1]), nb2 = clampi(neighbour[p * 3 + 2]);
        float nx[4], ny[4], nz[4];
        nx[0] = normal[p * 3];          ny[0] = normal[p * 3 + 1];          nz[0] = normal[p * 3 + 2];
        nx[1] = normal[(long)nb0 * 3];  ny[1] = normal[(long)nb0 * 3 + 1];  nz[1] = normal[(long)nb0 * 3 + 2];
        nx[2] = normal[(long)nb1 * 3];  ny[2] = normal[(long)nb1 * 3 + 1];  nz[2] = normal[(long)nb1 * 3 + 2];
        nx[3] = normal[(long)nb2 * 3];  ny[3] = normal[(long)nb2 * 3 + 1];  nz[3] = normal[(long)nb2 * 3 + 2];
        float kcs = 0.f;
#pragma unroll
        for (int s = 0; s < 4; ++s) {
            float kx = kt4x[s][lane], ky = kt4y[s][lane], kz = kt4z[s][lane];
#pragma unroll
            for (int t = 0; t < 4; ++t) {
                float dx = nx[t] - kx, dy = ny[t] - ky, dz = nz[t] - kz;
                kcs += __expf(-12.5f * (dx * dx + dy * dy + dz * dz));
            }
        }
        float kcv = kcs * (1.f / 16.f);
        float nrmv = (lane == 0) ? nx[0] : (lane == 1) ? ny[0] : (lane == 2) ? nz[0] : 0.f;
        row[lane] = f2bf(h1r); row[64 + lane] = f2bf(h3r);
        row[128 + lane] = f2bf(kcv); row[192 + lane] = f2bf(nrmv);
    }
}

// ---------------------------------------------------------------------------
// gathers
// ---------------------------------------------------------------------------
__global__ __launch_bounds__(256) void gather_agg1(
    const __hip_bfloat16* __restrict__ cat1, const int* __restrict__ neighbour,
    __hip_bfloat16* __restrict__ agg1)
{
    long p = (long)blockIdx.x * 4 + (threadIdx.x >> 6);
    int lane = threadIdx.x & 63;
    if (p >= NPAD) return;
    __hip_bfloat16* o = agg1 + p * 256;
    if (p >= NPTS) {
        __hip_bfloat16 z = f2bf(0.f);
        o[lane] = z; o[64 + lane] = z; o[128 + lane] = z; o[192 + lane] = z;
        return;
    }
    int nb0 = clampi(neighbour[p * 3]), nb1 = clampi(neighbour[p * 3 + 1]), nb2 = clampi(neighbour[p * 3 + 2]);
    const __hip_bfloat16* r0 = cat1 + p * 256 + 64;
    const __hip_bfloat16* r1 = cat1 + (long)nb0 * 256 + 64;
    const __hip_bfloat16* r2 = cat1 + (long)nb1 * 256 + 64;
    const __hip_bfloat16* r3 = cat1 + (long)nb2 * 256 + 64;
    float a = (bf2f(r0[lane]) + bf2f(r1[lane]) + bf2f(r2[lane]) + bf2f(r3[lane])) * 0.25f;
    float b = (bf2f(r0[64 + lane]) + bf2f(r1[64 + lane]) + bf2f(r2[64 + lane]) + bf2f(r3[64 + lane])) * 0.25f;
    float c = (lane < 3) ? (bf2f(r0[128 + lane]) + bf2f(r1[128 + lane]) + bf2f(r2[128 + lane]) + bf2f(r3[128 + lane])) * 0.25f : 0.f;
    o[lane] = f2bf(a); o[64 + lane] = f2bf(b); o[128 + lane] = f2bf(c); o[192 + lane] = f2bf(0.f);
}

__global__ __launch_bounds__(256) void gather_agg2(
    const __hip_bfloat16* __restrict__ out2, const int* __restrict__ neighbour,
    __hip_bfloat16* __restrict__ agg2)
{
    long p = (long)blockIdx.x * 4 + (threadIdx.x >> 6);
    int lane = threadIdx.x & 63;
    if (p >= NPAD) return;
    __hip_bfloat16* o = agg2 + p * 256;
    if (p >= NPTS) {
        __hip_bfloat16 z = f2bf(0.f);
        o[lane] = z; o[64 + lane] = z; o[128 + lane] = z; o[192 + lane] = z;
        return;
    }
    int nb0 = clampi(neighbour[p * 3]), nb1 = clampi(neighbour[p * 3 + 1]), nb2 = clampi(neighbour[p * 3 + 2]);
    const __hip_bfloat16* r0 = out2 + p * 256;
    const __hip_bfloat16* r1 = out2 + (long)nb0 * 256;
    const __hip_bfloat16* r2 = out2 + (long)nb1 * 256;
    const __hip_bfloat16* r3 = out2 + (long)nb2 * 256;
#pragma unroll
    for (int q = 0; q < 4; ++q) {
        int c = q * 64 + lane;
        o[c] = f2bf((bf2f(r0[c]) + bf2f(r1[c]) + bf2f(r2[c]) + bf2f(r3[c])) * 0.25f);
    }
}

// ---------------------------------------------------------------------------
// 128x128 bf16 MFMA GEMM core (R4 config: acc[4][4], 72 VGPR, ~28% occ)
// ---------------------------------------------------------------------------
__device__ __forceinline__ void gemm_core(
    const __hip_bfloat16* A0, int lda0, int k0end,
    const __hip_bfloat16* A1, int lda1, int k1end,
    const __hip_bfloat16* A2, int lda2,
    const __hip_bfloat16* B, int K,
    u16* Asm, u16* Bsm, long rowbase, int colbase, int tid,
    f32x4 acc[4][4])
{
    const int lane = tid & 63, wave = tid >> 6;
    const int wr = wave >> 1, wc = wave & 1;
    const int m16 = lane & 15, kg = lane >> 4;
    for (int kt = 0; kt < K; kt += 32) {
        const __hip_bfloat16* Ap; long lda; int kl;
        if (kt < k0end)      { Ap = A0; lda = lda0; kl = kt; }
        else if (kt < k1end) { Ap = A1; lda = lda1; kl = kt - k0end; }
        else                 { Ap = A2; lda = lda2; kl = kt - k1end; }
#pragma unroll
        for (int i = 0; i < 2; ++i) {
            int cid = i * 256 + tid;
            int row = cid >> 2, kc = cid & 3;
            gload_lds16(Ap + (rowbase + row) * lda + kl + kc * 8, Asm + cid * 8);
        }
#pragma unroll
        for (int i = 0; i < 2; ++i) {
            int cid = i * 256 + tid;
            int row = cid >> 2, kc = cid & 3;
            gload_lds16(B + (long)(colbase + row) * K + kt + kc * 8, Bsm + cid * 8);
        }
        __syncthreads();
        bf16x8 af[4], bv[4];
#pragma unroll
        for (int i = 0; i < 4; ++i)
            af[i] = *(const bf16x8*)(Asm + ((wr * 64 + i * 16 + m16) * 32 + kg * 8));
#pragma unroll
        for (int j = 0; j < 4; ++j)
            bv[j] = *(const bf16x8*)(Bsm + ((wc * 64 + j * 16 + m16) * 32 + kg * 8));
#pragma unroll
        for (int i = 0; i < 4; ++i)
#pragma unroll
            for (int j = 0; j < 4; ++j)
                acc[i][j] = __builtin_amdgcn_mfma_f32_16x16x32_bf16(af[i], bv[j], acc[i][j], 0, 0, 0);
        __syncthreads();
    }
}

__global__ __launch_bounds__(256) void gemm_nt(
    const __hip_bfloat16* __restrict__ A0, int lda0, int k0end,
    const __hip_bfloat16* __restrict__ A1, int lda1, int k1end,
    const __hip_bfloat16* __restrict__ A2, int lda2,
    const __hip_bfloat16* __restrict__ B, int K,
    const float* __restrict__ bias,
    __hip_bfloat16* __restrict__ C, int ldc)
{
    __shared__ __align__(16) u16 Asm[128 * 32];
    __shared__ __align__(16) u16 Bsm[128 * 32];
    const int tid = threadIdx.x;
    const long rowbase = (long)blockIdx.y * 128;
    const int colbase = blockIdx.x * 128;
    f32x4 acc[4][4] = {};
    gemm_core(A0, lda0, k0end, A1, lda1, k1end, A2, lda2, B, K, Asm, Bsm, rowbase, colbase, tid, acc);
    const int lane = tid & 63, wave = tid >> 6;
    const int wr = wave >> 1, wc = wave & 1;
    const int m16 = lane & 15, q = lane >> 4;
#pragma unroll
    for (int j = 0; j < 4; ++j) {
        int col = colbase + wc * 64 + j * 16 + m16;
        float bvv = bias[col];
#pragma unroll
        for (int i = 0; i < 4; ++i)
#pragma unroll
            for (int r = 0; r < 4; ++r) {
                long rowg = rowbase + wr * 64 + i * 16 + q * 4 + r;
                C[rowg * ldc + col] = f2bf(acc[i][j][r] + bvv);
            }
    }
}

// max-GEMM, XCD-swizzled 1D grid: all 8 col-tiles of a row-tile share id%8
// (-> same XCD under round-robin dispatch) so the A row-tile stays in that
// XCD's L2 instead of being refetched from HBM 8x.
__global__ __launch_bounds__(256) void gemm_nt_max(
    const __hip_bfloat16* __restrict__ A0, int lda0, int k0end,
    const __hip_bfloat16* __restrict__ A1, int lda1, int k1end,
    const __hip_bfloat16* __restrict__ A2, int lda2,
    const __hip_bfloat16* __restrict__ B, int K,
    unsigned* __restrict__ g_enc)
{
    __shared__ __align__(16) u16 Asm[128 * 32];
    __shared__ __align__(16) u16 Bsm[128 * 32];
    __shared__ float red[2][128];
    const int id = blockIdx.x;
    const int c = id & 7, tt = id >> 3;
    const int j8 = tt & 7, rh = tt >> 3;
    const int r = rh * 8 + c;
    if (r >= NPAD / 128) return;
    const long rowbase = (long)r * 128;
    const int colbase = j8 * 128;
    const int tid = threadIdx.x;
    f32x4 acc[4][4] = {};
    gemm_core(A0, lda0, k0end, A1, lda1, k1end, A2, lda2, B, K, Asm, Bsm, rowbase, colbase, tid, acc);
    const int lane = tid & 63, wave = tid >> 6;
    const int wr = wave >> 1, wc = wave & 1;
    const int m16 = lane & 15, q = lane >> 4;
#pragma unroll
    for (int j = 0; j < 4; ++j) {
        float m = -INFINITY;
#pragma unroll
        for (int i = 0; i < 4; ++i)
#pragma unroll
            for (int rr = 0; rr < 4; ++rr) {
                long rowg = rowbase + wr * 64 + i * 16 + q * 4 + rr;
                m = (rowg < NPTS) ? fmaxf(m, acc[i][j][rr]) : m;
            }
        m = fmaxf(m, __shfl_xor(m, 16));
        m = fmaxf(m, __shfl_xor(m, 32));
        if (lane < 16) red[wr][wc * 64 + j * 16 + m16] = m;
    }
    __syncthreads();
    if (tid < 128) {
        float v = fmaxf(red[0][tid], red[1][tid]);
        atomicMax(g_enc + colbase + tid, enc_f32(v));
    }
}

// ---------------------------------------------------------------------------
// parallel head
// ---------------------------------------------------------------------------
__global__ __launch_bounds__(256) void head_g(
    const unsigned* __restrict__ g_enc, const float* __restrict__ cvec,
    const float* __restrict__ b_m2, float* __restrict__ g)
{
    int i = blockIdx.x * 256 + threadIdx.x;
    if (i < 1024) g[i] = dec_f32(g_enc[i]) + cvec[i] + b_m2[i];
}

__global__ __launch_bounds__(256) void head_lin(
    const float* __restrict__ in, const float* __restrict__ W,
    const float* __restrict__ b, float* __restrict__ out,
    int In, int Out, int do_relu)
{
    int o = blockIdx.x * 4 + (threadIdx.x >> 6);
    int lane = threadIdx.x & 63;
    if (o >= Out) return;
    float a = 0.f;
    for (int k = lane; k < In; k += 64) a += in[k] * W[(long)o * In + k];
#pragma unroll
    for (int off = 32; off > 0; off >>= 1) a += __shfl_xor(a, off);
    if (lane == 0) {
        float v = a + b[o];
        out[o] = do_relu ? fmaxf(v, 0.f) : v;
    }
}

// ---------------------------------------------------------------------------
extern "C" void kernel_launch(void* const* d_in, const int* in_sizes, int n_in,
                              void* d_out, int out_size, void* d_ws, size_t ws_size,
                              hipStream_t stream)
{
    (void)in_sizes; (void)n_in; (void)out_size; (void)ws_size;
    const float* centre = (const float*)d_in[0];
    const float* corner = (const float*)d_in[1];
    const float* normal = (const float*)d_in[2];
    const int*   neighbour = (const int*)d_in[3];
    const float* W_sp2 = (const float*)d_in[4];
    const float* b_sp2 = (const float*)d_in[5];
    const float* W_sp1 = (const float*)d_in[6];
    const float* b_sp1 = (const float*)d_in[7];
    const float* conv_w = (const float*)d_in[8];
    const float* conv_b = (const float*)d_in[9];
    const float* W_fr3 = (const float*)d_in[10];
    const float* b_fr3 = (const float*)d_in[11];
    const float* W_fr4 = (const float*)d_in[12];
    const float* b_fr4 = (const float*)d_in[13];
    const float* theta = (const float*)d_in[14];
    const float* phi   = (const float*)d_in[15];
    const float* W_c1 = (const float*)d_in[16];
    const float* b_c1 = (const float*)d_in[17];
    const float* W_a1 = (const float*)d_in[18];
    const float* b_a1 = (const float*)d_in[19];
    const float* W_c2 = (const float*)d_in[20];
    const float* b_c2 = (const float*)d_in[21];
    const float* W_a2 = (const float*)d_in[22];
    const float* b_a2 = (const float*)d_in[23];
    const float* W_f  = (const float*)d_in[24];
    const float* b_f  = (const float*)d_in[25];
    const float* W_m2 = (const float*)d_in[26];
    const float* b_m2 = (const float*)d_in[27];
    const float* W_m31 = (const float*)d_in[28];
    const float* b_m31 = (const float*)d_in[29];
    const float* W_m32 = (const float*)d_in[30];
    const float* b_m32 = (const float*)d_in[31];
    const float* W_m33 = (const float*)d_in[32];
    const float* b_m33 = (const float*)d_in[33];

    char* ws = (char*)d_ws;
    size_t off = 0;
    auto alloc = [&](size_t bytes) { void* p = ws + off; off += (bytes + 255) & ~(size_t)255; return p; };
    __hip_bfloat16* cat1  = (__hip_bfloat16*)alloc((size_t)NPAD * 256 * 2);
    __hip_bfloat16* agg1  = (__hip_bfloat16*)alloc((size_t)NPAD * 256 * 2);
    __hip_bfloat16* out2  = (__hip_bfloat16*)alloc((size_t)NPAD * 256 * 2);
    __hip_bfloat16* agg2  = (__hip_bfloat16*)alloc((size_t)NPAD * 256 * 2);
    float* Wc1p  = (float*)alloc((size_t)65536 * 4);
    float* Wa1pf = (float*)alloc((size_t)65536 * 4);
    __hip_bfloat16* Wa1fb = (__hip_bfloat16*)alloc((size_t)65536 * 2);
    __hip_bfloat16* Xw    = (__hip_bfloat16*)alloc((size_t)1024 * 768 * 2);  // [X1'|X2'|V]
    float* Tf   = (float*)alloc((size_t)1024 * 1024 * 4);                    // [T3|T4]
    float* Uf   = (float*)alloc((size_t)1024 * 512 * 4);                     // [U1|U2]
    float* X1f  = (float*)alloc((size_t)1024 * 256 * 4);
    float* X2f  = (float*)alloc((size_t)1024 * 256 * 4);
    float* cvec = (float*)alloc(1024 * 4);
    float* b_a1p = (float*)alloc(256 * 4);
    unsigned* g_enc = (unsigned*)alloc(1024 * 4);
    float* gvec = (float*)alloc(1024 * 4);
    float* h1   = (float*)alloc(512 * 4);
    float* h2   = (float*)alloc(256 * 4);

    prep<<<516, 256, 0, stream>>>(W_c1, W_a1, Wc1p, Wa1pf, g_enc);

    // ---- weight collapse (merged): T=[T3|T4], U=[U1|U2], X1/X2, folds ----
    // T = M3 @ W_f (+ M2 on cols<512)
    wgemm64<<<dim3(16, 16), 256, 0, stream>>>(W_m2 + 768, 1792, W_f, 1024,
        W_m2 + 256, 1792, 512, Tf, (__hip_bfloat16*)nullptr, 1024, 1024);
    // U = T3 @ W_c2 (+ M1 on cols<256)
    wgemm64<<<dim3(8, 16), 256, 0, stream>>>(Tf, 1024, W_c2, 512,
        W_m2, 1792, 256, Uf, (__hip_bfloat16*)nullptr, 512, 512);
    // X1 = U1@Wc1p ; X2 = U2@Wa1pf
    wgemm64<<<dim3(4, 16), 256, 0, stream>>>(Uf, 512, Wc1p, 256,
        (const float*)nullptr, 0, 0, X1f, (__hip_bfloat16*)nullptr, 256, 256);
    wgemm64<<<dim3(4, 16), 256, 0, stream>>>(Uf + 256, 512, Wa1pf, 256,
        (const float*)nullptr, 0, 0, X2f, (__hip_bfloat16*)nullptr, 256, 256);
    // X1' = [X1[:,0:64]@Wsp1 | X1[:,64:128]@Wfr4 | X1[:,128:256]]
    wgemm64<<<dim3(1, 16), 256, 0, stream>>>(X1f, 256, W_sp1, 64,
        (const float*)nullptr, 0, 0, (float*)nullptr, Xw, 768, 64);
    wgemm64<<<dim3(1, 16), 256, 0, stream>>>(X1f + 64, 256, W_fr4, 64,
        (const float*)nullptr, 0, 0, (float*)nullptr, Xw + 64, 768, 64);
    convcopy<<<512, 256, 0, stream>>>(X1f + 128, 256, Xw + 128, 768, 1024, 128);
    // X2' = [X2[:,0:64]@Wfr4 | X2[:,64:256]]
    wgemm64<<<dim3(1, 16), 256, 0, stream>>>(X2f, 256, W_fr4, 64,
        (const float*)nullptr, 0, 0, (float*)nullptr, Xw + 256, 768, 64);
    convcopy<<<768, 256, 0, stream>>>(X2f + 64, 256, Xw + 320, 768, 1024, 192);
    // V = T4 @ W_a2
    wgemm64<<<dim3(4, 16), 256, 0, stream>>>(Tf + 512, 1024, W_a2, 256,
        (const float*)nullptr, 0, 0, (float*)nullptr, Xw + 512, 768, 512);
    // Wa1f fold + bias fold
    wgemm64<<<dim3(1, 4), 256, 0, stream>>>(Wa1pf, 256, W_fr4, 64,
        (const float*)nullptr, 0, 0, (float*)nullptr, Wa1fb, 256, 64);
    convcopy<<<192, 256, 0, stream>>>(Wa1pf + 64, 256, Wa1fb + 64, 256, 256, 192);
    biasfold<<<1, 256, 0, stream>>>(b_a1, Wa1pf, b_fr4, b_a1p);
    cvec_kernel<<<4, 256, 0, stream>>>(W_m2, Tf, Uf, X1f, X2f,
        b_f, b_c2, b_a2, b_c1, b_a1, b_sp1, b_fr4, cvec);

    // ---- per-point path ----
    featurize<<<2048, 256, 0, stream>>>(centre, corner, normal, neighbour,
        W_sp2, b_sp2, conv_w, conv_b, W_fr3, b_fr3, theta, phi, cat1);
    gather_agg1<<<NPAD / 4, 256, 0, stream>>>(cat1, neighbour, agg1);
    // out2 = agg1' @ Wa1f^T + b_a1'
    gemm_nt<<<dim3(2, NPAD / 128), 256, 0, stream>>>(agg1, 256, 256, agg1, 256, 256, agg1, 256,
                                                     Wa1fb, 256, b_a1p, out2, 256);
    gather_agg2<<<NPAD / 4, 256, 0, stream>>>(out2, neighbour, agg2);
    // g = max_n([cat1'|agg1'|agg2] @ Xw^T), XCD-swizzled grid
    gemm_nt_max<<<3136, 256, 0, stream>>>(cat1, 256, 256, agg1, 256, 512, agg2, 256,
                                          Xw, 768, g_enc);
    // ---- head ----
    head_g<<<4, 256, 0, stream>>>(g_enc, cvec, b_m2, gvec);
    head_lin<<<128, 256, 0, stream>>>(gvec, W_m31, b_m31, h1, 1024, 512, 1);
    head_lin<<<64, 256, 0, stream>>>(h1, W_m32, b_m32, h2, 512, 256, 1);
    head_lin<<<10, 256, 0, stream>>>(h2, W_m33, b_m33, (float*)d_out, 256, 40, 0);
}

// Round 7
// 610.564 us; speedup vs baseline: 1.3278x; 1.0077x over previous
//
#include <hip/hip_runtime.h>
#include <hip/hip_bf16.h>
#include <stdint.h>

#define NPTS 50000
#define NPAD 50048   // 391 * 128 row tiles

typedef unsigned short u16;
typedef __attribute__((ext_vector_type(8))) __bf16 bf16x8;
typedef __attribute__((ext_vector_type(4))) float f32x4;

__device__ __forceinline__ float bf2f(__hip_bfloat16 v) { return __bfloat162float(v); }
__device__ __forceinline__ __hip_bfloat16 f2bf(float v) { return __float2bfloat16(v); }
__device__ __forceinline__ int clampi(int v) { return v < 0 ? 0 : (v >= NPTS ? NPTS - 1 : v); }

__device__ __forceinline__ unsigned enc_f32(float f) {
    unsigned b = __float_as_uint(f);
    return (b & 0x80000000u) ? ~b : (b | 0x80000000u);
}
__device__ __forceinline__ float dec_f32(unsigned u) {
    return (u & 0x80000000u) ? __uint_as_float(u & 0x7fffffffu) : __uint_as_float(~u);
}

__device__ __forceinline__ void gload_lds16(const void* g, void* l) {
    __builtin_amdgcn_global_load_lds((__attribute__((address_space(1))) void*)g,
                                     (__attribute__((address_space(3))) void*)l, 16, 0, 0);
}

// ---------------------------------------------------------------------------
// prep: zero-pad W_c1 (256x195)->fp32, W_a1 (256x131)->fp32; g_enc=-inf
// ---------------------------------------------------------------------------
__global__ __launch_bounds__(256) void prep(
    const float* __restrict__ W_c1, const float* __restrict__ W_a1,
    float* __restrict__ Wc1p, float* __restrict__ Wa1pf,
    unsigned* __restrict__ g_enc)
{
    int i = blockIdx.x * 256 + threadIdx.x;
    if (i < 65536) {
        int o = i >> 8, k = i & 255;
        Wc1p[i] = (k < 195) ? W_c1[o * 195 + k] : 0.f;
    } else if (i < 131072) {
        int t = i - 65536;
        int o = t >> 8, k = t & 255;
        Wa1pf[t] = (k < 131) ? W_a1[o * 131 + k] : 0.f;
    } else if (i < 132096) {
        g_enc[i - 131072] = 0x007FFFFFu;   // enc(-inf)
    }
}

// ---------------------------------------------------------------------------
// wgemm64 (fp32): C = A@B (+ D on cols<dcols). 64x64 tile, 4x4/thread.
// ---------------------------------------------------------------------------
__global__ __launch_bounds__(256) void wgemm64(
    const float* __restrict__ A, int lda,
    const float* __restrict__ B, int ldb,
    const float* __restrict__ D, int ldd, int dcols,
    float* __restrict__ Cf, __hip_bfloat16* __restrict__ Cb, int ldc,
    int K)
{
    __shared__ float sA[16][68], sB[16][68];
    const int bj = blockIdx.x, bi = blockIdx.y;
    const int t = threadIdx.x, tx = t & 15, ty = t >> 4;
    float acc[4][4] = {};
    for (int k0 = 0; k0 < K; k0 += 16) {
        {
            int k = t & 15, m = t >> 4;
#pragma unroll
            for (int q = 0; q < 4; ++q)
                sA[k][m + q * 16] = A[(long)(bi * 64 + m + q * 16) * lda + k0 + k];
            int n = t & 63, kk = t >> 6;
#pragma unroll
            for (int q = 0; q < 4; ++q)
                sB[kk + q * 4][n] = B[(long)(k0 + kk + q * 4) * ldb + bj * 64 + n];
        }
        __syncthreads();
#pragma unroll
        for (int k = 0; k < 16; ++k) {
            f32x4 av = *(const f32x4*)&sA[k][ty * 4];
            f32x4 bv = *(const f32x4*)&sB[k][tx * 4];
#pragma unroll
            for (int i = 0; i < 4; ++i)
#pragma unroll
                for (int j = 0; j < 4; ++j)
                    acc[i][j] += av[i] * bv[j];
        }
        __syncthreads();
    }
#pragma unroll
    for (int i = 0; i < 4; ++i) {
        int r = bi * 64 + ty * 4 + i;
#pragma unroll
        for (int j = 0; j < 4; ++j) {
            int cidx = bj * 64 + tx * 4 + j;
            float v = acc[i][j];
            if (D && cidx < dcols) v += D[(long)r * ldd + cidx];
            if (Cf) Cf[(long)r * ldc + cidx] = v;
            if (Cb) Cb[(long)r * ldc + cidx] = f2bf(v);
        }
    }
}

// ---------------------------------------------------------------------------
// foldrhs: per output row r (256 blocks):
//   Wc1ff[r] = [Wc1p[r,0:64]@W_sp1 | Wc1p[r,64:128]@W_fr4 | Wc1p[r,128:256]]
//   Wa1ff[r] = [Wa1pf[r,0:64]@W_fr4 | Wa1pf[r,64:256]]  (+ bf16 copy Wa1fb)
// ---------------------------------------------------------------------------
__global__ __launch_bounds__(256) void foldrhs(
    const float* __restrict__ Wc1p, const float* __restrict__ Wa1pf,
    const float* __restrict__ W_sp1, const float* __restrict__ W_fr4,
    float* __restrict__ Wc1ff, float* __restrict__ Wa1ff,
    __hip_bfloat16* __restrict__ Wa1fb)
{
    const int r = blockIdx.x, t = threadIdx.x;
    float vc, va;
    if (t < 64) {
        float s = 0.f;
        for (int k = 0; k < 64; ++k) s += Wc1p[r * 256 + k] * W_sp1[k * 64 + t];
        vc = s;
        s = 0.f;
        for (int k = 0; k < 64; ++k) s += Wa1pf[r * 256 + k] * W_fr4[k * 64 + t];
        va = s;
    } else if (t < 128) {
        float s = 0.f;
        for (int k = 0; k < 64; ++k) s += Wc1p[r * 256 + 64 + k] * W_fr4[k * 64 + (t - 64)];
        vc = s;
        va = Wa1pf[r * 256 + t];
    } else {
        vc = Wc1p[r * 256 + t];
        va = Wa1pf[r * 256 + t];
    }
    Wc1ff[r * 256 + t] = vc;
    Wa1ff[r * 256 + t] = va;
    Wa1fb[r * 256 + t] = f2bf(va);
}

// ---------------------------------------------------------------------------
// vecfolds: one wave per output row o (1536 rows):
//  o<256:       bc1v[o]  = b_c1[o] + Wc1p[o,0:64]@b_sp1 + Wc1p[o,64:128]@b_fr4
//  256<=o<512:  b_a1p[o-256] = b_a1[·] + Wa1pf[·,0:64]@b_fr4
//  512<=o<1536: w2[o-512] = b_f[·] + W_f[·,512:1024]@b_a2
// ---------------------------------------------------------------------------
__global__ __launch_bounds__(256) void vecfolds(
    const float* __restrict__ Wc1p, const float* __restrict__ Wa1pf,
    const float* __restrict__ W_f,
    const float* __restrict__ b_sp1, const float* __restrict__ b_fr4,
    const float* __restrict__ b_c1, const float* __restrict__ b_a1,
    const float* __restrict__ b_f, const float* __restrict__ b_a2,
    float* __restrict__ bc1v, float* __restrict__ b_a1p, float* __restrict__ w2)
{
    int o = blockIdx.x * 4 + (threadIdx.x >> 6);
    int lane = threadIdx.x & 63;
    if (o >= 1536) return;
    float a = 0.f;
    if (o < 256) {
        a = Wc1p[o * 256 + lane] * b_sp1[lane] + Wc1p[o * 256 + 64 + lane] * b_fr4[lane];
    } else if (o < 512) {
        a = Wa1pf[(o - 256) * 256 + lane] * b_fr4[lane];
    } else {
        for (int k = lane; k < 512; k += 64) a += W_f[(long)(o - 512) * 1024 + 512 + k] * b_a2[k];
    }
#pragma unroll
    for (int off = 32; off > 0; off >>= 1) a += __shfl_xor(a, off);
    if (lane == 0) {
        if (o < 256)      bc1v[o] = b_c1[o] + a;
        else if (o < 512) b_a1p[o - 256] = b_a1[o - 256] + a;
        else              w2[o - 512] = b_f[o - 512] + a;
    }
}

// cvec[i] = w2@M3[i]^T + b_c2@T3[i]^T + bc1v@U1[i]^T + b_a1p@U2[i]^T
__global__ __launch_bounds__(256) void cvec_kernel(
    const float* __restrict__ W_m2,
    const float* __restrict__ T3f, const float* __restrict__ Uf,
    const float* __restrict__ w2, const float* __restrict__ b_c2,
    const float* __restrict__ bc1v, const float* __restrict__ b_a1p,
    float* __restrict__ cvec)
{
    int i = blockIdx.x * 256 + threadIdx.x;
    if (i >= 1024) return;
    float s = 0.f;
    for (int k = 0; k < 1024; ++k) s += w2[k] * W_m2[(long)i * 1792 + 768 + k];
    for (int k = 0; k < 512;  ++k) s += b_c2[k] * T3f[(long)i * 512 + k];
    for (int k = 0; k < 256;  ++k) s += bc1v[k] * Uf[(long)i * 512 + k];
    for (int k = 0; k < 256;  ++k) s += b_a1p[k] * Uf[(long)i * 512 + 256 + k];
    cvec[i] = s;
}

// ---------------------------------------------------------------------------
// featurize (light): cat1 row = [h1r | h3r | kc | nrm | 0]
// ---------------------------------------------------------------------------
__global__ __launch_bounds__(256) void featurize(
    const float* __restrict__ centre, const float* __restrict__ corner,
    const float* __restrict__ normal, const int* __restrict__ neighbour,
    const float* __restrict__ W_sp2, const float* __restrict__ b_sp2,
    const float* __restrict__ conv_w, const float* __restrict__ conv_b,
    const float* __restrict__ W_fr3, const float* __restrict__ b_fr3,
    const float* __restrict__ theta, const float* __restrict__ phi,
    __hip_bfloat16* __restrict__ cat1)
{
    __shared__ float sWsp2t[3][64];  __shared__ float sbsp2[64];
    __shared__ float sconvt[6][32];  __shared__ float sconvb[32];
    __shared__ float sWfr3t[32][64]; __shared__ float sbfr3[64];
    __shared__ float kt4x[4][64], kt4y[4][64], kt4z[4][64];

    const int tid = threadIdx.x;
    for (int i = tid; i < 2048; i += 256) { int j = i >> 5, k = i & 31; sWfr3t[k][j] = W_fr3[i]; }
    for (int i = tid; i < 192; i += 256) { int j = i / 3, k = i % 3; sWsp2t[k][j] = W_sp2[i]; }
    for (int i = tid; i < 192; i += 256) { int o = i / 6, k = i % 6; sconvt[k][o] = conv_w[i]; }
    if (tid < 64) { sbsp2[tid] = b_sp2[tid]; sbfr3[tid] = b_fr3[tid]; }
    if (tid < 32) sconvb[tid] = conv_b[tid];
    {
        int j = tid >> 2, s = tid & 3;
        float th = theta[tid], ph = phi[tid];
        float st = sinf(th), ct = cosf(th), sp = sinf(ph), cp = cosf(ph);
        kt4x[s][j] = st * sp; kt4y[s][j] = st * cp; kt4z[s][j] = ct;
    }
    __syncthreads();

    const int lane = tid & 63, wave = tid >> 6;
    for (long p = (long)blockIdx.x * 4 + wave; p < NPAD; p += (long)gridDim.x * 4) {
        __hip_bfloat16* row = cat1 + p * 256;
        if (p >= NPTS) {
            __hip_bfloat16 z = f2bf(0.f);
            row[lane] = z; row[64 + lane] = z; row[128 + lane] = z; row[192 + lane] = z;
            continue;
        }
        float cx = centre[p * 3], cy = centre[p * 3 + 1], cz = centre[p * 3 + 2];
        float h1r = fmaxf(sbsp2[lane] + cx * sWsp2t[0][lane] + cy * sWsp2t[1][lane]
                          + cz * sWsp2t[2][lane], 0.f);
        float mval = 0.f;
        if (lane < 32) {
            float c0 = corner[p*9+0], c1 = corner[p*9+1], c2 = corner[p*9+2];
            float c3 = corner[p*9+3], c4 = corner[p*9+4], c5 = corner[p*9+5];
            float c6 = corner[p*9+6], c7 = corner[p*9+7], c8 = corner[p*9+8];
            float s0 = c0 + c3 + c6, s1 = c1 + c4 + c7, s2 = c2 + c5 + c8;
            mval = sconvb[lane] + (1.f / 3.f) *
                ((sconvt[0][lane] + sconvt[3][lane]) * s0 +
                 (sconvt[1][lane] + sconvt[4][lane]) * s1 +
                 (sconvt[2][lane] + sconvt[5][lane]) * s2);
        }
        float h3 = sbfr3[lane];
#pragma unroll 8
        for (int k = 0; k < 32; ++k) h3 += __shfl(mval, k) * sWfr3t[k][lane];
        float h3r = fmaxf(h3, 0.f);
        int nb0 = clampi(neighbour[p * 3]), nb1 = clampi(neighbour[p * 3 + 1]), nb2 = clampi(neighbour[p * 3 + 2]);
        float nx[4], ny[4], nz[4];
        nx[0] = normal[p * 3];          ny[0] = normal[p * 3 + 1];          nz[0] = normal[p * 3 + 2];
        nx[1] = normal[(long)nb0 * 3];  ny[1] = normal[(long)nb0 * 3 + 1];  nz[1] = normal[(long)nb0 * 3 + 2];
        nx[2] = normal[(long)nb1 * 3];  ny[2] = normal[(long)nb1 * 3 + 1];  nz[2] = normal[(long)nb1 * 3 + 2];
        nx[3] = normal[(long)nb2 * 3];  ny[3] = normal[(long)nb2 * 3 + 1];  nz[3] = normal[(long)nb2 * 3 + 2];
        float kcs = 0.f;
#pragma unroll
        for (int s = 0; s < 4; ++s) {
            float kx = kt4x[s][lane], ky = kt4y[s][lane], kz = kt4z[s][lane];
#pragma unroll
            for (int t = 0; t < 4; ++t) {
                float dx = nx[t] - kx, dy = ny[t] - ky, dz = nz[t] - kz;
                kcs += __expf(-12.5f * (dx * dx + dy * dy + dz * dz));
            }
        }
        float kcv = kcs * (1.f / 16.f);
        float nrmv = (lane == 0) ? nx[0] : (lane == 1) ? ny[0] : (lane == 2) ? nz[0] : 0.f;
        row[lane] = f2bf(h1r); row[64 + lane] = f2bf(h3r);
        row[128 + lane] = f2bf(kcv); row[192 + lane] = f2bf(nrmv);
    }
}

// ---------------------------------------------------------------------------
// gathers
// ---------------------------------------------------------------------------
__global__ __launch_bounds__(256) void gather_agg1(
    const __hip_bfloat16* __restrict__ cat1, const int* __restrict__ neighbour,
    __hip_bfloat16* __restrict__ agg1)
{
    long p = (long)blockIdx.x * 4 + (threadIdx.x >> 6);
    int lane = threadIdx.x & 63;
    if (p >= NPAD) return;
    __hip_bfloat16* o = agg1 + p * 256;
    if (p >= NPTS) {
        __hip_bfloat16 z = f2bf(0.f);
        o[lane] = z; o[64 + lane] = z; o[128 + lane] = z; o[192 + lane] = z;
        return;
    }
    int nb0 = clampi(neighbour[p * 3]), nb1 = clampi(neighbour[p * 3 + 1]), nb2 = clampi(neighbour[p * 3 + 2]);
    const __hip_bfloat16* r0 = cat1 + p * 256 + 64;
    const __hip_bfloat16* r1 = cat1 + (long)nb0 * 256 + 64;
    const __hip_bfloat16* r2 = cat1 + (long)nb1 * 256 + 64;
    const __hip_bfloat16* r3 = cat1 + (long)nb2 * 256 + 64;
    float a = (bf2f(r0[lane]) + bf2f(r1[lane]) + bf2f(r2[lane]) + bf2f(r3[lane])) * 0.25f;
    float b = (bf2f(r0[64 + lane]) + bf2f(r1[64 + lane]) + bf2f(r2[64 + lane]) + bf2f(r3[64 + lane])) * 0.25f;
    float c = (lane < 3) ? (bf2f(r0[128 + lane]) + bf2f(r1[128 + lane]) + bf2f(r2[128 + lane]) + bf2f(r3[128 + lane])) * 0.25f : 0.f;
    o[lane] = f2bf(a); o[64 + lane] = f2bf(b); o[128 + lane] = f2bf(c); o[192 + lane] = f2bf(0.f);
}

__global__ __launch_bounds__(256) void gather_agg2(
    const __hip_bfloat16* __restrict__ out2, const int* __restrict__ neighbour,
    __hip_bfloat16* __restrict__ agg2)
{
    long p = (long)blockIdx.x * 4 + (threadIdx.x >> 6);
    int lane = threadIdx.x & 63;
    if (p >= NPAD) return;
    __hip_bfloat16* o = agg2 + p * 256;
    if (p >= NPTS) {
        __hip_bfloat16 z = f2bf(0.f);
        o[lane] = z; o[64 + lane] = z; o[128 + lane] = z; o[192 + lane] = z;
        return;
    }
    int nb0 = clampi(neighbour[p * 3]), nb1 = clampi(neighbour[p * 3 + 1]), nb2 = clampi(neighbour[p * 3 + 2]);
    const __hip_bfloat16* r0 = out2 + p * 256;
    const __hip_bfloat16* r1 = out2 + (long)nb0 * 256;
    const __hip_bfloat16* r2 = out2 + (long)nb1 * 256;
    const __hip_bfloat16* r3 = out2 + (long)nb2 * 256;
#pragma unroll
    for (int q = 0; q < 4; ++q) {
        int c = q * 64 + lane;
        o[c] = f2bf((bf2f(r0[c]) + bf2f(r1[c]) + bf2f(r2[c]) + bf2f(r3[c])) * 0.25f);
    }
}

// ---------------------------------------------------------------------------
// 128x128 bf16 MFMA GEMM core, BK=64 (two 32-col sub-buffers: same bank
// pattern as BK=32, half the barriers -> 32 MFMA per barrier pair).
// ---------------------------------------------------------------------------
__device__ __forceinline__ void gemm_core(
    const __hip_bfloat16* A0, int lda0, int k0end,
    const __hip_bfloat16* A1, int lda1, int k1end,
    const __hip_bfloat16* A2, int lda2,
    const __hip_bfloat16* B, int K,
    u16* Asm, u16* Bsm,   // each 2*128*32
    long rowbase, int colbase, int tid,
    f32x4 acc[4][4])
{
    const int lane = tid & 63, wave = tid >> 6;
    const int wr = wave >> 1, wc = wave & 1;
    const int m16 = lane & 15, kg = lane >> 4;
    for (int kt = 0; kt < K; kt += 64) {
#pragma unroll
        for (int h = 0; h < 2; ++h) {
            int kh = kt + h * 32;
            const __hip_bfloat16* Ap; long lda; int kl;
            if (kh < k0end)      { Ap = A0; lda = lda0; kl = kh; }
            else if (kh < k1end) { Ap = A1; lda = lda1; kl = kh - k0end; }
            else                 { Ap = A2; lda = lda2; kl = kh - k1end; }
#pragma unroll
            for (int i = 0; i < 2; ++i) {
                int cid = i * 256 + tid;
                int row = cid >> 2, kc = cid & 3;
                gload_lds16(Ap + (rowbase + row) * lda + kl + kc * 8, Asm + h * 4096 + cid * 8);
                gload_lds16(B + (long)(colbase + row) * K + kh + kc * 8, Bsm + h * 4096 + cid * 8);
            }
        }
        __syncthreads();
#pragma unroll
        for (int h = 0; h < 2; ++h) {
            bf16x8 af[4], bv[4];
#pragma unroll
            for (int i = 0; i < 4; ++i)
                af[i] = *(const bf16x8*)(Asm + h * 4096 + ((wr * 64 + i * 16 + m16) * 32 + kg * 8));
#pragma unroll
            for (int j = 0; j < 4; ++j)
                bv[j] = *(const bf16x8*)(Bsm + h * 4096 + ((wc * 64 + j * 16 + m16) * 32 + kg * 8));
#pragma unroll
            for (int i = 0; i < 4; ++i)
#pragma unroll
                for (int j = 0; j < 4; ++j)
                    acc[i][j] = __builtin_amdgcn_mfma_f32_16x16x32_bf16(af[i], bv[j], acc[i][j], 0, 0, 0);
        }
        __syncthreads();
    }
}

__global__ __launch_bounds__(256) void gemm_nt(
    const __hip_bfloat16* __restrict__ A0, int lda0, int k0end,
    const __hip_bfloat16* __restrict__ A1, int lda1, int k1end,
    const __hip_bfloat16* __restrict__ A2, int lda2,
    const __hip_bfloat16* __restrict__ B, int K,
    const float* __restrict__ bias,
    __hip_bfloat16* __restrict__ C, int ldc)
{
    __shared__ __align__(16) u16 Asm[2 * 128 * 32];
    __shared__ __align__(16) u16 Bsm[2 * 128 * 32];
    const int tid = threadIdx.x;
    const long rowbase = (long)blockIdx.y * 128;
    const int colbase = blockIdx.x * 128;
    f32x4 acc[4][4] = {};
    gemm_core(A0, lda0, k0end, A1, lda1, k1end, A2, lda2, B, K, Asm, Bsm, rowbase, colbase, tid, acc);
    const int lane = tid & 63, wave = tid >> 6;
    const int wr = wave >> 1, wc = wave & 1;
    const int m16 = lane & 15, q = lane >> 4;
#pragma unroll
    for (int j = 0; j < 4; ++j) {
        int col = colbase + wc * 64 + j * 16 + m16;
        float bvv = bias[col];
#pragma unroll
        for (int i = 0; i < 4; ++i)
#pragma unroll
            for (int r = 0; r < 4; ++r) {
                long rowg = rowbase + wr * 64 + i * 16 + q * 4 + r;
                C[rowg * ldc + col] = f2bf(acc[i][j][r] + bvv);
            }
    }
}

// max-GEMM, XCD-swizzled 1D grid (R6 win: keeps A row-tile in one XCD's L2)
__global__ __launch_bounds__(256) void gemm_nt_max(
    const __hip_bfloat16* __restrict__ A0, int lda0, int k0end,
    const __hip_bfloat16* __restrict__ A1, int lda1, int k1end,
    const __hip_bfloat16* __restrict__ A2, int lda2,
    const __hip_bfloat16* __restrict__ B, int K,
    unsigned* __restrict__ g_enc)
{
    __shared__ __align__(16) u16 Asm[2 * 128 * 32];
    __shared__ __align__(16) u16 Bsm[2 * 128 * 32];
    __shared__ float red[2][128];
    const int id = blockIdx.x;
    const int c = id & 7, tt = id >> 3;
    const int j8 = tt & 7, rh = tt >> 3;
    const int r = rh * 8 + c;
    if (r >= NPAD / 128) return;
    const long rowbase = (long)r * 128;
    const int colbase = j8 * 128;
    const int tid = threadIdx.x;
    f32x4 acc[4][4] = {};
    gemm_core(A0, lda0, k0end, A1, lda1, k1end, A2, lda2, B, K, Asm, Bsm, rowbase, colbase, tid, acc);
    const int lane = tid & 63, wave = tid >> 6;
    const int wr = wave >> 1, wc = wave & 1;
    const int m16 = lane & 15, q = lane >> 4;
#pragma unroll
    for (int j = 0; j < 4; ++j) {
        float m = -INFINITY;
#pragma unroll
        for (int i = 0; i < 4; ++i)
#pragma unroll
            for (int rr = 0; rr < 4; ++rr) {
                long rowg = rowbase + wr * 64 + i * 16 + q * 4 + rr;
                m = (rowg < NPTS) ? fmaxf(m, acc[i][j][rr]) : m;
            }
        m = fmaxf(m, __shfl_xor(m, 16));
        m = fmaxf(m, __shfl_xor(m, 32));
        if (lane < 16) red[wr][wc * 64 + j * 16 + m16] = m;
    }
    __syncthreads();
    if (tid < 128) {
        float v = fmaxf(red[0][tid], red[1][tid]);
        atomicMax(g_enc + colbase + tid, enc_f32(v));
    }
}

// ---------------------------------------------------------------------------
// parallel head
// ---------------------------------------------------------------------------
__global__ __launch_bounds__(256) void head_g(
    const unsigned* __restrict__ g_enc, const float* __restrict__ cvec,
    const float* __restrict__ b_m2, float* __restrict__ g)
{
    int i = blockIdx.x * 256 + threadIdx.x;
    if (i < 1024) g[i] = dec_f32(g_enc[i]) + cvec[i] + b_m2[i];
}

__global__ __launch_bounds__(256) void head_lin(
    const float* __restrict__ in, const float* __restrict__ W,
    const float* __restrict__ b, float* __restrict__ out,
    int In, int Out, int do_relu)
{
    int o = blockIdx.x * 4 + (threadIdx.x >> 6);
    int lane = threadIdx.x & 63;
    if (o >= Out) return;
    float a = 0.f;
    for (int k = lane; k < In; k += 64) a += in[k] * W[(long)o * In + k];
#pragma unroll
    for (int off = 32; off > 0; off >>= 1) a += __shfl_xor(a, off);
    if (lane == 0) {
        float v = a + b[o];
        out[o] = do_relu ? fmaxf(v, 0.f) : v;
    }
}

// ---------------------------------------------------------------------------
extern "C" void kernel_launch(void* const* d_in, const int* in_sizes, int n_in,
                              void* d_out, int out_size, void* d_ws, size_t ws_size,
                              hipStream_t stream)
{
    (void)in_sizes; (void)n_in; (void)out_size; (void)ws_size;
    const float* centre = (const float*)d_in[0];
    const float* corner = (const float*)d_in[1];
    const float* normal = (const float*)d_in[2];
    const int*   neighbour = (const int*)d_in[3];
    const float* W_sp2 = (const float*)d_in[4];
    const float* b_sp2 = (const float*)d_in[5];
    const float* W_sp1 = (const float*)d_in[6];
    const float* b_sp1 = (const float*)d_in[7];
    const float* conv_w = (const float*)d_in[8];
    const float* conv_b = (const float*)d_in[9];
    const float* W_fr3 = (const float*)d_in[10];
    const float* b_fr3 = (const float*)d_in[11];
    const float* W_fr4 = (const float*)d_in[12];
    const float* b_fr4 = (const float*)d_in[13];
    const float* theta = (const float*)d_in[14];
    const float* phi   = (const float*)d_in[15];
    const float* W_c1 = (const float*)d_in[16];
    const float* b_c1 = (const float*)d_in[17];
    const float* W_a1 = (const float*)d_in[18];
    const float* b_a1 = (const float*)d_in[19];
    const float* W_c2 = (const float*)d_in[20];
    const float* b_c2 = (const float*)d_in[21];
    const float* W_a2 = (const float*)d_in[22];
    const float* b_a2 = (const float*)d_in[23];
    const float* W_f  = (const float*)d_in[24];
    const float* b_f  = (const float*)d_in[25];
    const float* W_m2 = (const float*)d_in[26];
    const float* b_m2 = (const float*)d_in[27];
    const float* W_m31 = (const float*)d_in[28];
    const float* b_m31 = (const float*)d_in[29];
    const float* W_m32 = (const float*)d_in[30];
    const float* b_m32 = (const float*)d_in[31];
    const float* W_m33 = (const float*)d_in[32];
    const float* b_m33 = (const float*)d_in[33];

    char* ws = (char*)d_ws;
    size_t off = 0;
    auto alloc = [&](size_t bytes) { void* p = ws + off; off += (bytes + 255) & ~(size_t)255; return p; };
    __hip_bfloat16* cat1  = (__hip_bfloat16*)alloc((size_t)NPAD * 256 * 2);
    __hip_bfloat16* agg1  = (__hip_bfloat16*)alloc((size_t)NPAD * 256 * 2);
    __hip_bfloat16* out2  = (__hip_bfloat16*)alloc((size_t)NPAD * 256 * 2);
    __hip_bfloat16* agg2  = (__hip_bfloat16*)alloc((size_t)NPAD * 256 * 2);
    float* Wc1p  = (float*)alloc((size_t)65536 * 4);
    float* Wa1pf = (float*)alloc((size_t)65536 * 4);
    float* Wc1ff = (float*)alloc((size_t)65536 * 4);
    float* Wa1ff = (float*)alloc((size_t)65536 * 4);
    __hip_bfloat16* Wa1fb = (__hip_bfloat16*)alloc((size_t)65536 * 2);
    __hip_bfloat16* Xw    = (__hip_bfloat16*)alloc((size_t)1024 * 768 * 2);  // [X1'|X2'|V]
    float* T3f  = (float*)alloc((size_t)1024 * 512 * 4);
    float* Uf   = (float*)alloc((size_t)1024 * 512 * 4);                     // [U1|U2]
    float* B2f  = (float*)alloc((size_t)1024 * 256 * 4);
    float* bc1v = (float*)alloc(256 * 4);
    float* b_a1p = (float*)alloc(256 * 4);
    float* w2   = (float*)alloc(1024 * 4);
    float* cvec = (float*)alloc(1024 * 4);
    unsigned* g_enc = (unsigned*)alloc(1024 * 4);
    float* gvec = (float*)alloc(1024 * 4);
    float* h1   = (float*)alloc(512 * 4);
    float* h2   = (float*)alloc(256 * 4);

    prep<<<516, 256, 0, stream>>>(W_c1, W_a1, Wc1p, Wa1pf, g_enc);

    // ---- weight collapse, fold-first (2.96 GF, 10 launches) ----
    // T3 = M3@Wfa + M2   (1024x512)
    wgemm64<<<dim3(8, 16), 256, 0, stream>>>(W_m2 + 768, 1792, W_f, 1024,
        W_m2 + 256, 1792, 512, T3f, (__hip_bfloat16*)nullptr, 512, 1024);
    // U = [U1|U2] = T3@W_c2 + [M1|0]  (1024x512)
    wgemm64<<<dim3(8, 16), 256, 0, stream>>>(T3f, 512, W_c2, 512,
        W_m2, 1792, 256, Uf, (__hip_bfloat16*)nullptr, 512, 512);
    // Wc1f / Wa1f: fold Wsp1/Wfr4 into the 256x256 RHS matrices
    foldrhs<<<256, 256, 0, stream>>>(Wc1p, Wa1pf, W_sp1, W_fr4, Wc1ff, Wa1ff, Wa1fb);
    // X1' = U1@Wc1f ; X2' = U2@Wa1f   -> Xw bf16 directly
    wgemm64<<<dim3(4, 16), 256, 0, stream>>>(Uf, 512, Wc1ff, 256,
        (const float*)nullptr, 0, 0, (float*)nullptr, Xw, 768, 256);
    wgemm64<<<dim3(4, 16), 256, 0, stream>>>(Uf + 256, 512, Wa1ff, 256,
        (const float*)nullptr, 0, 0, (float*)nullptr, Xw + 256, 768, 256);
    // B2' = Wfb@W_a2 (1024x256) ; V = M3@B2' -> Xw+512 bf16
    wgemm64<<<dim3(4, 16), 256, 0, stream>>>(W_f + 512, 1024, W_a2, 256,
        (const float*)nullptr, 0, 0, B2f, (__hip_bfloat16*)nullptr, 256, 512);
    wgemm64<<<dim3(4, 16), 256, 0, stream>>>(W_m2 + 768, 1792, B2f, 256,
        (const float*)nullptr, 0, 0, (float*)nullptr, Xw + 512, 768, 1024);
    // bias vector folds + cvec
    vecfolds<<<384, 256, 0, stream>>>(Wc1p, Wa1pf, W_f, b_sp1, b_fr4,
        b_c1, b_a1, b_f, b_a2, bc1v, b_a1p, w2);
    cvec_kernel<<<4, 256, 0, stream>>>(W_m2, T3f, Uf, w2, b_c2, bc1v, b_a1p, cvec);

    // ---- per-point path ----
    featurize<<<2048, 256, 0, stream>>>(centre, corner, normal, neighbour,
        W_sp2, b_sp2, conv_w, conv_b, W_fr3, b_fr3, theta, phi, cat1);
    gather_agg1<<<NPAD / 4, 256, 0, stream>>>(cat1, neighbour, agg1);
    // out2 = agg1' @ Wa1f^T + b_a1'
    gemm_nt<<<dim3(2, NPAD / 128), 256, 0, stream>>>(agg1, 256, 256, agg1, 256, 256, agg1, 256,
                                                     Wa1fb, 256, b_a1p, out2, 256);
    gather_agg2<<<NPAD / 4, 256, 0, stream>>>(out2, neighbour, agg2);
    // g = max_n([cat1'|agg1'|agg2] @ Xw^T), XCD-swizzled grid
    gemm_nt_max<<<3136, 256, 0, stream>>>(cat1, 256, 256, agg1, 256, 512, agg2, 256,
                                          Xw, 768, g_enc);
    // ---- head ----
    head_g<<<4, 256, 0, stream>>>(g_enc, cvec, b_m2, gvec);
    head_lin<<<128, 256, 0, stream>>>(gvec, W_m31, b_m31, h1, 1024, 512, 1);
    head_lin<<<64, 256, 0, stream>>>(h1, W_m32, b_m32, h2, 512, 256, 1);
    head_lin<<<10, 256, 0, stream>>>(h2, W_m33, b_m33, (float*)d_out, 256, 40, 0);
}

// Round 9
// 505.050 us; speedup vs baseline: 1.6052x; 1.2089x over previous
//
#include <hip/hip_runtime.h>
#include <hip/hip_bf16.h>
#include <stdint.h>

#define NPTS 50000
#define NPAD 50048   // 391 * 128 row tiles

typedef unsigned short u16;
typedef __attribute__((ext_vector_type(8))) __bf16 bf16x8;
typedef __attribute__((ext_vector_type(4))) float f32x4;

__device__ __forceinline__ float bf2f(__hip_bfloat16 v) { return __bfloat162float(v); }
__device__ __forceinline__ __hip_bfloat16 f2bf(float v) { return __float2bfloat16(v); }
__device__ __forceinline__ float bfbits2f(unsigned short u) { return __uint_as_float(((unsigned)u) << 16); }
__device__ __forceinline__ unsigned short f2bfbits(float f) {
    __hip_bfloat16 h = f2bf(f);
    return *(unsigned short*)&h;
}
__device__ __forceinline__ int clampi(int v) { return v < 0 ? 0 : (v >= NPTS ? NPTS - 1 : v); }

__device__ __forceinline__ unsigned enc_f32(float f) {
    unsigned b = __float_as_uint(f);
    return (b & 0x80000000u) ? ~b : (b | 0x80000000u);
}
__device__ __forceinline__ float dec_f32(unsigned u) {
    return (u & 0x80000000u) ? __uint_as_float(u & 0x7fffffffu) : __uint_as_float(~u);
}

__device__ __forceinline__ void gload_lds16(const void* g, void* l) {
    __builtin_amdgcn_global_load_lds((__attribute__((address_space(1))) void*)g,
                                     (__attribute__((address_space(3))) void*)l, 16, 0, 0);
}

// ---------------------------------------------------------------------------
// prep: zero-pad W_c1 (256x195)->fp32, W_a1 (256x131)->fp32; g_enc=-inf
// ---------------------------------------------------------------------------
__global__ __launch_bounds__(256) void prep(
    const float* __restrict__ W_c1, const float* __restrict__ W_a1,
    float* __restrict__ Wc1p, float* __restrict__ Wa1pf,
    unsigned* __restrict__ g_enc)
{
    int i = blockIdx.x * 256 + threadIdx.x;
    if (i < 65536) {
        int o = i >> 8, k = i & 255;
        Wc1p[i] = (k < 195) ? W_c1[o * 195 + k] : 0.f;
    } else if (i < 131072) {
        int t = i - 65536;
        int o = t >> 8, k = t & 255;
        Wa1pf[t] = (k < 131) ? W_a1[o * 131 + k] : 0.f;
    } else if (i < 132096) {
        g_enc[i - 131072] = 0x007FFFFFu;   // enc(-inf)
    }
}

// ---------------------------------------------------------------------------
// wg_body: 64x64-tile fp32 GEMM body. C = A@B (+ D on cols<dcols); stores
// guarded by cidx<ncols.
// ---------------------------------------------------------------------------
__device__ __forceinline__ void wg_body(
    const float* A, int lda, const float* B, int ldb,
    const float* D, int ldd, int dcols,
    float* Cf, __hip_bfloat16* Cb, int ldc, int K, int ncols,
    int bj, int bi, int t, float (*sA)[68], float (*sB)[68])
{
    const int tx = t & 15, ty = t >> 4;
    float acc[4][4] = {};
    for (int k0 = 0; k0 < K; k0 += 16) {
        {
            int k = t & 15, m = t >> 4;
#pragma unroll
            for (int q = 0; q < 4; ++q)
                sA[k][m + q * 16] = A[(long)(bi * 64 + m + q * 16) * lda + k0 + k];
            int n = t & 63, kk = t >> 6;
#pragma unroll
            for (int q = 0; q < 4; ++q)
                sB[kk + q * 4][n] = B[(long)(k0 + kk + q * 4) * ldb + bj * 64 + n];
        }
        __syncthreads();
#pragma unroll
        for (int k = 0; k < 16; ++k) {
            f32x4 av = *(const f32x4*)&sA[k][ty * 4];
            f32x4 bv = *(const f32x4*)&sB[k][tx * 4];
#pragma unroll
            for (int i = 0; i < 4; ++i)
#pragma unroll
                for (int j = 0; j < 4; ++j)
                    acc[i][j] += av[i] * bv[j];
        }
        __syncthreads();
    }
#pragma unroll
    for (int i = 0; i < 4; ++i) {
        int r = bi * 64 + ty * 4 + i;
#pragma unroll
        for (int j = 0; j < 4; ++j) {
            int cidx = bj * 64 + tx * 4 + j;
            if (cidx >= ncols) continue;
            float v = acc[i][j];
            if (D && cidx < dcols) v += D[(long)r * ldd + cidx];
            if (Cf) Cf[(long)r * ldc + cidx] = v;
            if (Cb) Cb[(long)r * ldc + cidx] = f2bf(v);
        }
    }
}

// two independent GEMMs in one launch (block-range dispatch on blockIdx.x)
__global__ __launch_bounds__(256) void wgemm64b(
    const float* A0, int lda0, const float* B0, int ldb0,
    const float* D0, int ldd0, int dcols0,
    float* Cf0, __hip_bfloat16* Cb0, int ldc0, int K0, int nbj0, int ncols0,
    const float* A1, int lda1, const float* B1, int ldb1,
    const float* D1, int ldd1, int dcols1,
    float* Cf1, __hip_bfloat16* Cb1, int ldc1, int K1, int ncols1)
{
    __shared__ float sA[16][68], sB[16][68];
    const int bx = blockIdx.x, bi = blockIdx.y, t = threadIdx.x;
    if (bx < nbj0)
        wg_body(A0, lda0, B0, ldb0, D0, ldd0, dcols0, Cf0, Cb0, ldc0, K0, ncols0, bx, bi, t, sA, sB);
    else
        wg_body(A1, lda1, B1, ldb1, D1, ldd1, dcols1, Cf1, Cb1, ldc1, K1, ncols1, bx - nbj0, bi, t, sA, sB);
}

// ---------------------------------------------------------------------------
// foldrhs: per output row r (256 blocks):
//   Wc1ff[r] = [Wc1p[r,0:64]@W_sp1 | Wc1p[r,64:128]@W_fr4 | Wc1p[r,128:256]]
//   Wa1ff[r] = [Wa1pf[r,0:64]@W_fr4 | Wa1pf[r,64:256]]
//   Wa1fb = bf16 copy of Wa1ff cols 0:160 (ld 160)
// ---------------------------------------------------------------------------
__global__ __launch_bounds__(256) void foldrhs(
    const float* __restrict__ Wc1p, const float* __restrict__ Wa1pf,
    const float* __restrict__ W_sp1, const float* __restrict__ W_fr4,
    float* __restrict__ Wc1ff, float* __restrict__ Wa1ff,
    __hip_bfloat16* __restrict__ Wa1fb)
{
    const int r = blockIdx.x, t = threadIdx.x;
    float vc, va;
    if (t < 64) {
        float s = 0.f;
        for (int k = 0; k < 64; ++k) s += Wc1p[r * 256 + k] * W_sp1[k * 64 + t];
        vc = s;
        s = 0.f;
        for (int k = 0; k < 64; ++k) s += Wa1pf[r * 256 + k] * W_fr4[k * 64 + t];
        va = s;
    } else if (t < 128) {
        float s = 0.f;
        for (int k = 0; k < 64; ++k) s += Wc1p[r * 256 + 64 + k] * W_fr4[k * 64 + (t - 64)];
        vc = s;
        va = Wa1pf[r * 256 + t];
    } else {
        vc = Wc1p[r * 256 + t];
        va = Wa1pf[r * 256 + t];
    }
    Wc1ff[r * 256 + t] = vc;
    Wa1ff[r * 256 + t] = va;
    if (t < 160) Wa1fb[r * 160 + t] = f2bf(va);
}

// ---------------------------------------------------------------------------
// vecfolds: one wave per output row o (1536 rows)
// ---------------------------------------------------------------------------
__global__ __launch_bounds__(256) void vecfolds(
    const float* __restrict__ Wc1p, const float* __restrict__ Wa1pf,
    const float* __restrict__ W_f,
    const float* __restrict__ b_sp1, const float* __restrict__ b_fr4,
    const float* __restrict__ b_c1, const float* __restrict__ b_a1,
    const float* __restrict__ b_f, const float* __restrict__ b_a2,
    float* __restrict__ bc1v, float* __restrict__ b_a1p, float* __restrict__ w2)
{
    int o = blockIdx.x * 4 + (threadIdx.x >> 6);
    int lane = threadIdx.x & 63;
    if (o >= 1536) return;
    float a = 0.f;
    if (o < 256) {
        a = Wc1p[o * 256 + lane] * b_sp1[lane] + Wc1p[o * 256 + 64 + lane] * b_fr4[lane];
    } else if (o < 512) {
        a = Wa1pf[(o - 256) * 256 + lane] * b_fr4[lane];
    } else {
        for (int k = lane; k < 512; k += 64) a += W_f[(long)(o - 512) * 1024 + 512 + k] * b_a2[k];
    }
#pragma unroll
    for (int off = 32; off > 0; off >>= 1) a += __shfl_xor(a, off);
    if (lane == 0) {
        if (o < 256)      bc1v[o] = b_c1[o] + a;
        else if (o < 512) b_a1p[o - 256] = b_a1[o - 256] + a;
        else              w2[o - 512] = b_f[o - 512] + a;
    }
}

// cvec: one wave per row i, lane-strided k (coalesced row reads)
__global__ __launch_bounds__(256) void cvec_kernel(
    const float* __restrict__ W_m2,
    const float* __restrict__ T3f, const float* __restrict__ Uf,
    const float* __restrict__ w2, const float* __restrict__ b_c2,
    const float* __restrict__ bc1v, const float* __restrict__ b_a1p,
    float* __restrict__ cvec)
{
    int i = blockIdx.x * 4 + (threadIdx.x >> 6);
    int lane = threadIdx.x & 63;
    if (i >= 1024) return;
    const float* m3row = W_m2 + (long)i * 1792 + 768;
    float a = 0.f;
    for (int k = lane; k < 1024; k += 64) a += w2[k] * m3row[k];
    for (int k = lane; k < 512;  k += 64) a += b_c2[k] * T3f[(long)i * 512 + k];
    for (int k = lane; k < 256;  k += 64) a += bc1v[k] * Uf[(long)i * 512 + k];
    for (int k = lane; k < 256;  k += 64) a += b_a1p[k] * Uf[(long)i * 512 + 256 + k];
#pragma unroll
    for (int off = 32; off > 0; off >>= 1) a += __shfl_xor(a, off);
    if (lane == 0) cvec[i] = a;
}

// ---------------------------------------------------------------------------
// featurize: cat1 row (ld 224) = [h1r(64) | h3r(64) | kc(64) | nrm(3)+pad(29)]
// ---------------------------------------------------------------------------
__global__ __launch_bounds__(256) void featurize(
    const float* __restrict__ centre, const float* __restrict__ corner,
    const float* __restrict__ normal, const int* __restrict__ neighbour,
    const float* __restrict__ W_sp2, const float* __restrict__ b_sp2,
    const float* __restrict__ conv_w, const float* __restrict__ conv_b,
    const float* __restrict__ W_fr3, const float* __restrict__ b_fr3,
    const float* __restrict__ theta, const float* __restrict__ phi,
    __hip_bfloat16* __restrict__ cat1)
{
    __shared__ float sWsp2t[3][64];  __shared__ float sbsp2[64];
    __shared__ float sconvt[6][32];  __shared__ float sconvb[32];
    __shared__ float sWfr3t[32][64]; __shared__ float sbfr3[64];
    __shared__ float kt4x[4][64], kt4y[4][64], kt4z[4][64];

    const int tid = threadIdx.x;
    for (int i = tid; i < 2048; i += 256) { int j = i >> 5, k = i & 31; sWfr3t[k][j] = W_fr3[i]; }
    for (int i = tid; i < 192; i += 256) { int j = i / 3, k = i % 3; sWsp2t[k][j] = W_sp2[i]; }
    for (int i = tid; i < 192; i += 256) { int o = i / 6, k = i % 6; sconvt[k][o] = conv_w[i]; }
    if (tid < 64) { sbsp2[tid] = b_sp2[tid]; sbfr3[tid] = b_fr3[tid]; }
    if (tid < 32) sconvb[tid] = conv_b[tid];
    {
        int j = tid >> 2, s = tid & 3;
        float th = theta[tid], ph = phi[tid];
        float st = sinf(th), ct = cosf(th), sp = sinf(ph), cp = cosf(ph);
        kt4x[s][j] = st * sp; kt4y[s][j] = st * cp; kt4z[s][j] = ct;
    }
    __syncthreads();

    const int lane = tid & 63, wave = tid >> 6;
    for (long p = (long)blockIdx.x * 4 + wave; p < NPAD; p += (long)gridDim.x * 4) {
        __hip_bfloat16* row = cat1 + p * 224;
        if (p >= NPTS) {
            __hip_bfloat16 z = f2bf(0.f);
            row[lane] = z; row[64 + lane] = z; row[128 + lane] = z;
            if (lane < 32) row[192 + lane] = z;
            continue;
        }
        float cx = centre[p * 3], cy = centre[p * 3 + 1], cz = centre[p * 3 + 2];
        float h1r = fmaxf(sbsp2[lane] + cx * sWsp2t[0][lane] + cy * sWsp2t[1][lane]
                          + cz * sWsp2t[2][lane], 0.f);
        float mval = 0.f;
        if (lane < 32) {
            float c0 = corner[p*9+0], c1 = corner[p*9+1], c2 = corner[p*9+2];
            float c3 = corner[p*9+3], c4 = corner[p*9+4], c5 = corner[p*9+5];
            float c6 = corner[p*9+6], c7 = corner[p*9+7], c8 = corner[p*9+8];
            float s0 = c0 + c3 + c6, s1 = c1 + c4 + c7, s2 = c2 + c5 + c8;
            mval = sconvb[lane] + (1.f / 3.f) *
                ((sconvt[0][lane] + sconvt[3][lane]) * s0 +
                 (sconvt[1][lane] + sconvt[4][lane]) * s1 +
                 (sconvt[2][lane] + sconvt[5][lane]) * s2);
        }
        float h3 = sbfr3[lane];
#pragma unroll 8
        for (int k = 0; k < 32; ++k) h3 += __shfl(mval, k) * sWfr3t[k][lane];
        float h3r = fmaxf(h3, 0.f);
        int nb0 = clampi(neighbour[p * 3]), nb1 = clampi(neighbour[p * 3 + 1]), nb2 = clampi(neighbour[p * 3 + 2]);
        float nx[4], ny[4], nz[4];
        nx[0] = normal[p * 3];          ny[0] = normal[p * 3 + 1];          nz[0] = normal[p * 3 + 2];
        nx[1] = normal[(long)nb0 * 3];  ny[1] = normal[(long)nb0 * 3 + 1];  nz[1] = normal[(long)nb0 * 3 + 2];
        nx[2] = normal[(long)nb1 * 3];  ny[2] = normal[(long)nb1 * 3 + 1];  nz[2] = normal[(long)nb1 * 3 + 2];
        nx[3] = normal[(long)nb2 * 3];  ny[3] = normal[(long)nb2 * 3 + 1];  nz[3] = normal[(long)nb2 * 3 + 2];
        float kcs = 0.f;
#pragma unroll
        for (int s = 0; s < 4; ++s) {
            float kx = kt4x[s][lane], ky = kt4y[s][lane], kz = kt4z[s][lane];
#pragma unroll
            for (int t = 0; t < 4; ++t) {
                float dx = nx[t] - kx, dy = ny[t] - ky, dz = nz[t] - kz;
                kcs += __expf(-12.5f * (dx * dx + dy * dy + dz * dz));
            }
        }
        float kcv = kcs * (1.f / 16.f);
        row[lane] = f2bf(h1r); row[64 + lane] = f2bf(h3r); row[128 + lane] = f2bf(kcv);
        if (lane < 32) {
            float nrmv = (lane == 0) ? nx[0] : (lane == 1) ? ny[0] : (lane == 2) ? nz[0] : 0.f;
            row[192 + lane] = f2bf(nrmv);
        }
    }
}

// ---------------------------------------------------------------------------
// gathers (ushort4-vectorized, one wave per point)
// ---------------------------------------------------------------------------
__global__ __launch_bounds__(256) void gather_agg1(
    const __hip_bfloat16* __restrict__ cat1, const int* __restrict__ neighbour,
    __hip_bfloat16* __restrict__ agg1)
{
    long p = (long)blockIdx.x * 4 + (threadIdx.x >> 6);
    int lane = threadIdx.x & 63;
    if (p >= NPAD || lane >= 40) return;
    ushort4* o = (ushort4*)(agg1 + p * 160);
    if (p >= NPTS) { o[lane] = make_ushort4(0, 0, 0, 0); return; }
    int nb0 = clampi(neighbour[p * 3]), nb1 = clampi(neighbour[p * 3 + 1]), nb2 = clampi(neighbour[p * 3 + 2]);
    ushort4 a = ((const ushort4*)(cat1 + p * 224 + 64))[lane];
    ushort4 b = ((const ushort4*)(cat1 + (long)nb0 * 224 + 64))[lane];
    ushort4 c = ((const ushort4*)(cat1 + (long)nb1 * 224 + 64))[lane];
    ushort4 d = ((const ushort4*)(cat1 + (long)nb2 * 224 + 64))[lane];
    ushort4 r;
    r.x = f2bfbits((bfbits2f(a.x) + bfbits2f(b.x) + bfbits2f(c.x) + bfbits2f(d.x)) * 0.25f);
    r.y = f2bfbits((bfbits2f(a.y) + bfbits2f(b.y) + bfbits2f(c.y) + bfbits2f(d.y)) * 0.25f);
    r.z = f2bfbits((bfbits2f(a.z) + bfbits2f(b.z) + bfbits2f(c.z) + bfbits2f(d.z)) * 0.25f);
    r.w = f2bfbits((bfbits2f(a.w) + bfbits2f(b.w) + bfbits2f(c.w) + bfbits2f(d.w)) * 0.25f);
    o[lane] = r;
}

__global__ __launch_bounds__(256) void gather_agg2(
    const __hip_bfloat16* __restrict__ out2, const int* __restrict__ neighbour,
    __hip_bfloat16* __restrict__ agg2)
{
    long p = (long)blockIdx.x * 4 + (threadIdx.x >> 6);
    int lane = threadIdx.x & 63;
    if (p >= NPAD) return;
    ushort4* o = (ushort4*)(agg2 + p * 256);
    if (p >= NPTS) { o[lane] = make_ushort4(0, 0, 0, 0); return; }
    int nb0 = clampi(neighbour[p * 3]), nb1 = clampi(neighbour[p * 3 + 1]), nb2 = clampi(neighbour[p * 3 + 2]);
    ushort4 a = ((const ushort4*)(out2 + p * 256))[lane];
    ushort4 b = ((const ushort4*)(out2 + (long)nb0 * 256))[lane];
    ushort4 c = ((const ushort4*)(out2 + (long)nb1 * 256))[lane];
    ushort4 d = ((const ushort4*)(out2 + (long)nb2 * 256))[lane];
    ushort4 r;
    r.x = f2bfbits((bfbits2f(a.x) + bfbits2f(b.x) + bfbits2f(c.x) + bfbits2f(d.x)) * 0.25f);
    r.y = f2bfbits((bfbits2f(a.y) + bfbits2f(b.y) + bfbits2f(c.y) + bfbits2f(d.y)) * 0.25f);
    r.z = f2bfbits((bfbits2f(a.z) + bfbits2f(b.z) + bfbits2f(c.z) + bfbits2f(d.z)) * 0.25f);
    r.w = f2bfbits((bfbits2f(a.w) + bfbits2f(b.w) + bfbits2f(c.w) + bfbits2f(d.w)) * 0.25f);
    o[lane] = r;
}

// ---------------------------------------------------------------------------
// 128x128 bf16 MFMA GEMM core, BK=64 with K-tail-32 support.
// ---------------------------------------------------------------------------
__device__ __forceinline__ void gemm_core(
    const __hip_bfloat16* A0, int lda0, int k0end,
    const __hip_bfloat16* A1, int lda1, int k1end,
    const __hip_bfloat16* A2, int lda2,
    const __hip_bfloat16* B, int K,
    u16* Asm, u16* Bsm,   // each 2*128*32
    long rowbase, int colbase, int tid,
    f32x4 acc[4][4])
{
    const int lane = tid & 63, wave = tid >> 6;
    const int wr = wave >> 1, wc = wave & 1;
    const int m16 = lane & 15, kg = lane >> 4;
    for (int kt = 0; kt < K; kt += 64) {
        const bool has2 = (kt + 32 < K);
#pragma unroll
        for (int h = 0; h < 2; ++h) {
            if (h == 1 && !has2) break;
            int kh = kt + h * 32;
            const __hip_bfloat16* Ap; long lda; int kl;
            if (kh < k0end)      { Ap = A0; lda = lda0; kl = kh; }
            else if (kh < k1end) { Ap = A1; lda = lda1; kl = kh - k0end; }
            else                 { Ap = A2; lda = lda2; kl = kh - k1end; }
#pragma unroll
            for (int i = 0; i < 2; ++i) {
                int cid = i * 256 + tid;
                int row = cid >> 2, kc = cid & 3;
                gload_lds16(Ap + (rowbase + row) * lda + kl + kc * 8, Asm + h * 4096 + cid * 8);
                gload_lds16(B + (long)(colbase + row) * K + kh + kc * 8, Bsm + h * 4096 + cid * 8);
            }
        }
        __syncthreads();
#pragma unroll
        for (int h = 0; h < 2; ++h) {
            if (h == 1 && !has2) break;
            bf16x8 af[4], bv[4];
#pragma unroll
            for (int i = 0; i < 4; ++i)
                af[i] = *(const bf16x8*)(Asm + h * 4096 + ((wr * 64 + i * 16 + m16) * 32 + kg * 8));
#pragma unroll
            for (int j = 0; j < 4; ++j)
                bv[j] = *(const bf16x8*)(Bsm + h * 4096 + ((wc * 64 + j * 16 + m16) * 32 + kg * 8));
#pragma unroll
            for (int i = 0; i < 4; ++i)
#pragma unroll
                for (int j = 0; j < 4; ++j)
                    acc[i][j] = __builtin_amdgcn_mfma_f32_16x16x32_bf16(af[i], bv[j], acc[i][j], 0, 0, 0);
        }
        __syncthreads();
    }
}

__global__ __launch_bounds__(256) void gemm_nt(
    const __hip_bfloat16* __restrict__ A0, int lda0, int k0end,
    const __hip_bfloat16* __restrict__ A1, int lda1, int k1end,
    const __hip_bfloat16* __restrict__ A2, int lda2,
    const __hip_bfloat16* __restrict__ B, int K,
    const float* __restrict__ bias,
    __hip_bfloat16* __restrict__ C, int ldc)
{
    __shared__ __align__(16) u16 Asm[2 * 128 * 32];
    __shared__ __align__(16) u16 Bsm[2 * 128 * 32];
    const int tid = threadIdx.x;
    const long rowbase = (long)blockIdx.y * 128;
    const int colbase = blockIdx.x * 128;
    f32x4 acc[4][4] = {};
    gemm_core(A0, lda0, k0end, A1, lda1, k1end, A2, lda2, B, K, Asm, Bsm, rowbase, colbase, tid, acc);
    const int lane = tid & 63, wave = tid >> 6;
    const int wr = wave >> 1, wc = wave & 1;
    const int m16 = lane & 15, q = lane >> 4;
#pragma unroll
    for (int j = 0; j < 4; ++j) {
        int col = colbase + wc * 64 + j * 16 + m16;
        float bvv = bias[col];
#pragma unroll
        for (int i = 0; i < 4; ++i)
#pragma unroll
            for (int r = 0; r < 4; ++r) {
                long rowg = rowbase + wr * 64 + i * 16 + q * 4 + r;
                C[rowg * ldc + col] = f2bf(acc[i][j][r] + bvv);
            }
    }
}

// max-GEMM, XCD-swizzled 1D grid (keeps A row-tile in one XCD's L2)
__global__ __launch_bounds__(256) void gemm_nt_max(
    const __hip_bfloat16* __restrict__ A0, int lda0, int k0end,
    const __hip_bfloat16* __restrict__ A1, int lda1, int k1end,
    const __hip_bfloat16* __restrict__ A2, int lda2,
    const __hip_bfloat16* __restrict__ B, int K,
    unsigned* __restrict__ g_enc)
{
    __shared__ __align__(16) u16 Asm[2 * 128 * 32];
    __shared__ __align__(16) u16 Bsm[2 * 128 * 32];
    __shared__ float red[2][128];
    const int id = blockIdx.x;
    const int c = id & 7, tt = id >> 3;
    const int j8 = tt & 7, rh = tt >> 3;
    const int r = rh * 8 + c;
    if (r >= NPAD / 128) return;
    const long rowbase = (long)r * 128;
    const int colbase = j8 * 128;
    const int tid = threadIdx.x;
    f32x4 acc[4][4] = {};
    gemm_core(A0, lda0, k0end, A1, lda1, k1end, A2, lda2, B, K, Asm, Bsm, rowbase, colbase, tid, acc);
    const int lane = tid & 63, wave = tid >> 6;
    const int wr = wave >> 1, wc = wave & 1;
    const int m16 = lane & 15, q = lane >> 4;
#pragma unroll
    for (int j = 0; j < 4; ++j) {
        float m = -INFINITY;
#pragma unroll
        for (int i = 0; i < 4; ++i)
#pragma unroll
            for (int rr = 0; rr < 4; ++rr) {
                long rowg = rowbase + wr * 64 + i * 16 + q * 4 + rr;
                m = (rowg < NPTS) ? fmaxf(m, acc[i][j][rr]) : m;
            }
        m = fmaxf(m, __shfl_xor(m, 16));
        m = fmaxf(m, __shfl_xor(m, 32));
        if (lane < 16) red[wr][wc * 64 + j * 16 + m16] = m;
    }
    __syncthreads();
    if (tid < 128) {
        float v = fmaxf(red[0][tid], red[1][tid]);
        atomicMax(g_enc + colbase + tid, enc_f32(v));
    }
}

// ---------------------------------------------------------------------------
// parallel head
// ---------------------------------------------------------------------------
__global__ __launch_bounds__(256) void head_g(
    const unsigned* __restrict__ g_enc, const float* __restrict__ cvec,
    const float* __restrict__ b_m2, float* __restrict__ g)
{
    int i = blockIdx.x * 256 + threadIdx.x;
    if (i < 1024) g[i] = dec_f32(g_enc[i]) + cvec[i] + b_m2[i];
}

__global__ __launch_bounds__(256) void head_lin(
    const float* __restrict__ in, const float* __restrict__ W,
    const float* __restrict__ b, float* __restrict__ out,
    int In, int Out, int do_relu)
{
    int o = blockIdx.x * 4 + (threadIdx.x >> 6);
    int lane = threadIdx.x & 63;
    if (o >= Out) return;
    float a = 0.f;
    for (int k = lane; k < In; k += 64) a += in[k] * W[(long)o * In + k];
#pragma unroll
    for (int off = 32; off > 0; off >>= 1) a += __shfl_xor(a, off);
    if (lane == 0) {
        float v = a + b[o];
        out[o] = do_relu ? fmaxf(v, 0.f) : v;
    }
}

// ---------------------------------------------------------------------------
extern "C" void kernel_launch(void* const* d_in, const int* in_sizes, int n_in,
                              void* d_out, int out_size, void* d_ws, size_t ws_size,
                              hipStream_t stream)
{
    (void)in_sizes; (void)n_in; (void)out_size; (void)ws_size;
    const float* centre = (const float*)d_in[0];
    const float* corner = (const float*)d_in[1];
    const float* normal = (const float*)d_in[2];
    const int*   neighbour = (const int*)d_in[3];
    const float* W_sp2 = (const float*)d_in[4];
    const float* b_sp2 = (const float*)d_in[5];
    const float* W_sp1 = (const float*)d_in[6];
    const float* b_sp1 = (const float*)d_in[7];
    const float* conv_w = (const float*)d_in[8];
    const float* conv_b = (const float*)d_in[9];
    const float* W_fr3 = (const float*)d_in[10];
    const float* b_fr3 = (const float*)d_in[11];
    const float* W_fr4 = (const float*)d_in[12];
    const float* b_fr4 = (const float*)d_in[13];
    const float* theta = (const float*)d_in[14];
    const float* phi   = (const float*)d_in[15];
    const float* W_c1 = (const float*)d_in[16];
    const float* b_c1 = (const float*)d_in[17];
    const float* W_a1 = (const float*)d_in[18];
    const float* b_a1 = (const float*)d_in[19];
    const float* W_c2 = (const float*)d_in[20];
    const float* b_c2 = (const float*)d_in[21];
    const float* W_a2 = (const float*)d_in[22];
    const float* b_a2 = (const float*)d_in[23];
    const float* W_f  = (const float*)d_in[24];
    const float* b_f  = (const float*)d_in[25];
    const float* W_m2 = (const float*)d_in[26];
    const float* b_m2 = (const float*)d_in[27];
    const float* W_m31 = (const float*)d_in[28];
    const float* b_m31 = (const float*)d_in[29];
    const float* W_m32 = (const float*)d_in[30];
    const float* b_m32 = (const float*)d_in[31];
    const float* W_m33 = (const float*)d_in[32];
    const float* b_m33 = (const float*)d_in[33];

    char* ws = (char*)d_ws;
    size_t off = 0;
    auto alloc = [&](size_t bytes) { void* p = ws + off; off += (bytes + 255) & ~(size_t)255; return p; };
    __hip_bfloat16* cat1  = (__hip_bfloat16*)alloc((size_t)NPAD * 224 * 2);  // [h1r|h3r|kc|nrm+pad]
    __hip_bfloat16* agg1  = (__hip_bfloat16*)alloc((size_t)NPAD * 160 * 2);  // avg [h3r|kc|nrm+pad]
    __hip_bfloat16* out2  = (__hip_bfloat16*)alloc((size_t)NPAD * 256 * 2);
    __hip_bfloat16* agg2  = (__hip_bfloat16*)alloc((size_t)NPAD * 256 * 2);
    float* Wc1p  = (float*)alloc((size_t)65536 * 4);
    float* Wa1pf = (float*)alloc((size_t)65536 * 4);
    float* Wc1ff = (float*)alloc((size_t)65536 * 4);
    float* Wa1ff = (float*)alloc((size_t)65536 * 4);
    __hip_bfloat16* Wa1fb = (__hip_bfloat16*)alloc((size_t)256 * 160 * 2);   // ld 160
    __hip_bfloat16* Xw    = (__hip_bfloat16*)alloc((size_t)1024 * 640 * 2);  // [X1'(224)|X2'(160)|V(256)]
    float* T3f  = (float*)alloc((size_t)1024 * 512 * 4);
    float* Uf   = (float*)alloc((size_t)1024 * 512 * 4);                     // [U1|U2]
    float* B2f  = (float*)alloc((size_t)1024 * 256 * 4);
    float* bc1v = (float*)alloc(256 * 4);
    float* b_a1p = (float*)alloc(256 * 4);
    float* w2   = (float*)alloc(1024 * 4);
    float* cvec = (float*)alloc(1024 * 4);
    unsigned* g_enc = (unsigned*)alloc(1024 * 4);
    float* gvec = (float*)alloc(1024 * 4);
    float* h1   = (float*)alloc(512 * 4);
    float* h2   = (float*)alloc(256 * 4);

    prep<<<516, 256, 0, stream>>>(W_c1, W_a1, Wc1p, Wa1pf, g_enc);
    foldrhs<<<256, 256, 0, stream>>>(Wc1p, Wa1pf, W_sp1, W_fr4, Wc1ff, Wa1ff, Wa1fb);
    vecfolds<<<384, 256, 0, stream>>>(Wc1p, Wa1pf, W_f, b_sp1, b_fr4,
        b_c1, b_a1, b_f, b_a2, bc1v, b_a1p, w2);

    // L1: T3 = M3@Wfa + M2 (K=1024, 8 col-blocks) || B2' = Wfb@W_a2 (K=512, 4)
    wgemm64b<<<dim3(12, 16), 256, 0, stream>>>(
        W_m2 + 768, 1792, W_f, 1024, W_m2 + 256, 1792, 512,
        T3f, (__hip_bfloat16*)nullptr, 512, 1024, 8, 512,
        W_f + 512, 1024, W_a2, 256, (const float*)nullptr, 0, 0,
        B2f, (__hip_bfloat16*)nullptr, 256, 512, 256);
    // L2: U = T3@W_c2 + [M1|0] (K=512, 8) || V = M3@B2' -> Xw cols 384:640 (K=1024, 4)
    wgemm64b<<<dim3(12, 16), 256, 0, stream>>>(
        T3f, 512, W_c2, 512, W_m2, 1792, 256,
        Uf, (__hip_bfloat16*)nullptr, 512, 512, 8, 512,
        W_m2 + 768, 1792, B2f, 256, (const float*)nullptr, 0, 0,
        (float*)nullptr, Xw + 384, 640, 1024, 256);
    cvec_kernel<<<256, 256, 0, stream>>>(W_m2, T3f, Uf, w2, b_c2, bc1v, b_a1p, cvec);
    // L3: X1' = U1@Wc1f -> Xw cols 0:224 (K=256, 4) || X2' = U2@Wa1f -> cols 224:384 (K=256, 3)
    wgemm64b<<<dim3(7, 16), 256, 0, stream>>>(
        Uf, 512, Wc1ff, 256, (const float*)nullptr, 0, 0,
        (float*)nullptr, Xw, 640, 256, 4, 224,
        Uf + 256, 512, Wa1ff, 256, (const float*)nullptr, 0, 0,
        (float*)nullptr, Xw + 224, 640, 256, 160);

    // ---- per-point path ----
    featurize<<<2048, 256, 0, stream>>>(centre, corner, normal, neighbour,
        W_sp2, b_sp2, conv_w, conv_b, W_fr3, b_fr3, theta, phi, cat1);
    gather_agg1<<<NPAD / 4, 256, 0, stream>>>(cat1, neighbour, agg1);
    // out2 = agg1 @ Wa1f^T + b_a1'  (K=160)
    gemm_nt<<<dim3(2, NPAD / 128), 256, 0, stream>>>(agg1, 160, 160, agg1, 160, 160, agg1, 160,
                                                     Wa1fb, 160, b_a1p, out2, 256);
    gather_agg2<<<NPAD / 4, 256, 0, stream>>>(out2, neighbour, agg2);
    // g = max_n([cat1|agg1|agg2] @ Xw^T), K=640, XCD-swizzled grid
    gemm_nt_max<<<3136, 256, 0, stream>>>(cat1, 224, 224, agg1, 160, 384, agg2, 256,
                                          Xw, 640, g_enc);
    // ---- head ----
    head_g<<<4, 256, 0, stream>>>(g_enc, cvec, b_m2, gvec);
    head_lin<<<128, 256, 0, stream>>>(gvec, W_m31, b_m31, h1, 1024, 512, 1);
    head_lin<<<64, 256, 0, stream>>>(h1, W_m32, b_m32, h2, 512, 256, 1);
    head_lin<<<10, 256, 0, stream>>>(h2, W_m33, b_m33, (float*)d_out, 256, 40, 0);
}

// Round 10
// 458.182 us; speedup vs baseline: 1.7694x; 1.1023x over previous
//
#include <hip/hip_runtime.h>
#include <hip/hip_bf16.h>
#include <stdint.h>

#define NPTS 50000
#define NPAD 50048   // 391 * 128 row tiles

typedef unsigned short u16;
typedef __attribute__((ext_vector_type(8))) __bf16 bf16x8;
typedef __attribute__((ext_vector_type(4))) float f32x4;

__device__ __forceinline__ float bf2f(__hip_bfloat16 v) { return __bfloat162float(v); }
__device__ __forceinline__ __hip_bfloat16 f2bf(float v) { return __float2bfloat16(v); }
__device__ __forceinline__ float bfbits2f(unsigned short u) { return __uint_as_float(((unsigned)u) << 16); }
__device__ __forceinline__ unsigned short f2bfbits(float f) {
    __hip_bfloat16 h = f2bf(f);
    return *(unsigned short*)&h;
}
__device__ __forceinline__ int clampi(int v) { return v < 0 ? 0 : (v >= NPTS ? NPTS - 1 : v); }

__device__ __forceinline__ unsigned enc_f32(float f) {
    unsigned b = __float_as_uint(f);
    return (b & 0x80000000u) ? ~b : (b | 0x80000000u);
}
__device__ __forceinline__ float dec_f32(unsigned u) {
    return (u & 0x80000000u) ? __uint_as_float(u & 0x7fffffffu) : __uint_as_float(~u);
}

__device__ __forceinline__ void gload_lds16(const void* g, void* l) {
    __builtin_amdgcn_global_load_lds((__attribute__((address_space(1))) void*)g,
                                     (__attribute__((address_space(3))) void*)l, 16, 0, 0);
}

// ---------------------------------------------------------------------------
// wg_body: 64x64-tile fp32 GEMM body. C = A@B (+ D on cols<dcols); stores
// guarded by cidx<ncols.
// ---------------------------------------------------------------------------
__device__ __forceinline__ void wg_body(
    const float* A, int lda, const float* B, int ldb,
    const float* D, int ldd, int dcols,
    float* Cf, __hip_bfloat16* Cb, int ldc, int K, int ncols,
    int bj, int bi, int t, float (*sA)[68], float (*sB)[68])
{
    const int tx = t & 15, ty = t >> 4;
    float acc[4][4] = {};
    for (int k0 = 0; k0 < K; k0 += 16) {
        {
            int k = t & 15, m = t >> 4;
#pragma unroll
            for (int q = 0; q < 4; ++q)
                sA[k][m + q * 16] = A[(long)(bi * 64 + m + q * 16) * lda + k0 + k];
            int n = t & 63, kk = t >> 6;
#pragma unroll
            for (int q = 0; q < 4; ++q)
                sB[kk + q * 4][n] = B[(long)(k0 + kk + q * 4) * ldb + bj * 64 + n];
        }
        __syncthreads();
#pragma unroll
        for (int k = 0; k < 16; ++k) {
            f32x4 av = *(const f32x4*)&sA[k][ty * 4];
            f32x4 bv = *(const f32x4*)&sB[k][tx * 4];
#pragma unroll
            for (int i = 0; i < 4; ++i)
#pragma unroll
                for (int j = 0; j < 4; ++j)
                    acc[i][j] += av[i] * bv[j];
        }
        __syncthreads();
    }
#pragma unroll
    for (int i = 0; i < 4; ++i) {
        int r = bi * 64 + ty * 4 + i;
#pragma unroll
        for (int j = 0; j < 4; ++j) {
            int cidx = bj * 64 + tx * 4 + j;
            if (cidx >= ncols) continue;
            float v = acc[i][j];
            if (D && cidx < dcols) v += D[(long)r * ldd + cidx];
            if (Cf) Cf[(long)r * ldc + cidx] = v;
            if (Cb) Cb[(long)r * ldc + cidx] = f2bf(v);
        }
    }
}

// two independent GEMMs in one launch (block-range dispatch on blockIdx.x)
__global__ __launch_bounds__(256) void wgemm64b(
    const float* A0, int lda0, const float* B0, int ldb0,
    const float* D0, int ldd0, int dcols0,
    float* Cf0, __hip_bfloat16* Cb0, int ldc0, int K0, int nbj0, int ncols0,
    const float* A1, int lda1, const float* B1, int ldb1,
    const float* D1, int ldd1, int dcols1,
    float* Cf1, __hip_bfloat16* Cb1, int ldc1, int K1, int ncols1)
{
    __shared__ float sA[16][68], sB[16][68];
    const int bx = blockIdx.x, bi = blockIdx.y, t = threadIdx.x;
    if (bx < nbj0)
        wg_body(A0, lda0, B0, ldb0, D0, ldd0, dcols0, Cf0, Cb0, ldc0, K0, ncols0, bx, bi, t, sA, sB);
    else
        wg_body(A1, lda1, B1, ldb1, D1, ldd1, dcols1, Cf1, Cb1, ldc1, K1, ncols1, bx - nbj0, bi, t, sA, sB);
}

// ---------------------------------------------------------------------------
// foldcombo: one launch, 644 blocks, reads RAW W_c1 (256x195), W_a1 (256x131)
//   b<256:    foldrhs row r=b -> Wc1ff/Wa1ff (fp32, ld 256), Wa1fb (bf16 ld 160)
//   256..640: vecfolds (o = (b-256)*4+wave): bc1v / b_a1p / w2
//   640..644: g_enc = enc(-inf)
// ---------------------------------------------------------------------------
__global__ __launch_bounds__(256) void foldcombo(
    const float* __restrict__ W_c1, const float* __restrict__ W_a1,
    const float* __restrict__ W_sp1, const float* __restrict__ W_fr4,
    const float* __restrict__ W_f,
    const float* __restrict__ b_sp1, const float* __restrict__ b_fr4,
    const float* __restrict__ b_c1, const float* __restrict__ b_a1,
    const float* __restrict__ b_f, const float* __restrict__ b_a2,
    float* __restrict__ Wc1ff, float* __restrict__ Wa1ff,
    __hip_bfloat16* __restrict__ Wa1fb,
    float* __restrict__ bc1v, float* __restrict__ b_a1p, float* __restrict__ w2,
    unsigned* __restrict__ g_enc)
{
    const int b = blockIdx.x, t = threadIdx.x;
    if (b < 256) {
        const int r = b;
        float vc, va;
        if (t < 64) {
            float s = 0.f;
            for (int k = 0; k < 64; ++k) s += W_c1[r * 195 + k] * W_sp1[k * 64 + t];
            vc = s;
            s = 0.f;
            for (int k = 0; k < 64; ++k) s += W_a1[r * 131 + k] * W_fr4[k * 64 + t];
            va = s;
        } else if (t < 128) {
            float s = 0.f;
            for (int k = 0; k < 64; ++k) s += W_c1[r * 195 + 64 + k] * W_fr4[k * 64 + (t - 64)];
            vc = s;
            va = W_a1[r * 131 + t];   // t in [64,128) < 131: real
        } else {
            vc = (t < 195) ? W_c1[r * 195 + t] : 0.f;
            va = (t < 131) ? W_a1[r * 131 + t] : 0.f;
        }
        Wc1ff[r * 256 + t] = vc;
        Wa1ff[r * 256 + t] = va;
        if (t < 160) Wa1fb[r * 160 + t] = f2bf(va);
    } else if (b < 640) {
        int o = (b - 256) * 4 + (t >> 6);
        int lane = t & 63;
        float a = 0.f;
        if (o < 256) {
            a = W_c1[o * 195 + lane] * b_sp1[lane] + W_c1[o * 195 + 64 + lane] * b_fr4[lane];
        } else if (o < 512) {
            a = W_a1[(o - 256) * 131 + lane] * b_fr4[lane];
        } else {
            for (int k = lane; k < 512; k += 64) a += W_f[(long)(o - 512) * 1024 + 512 + k] * b_a2[k];
        }
#pragma unroll
        for (int off = 32; off > 0; off >>= 1) a += __shfl_xor(a, off);
        if (lane == 0) {
            if (o < 256)      bc1v[o] = b_c1[o] + a;
            else if (o < 512) b_a1p[o - 256] = b_a1[o - 256] + a;
            else              w2[o - 512] = b_f[o - 512] + a;
        }
    } else {
        g_enc[(b - 640) * 256 + t] = 0x007FFFFFu;
    }
}

// ---------------------------------------------------------------------------
// l3_cvec: one launch, grid (23,16):
//   bx<4:  X1' = U1@Wc1ff -> Xw cols 0:224   (K=256)
//   4..7:  X2' = U2@Wa1ff -> Xw cols 224:384 (K=256)
//   7..23: cvec rows i = ((bx-7)*16+bi)*4+wave
// ---------------------------------------------------------------------------
__global__ __launch_bounds__(256) void l3_cvec(
    const float* __restrict__ Uf,
    const float* __restrict__ Wc1ff, const float* __restrict__ Wa1ff,
    __hip_bfloat16* __restrict__ Xw,
    const float* __restrict__ W_m2, const float* __restrict__ T3f,
    const float* __restrict__ w2, const float* __restrict__ b_c2,
    const float* __restrict__ bc1v, const float* __restrict__ b_a1p,
    float* __restrict__ cvec)
{
    __shared__ float sA[16][68], sB[16][68];
    const int bx = blockIdx.x, bi = blockIdx.y, t = threadIdx.x;
    if (bx < 4) {
        wg_body(Uf, 512, Wc1ff, 256, (const float*)nullptr, 0, 0,
                (float*)nullptr, Xw, 640, 256, 224, bx, bi, t, sA, sB);
    } else if (bx < 7) {
        wg_body(Uf + 256, 512, Wa1ff, 256, (const float*)nullptr, 0, 0,
                (float*)nullptr, Xw + 224, 640, 256, 160, bx - 4, bi, t, sA, sB);
    } else {
        int i = ((bx - 7) * 16 + bi) * 4 + (t >> 6);
        int lane = t & 63;
        const float* m3row = W_m2 + (long)i * 1792 + 768;
        float a = 0.f;
        for (int k = lane; k < 1024; k += 64) a += w2[k] * m3row[k];
        for (int k = lane; k < 512;  k += 64) a += b_c2[k] * T3f[(long)i * 512 + k];
        for (int k = lane; k < 256;  k += 64) a += bc1v[k] * Uf[(long)i * 512 + k];
        for (int k = lane; k < 256;  k += 64) a += b_a1p[k] * Uf[(long)i * 512 + 256 + k];
#pragma unroll
        for (int off = 32; off > 0; off >>= 1) a += __shfl_xor(a, off);
        if (lane == 0) cvec[i] = a;
    }
}

// ---------------------------------------------------------------------------
// featurize: cat1 row (ld 224) = [h1r(64) | h3r(64) | kc(64) | nrm(3)+pad(29)]
// ---------------------------------------------------------------------------
__global__ __launch_bounds__(256) void featurize(
    const float* __restrict__ centre, const float* __restrict__ corner,
    const float* __restrict__ normal, const int* __restrict__ neighbour,
    const float* __restrict__ W_sp2, const float* __restrict__ b_sp2,
    const float* __restrict__ conv_w, const float* __restrict__ conv_b,
    const float* __restrict__ W_fr3, const float* __restrict__ b_fr3,
    const float* __restrict__ theta, const float* __restrict__ phi,
    __hip_bfloat16* __restrict__ cat1)
{
    __shared__ float sWsp2t[3][64];  __shared__ float sbsp2[64];
    __shared__ float sconvt[6][32];  __shared__ float sconvb[32];
    __shared__ float sWfr3t[32][64]; __shared__ float sbfr3[64];
    __shared__ float kt4x[4][64], kt4y[4][64], kt4z[4][64];

    const int tid = threadIdx.x;
    for (int i = tid; i < 2048; i += 256) { int j = i >> 5, k = i & 31; sWfr3t[k][j] = W_fr3[i]; }
    for (int i = tid; i < 192; i += 256) { int j = i / 3, k = i % 3; sWsp2t[k][j] = W_sp2[i]; }
    for (int i = tid; i < 192; i += 256) { int o = i / 6, k = i % 6; sconvt[k][o] = conv_w[i]; }
    if (tid < 64) { sbsp2[tid] = b_sp2[tid]; sbfr3[tid] = b_fr3[tid]; }
    if (tid < 32) sconvb[tid] = conv_b[tid];
    {
        int j = tid >> 2, s = tid & 3;
        float th = theta[tid], ph = phi[tid];
        float st = sinf(th), ct = cosf(th), sp = sinf(ph), cp = cosf(ph);
        kt4x[s][j] = st * sp; kt4y[s][j] = st * cp; kt4z[s][j] = ct;
    }
    __syncthreads();

    const int lane = tid & 63, wave = tid >> 6;
    for (long p = (long)blockIdx.x * 4 + wave; p < NPAD; p += (long)gridDim.x * 4) {
        __hip_bfloat16* row = cat1 + p * 224;
        if (p >= NPTS) {
            __hip_bfloat16 z = f2bf(0.f);
            row[lane] = z; row[64 + lane] = z; row[128 + lane] = z;
            if (lane < 32) row[192 + lane] = z;
            continue;
        }
        float cx = centre[p * 3], cy = centre[p * 3 + 1], cz = centre[p * 3 + 2];
        float h1r = fmaxf(sbsp2[lane] + cx * sWsp2t[0][lane] + cy * sWsp2t[1][lane]
                          + cz * sWsp2t[2][lane], 0.f);
        float mval = 0.f;
        if (lane < 32) {
            float c0 = corner[p*9+0], c1 = corner[p*9+1], c2 = corner[p*9+2];
            float c3 = corner[p*9+3], c4 = corner[p*9+4], c5 = corner[p*9+5];
            float c6 = corner[p*9+6], c7 = corner[p*9+7], c8 = corner[p*9+8];
            float s0 = c0 + c3 + c6, s1 = c1 + c4 + c7, s2 = c2 + c5 + c8;
            mval = sconvb[lane] + (1.f / 3.f) *
                ((sconvt[0][lane] + sconvt[3][lane]) * s0 +
                 (sconvt[1][lane] + sconvt[4][lane]) * s1 +
                 (sconvt[2][lane] + sconvt[5][lane]) * s2);
        }
        float h3 = sbfr3[lane];
#pragma unroll 8
        for (int k = 0; k < 32; ++k) h3 += __shfl(mval, k) * sWfr3t[k][lane];
        float h3r = fmaxf(h3, 0.f);
        int nb0 = clampi(neighbour[p * 3]), nb1 = clampi(neighbour[p * 3 + 1]), nb2 = clampi(neighbour[p * 3 + 2]);
        float nx[4], ny[4], nz[4];
        nx[0] = normal[p * 3];          ny[0] = normal[p * 3 + 1];          nz[0] = normal[p * 3 + 2];
        nx[1] = normal[(long)nb0 * 3];  ny[1] = normal[(long)nb0 * 3 + 1];  nz[1] = normal[(long)nb0 * 3 + 2];
        nx[2] = normal[(long)nb1 * 3];  ny[2] = normal[(long)nb1 * 3 + 1];  nz[2] = normal[(long)nb1 * 3 + 2];
        nx[3] = normal[(long)nb2 * 3];  ny[3] = normal[(long)nb2 * 3 + 1];  nz[3] = normal[(long)nb2 * 3 + 2];
        float kcs = 0.f;
#pragma unroll
        for (int s = 0; s < 4; ++s) {
            float kx = kt4x[s][lane], ky = kt4y[s][lane], kz = kt4z[s][lane];
#pragma unroll
            for (int t = 0; t < 4; ++t) {
                float dx = nx[t] - kx, dy = ny[t] - ky, dz = nz[t] - kz;
                kcs += __expf(-12.5f * (dx * dx + dy * dy + dz * dz));
            }
        }
        float kcv = kcs * (1.f / 16.f);
        row[lane] = f2bf(h1r); row[64 + lane] = f2bf(h3r); row[128 + lane] = f2bf(kcv);
        if (lane < 32) {
            float nrmv = (lane == 0) ? nx[0] : (lane == 1) ? ny[0] : (lane == 2) ? nz[0] : 0.f;
            row[192 + lane] = f2bf(nrmv);
        }
    }
}

// ---------------------------------------------------------------------------
// gathers (ushort4-vectorized, one wave per point)
// ---------------------------------------------------------------------------
__global__ __launch_bounds__(256) void gather_agg1(
    const __hip_bfloat16* __restrict__ cat1, const int* __restrict__ neighbour,
    __hip_bfloat16* __restrict__ agg1)
{
    long p = (long)blockIdx.x * 4 + (threadIdx.x >> 6);
    int lane = threadIdx.x & 63;
    if (p >= NPAD || lane >= 40) return;
    ushort4* o = (ushort4*)(agg1 + p * 160);
    if (p >= NPTS) { o[lane] = make_ushort4(0, 0, 0, 0); return; }
    int nb0 = clampi(neighbour[p * 3]), nb1 = clampi(neighbour[p * 3 + 1]), nb2 = clampi(neighbour[p * 3 + 2]);
    ushort4 a = ((const ushort4*)(cat1 + p * 224 + 64))[lane];
    ushort4 b = ((const ushort4*)(cat1 + (long)nb0 * 224 + 64))[lane];
    ushort4 c = ((const ushort4*)(cat1 + (long)nb1 * 224 + 64))[lane];
    ushort4 d = ((const ushort4*)(cat1 + (long)nb2 * 224 + 64))[lane];
    ushort4 r;
    r.x = f2bfbits((bfbits2f(a.x) + bfbits2f(b.x) + bfbits2f(c.x) + bfbits2f(d.x)) * 0.25f);
    r.y = f2bfbits((bfbits2f(a.y) + bfbits2f(b.y) + bfbits2f(c.y) + bfbits2f(d.y)) * 0.25f);
    r.z = f2bfbits((bfbits2f(a.z) + bfbits2f(b.z) + bfbits2f(c.z) + bfbits2f(d.z)) * 0.25f);
    r.w = f2bfbits((bfbits2f(a.w) + bfbits2f(b.w) + bfbits2f(c.w) + bfbits2f(d.w)) * 0.25f);
    o[lane] = r;
}

__global__ __launch_bounds__(256) void gather_agg2(
    const __hip_bfloat16* __restrict__ out2, const int* __restrict__ neighbour,
    __hip_bfloat16* __restrict__ agg2)
{
    long p = (long)blockIdx.x * 4 + (threadIdx.x >> 6);
    int lane = threadIdx.x & 63;
    if (p >= NPAD) return;
    ushort4* o = (ushort4*)(agg2 + p * 256);
    if (p >= NPTS) { o[lane] = make_ushort4(0, 0, 0, 0); return; }
    int nb0 = clampi(neighbour[p * 3]), nb1 = clampi(neighbour[p * 3 + 1]), nb2 = clampi(neighbour[p * 3 + 2]);
    ushort4 a = ((const ushort4*)(out2 + p * 256))[lane];
    ushort4 b = ((const ushort4*)(out2 + (long)nb0 * 256))[lane];
    ushort4 c = ((const ushort4*)(out2 + (long)nb1 * 256))[lane];
    ushort4 d = ((const ushort4*)(out2 + (long)nb2 * 256))[lane];
    ushort4 r;
    r.x = f2bfbits((bfbits2f(a.x) + bfbits2f(b.x) + bfbits2f(c.x) + bfbits2f(d.x)) * 0.25f);
    r.y = f2bfbits((bfbits2f(a.y) + bfbits2f(b.y) + bfbits2f(c.y) + bfbits2f(d.y)) * 0.25f);
    r.z = f2bfbits((bfbits2f(a.z) + bfbits2f(b.z) + bfbits2f(c.z) + bfbits2f(d.z)) * 0.25f);
    r.w = f2bfbits((bfbits2f(a.w) + bfbits2f(b.w) + bfbits2f(c.w) + bfbits2f(d.w)) * 0.25f);
    o[lane] = r;
}

// ---------------------------------------------------------------------------
// 128x128 bf16 MFMA GEMM core, BK=64. TAIL is compile-time: TAIL=false
// (K multiple of 64) generates the clean branch-free R7 codegen.
// ---------------------------------------------------------------------------
template <bool TAIL>
__device__ __forceinline__ void gemm_core(
    const __hip_bfloat16* A0, int lda0, int k0end,
    const __hip_bfloat16* A1, int lda1, int k1end,
    const __hip_bfloat16* A2, int lda2,
    const __hip_bfloat16* B, int K,
    u16* Asm, u16* Bsm,   // each 2*128*32
    long rowbase, int colbase, int tid,
    f32x4 acc[4][4])
{
    const int lane = tid & 63, wave = tid >> 6;
    const int wr = wave >> 1, wc = wave & 1;
    const int m16 = lane & 15, kg = lane >> 4;
    for (int kt = 0; kt < K; kt += 64) {
        const bool has2 = TAIL ? (kt + 32 < K) : true;
#pragma unroll
        for (int h = 0; h < 2; ++h) {
            if (TAIL && h == 1 && !has2) break;
            int kh = kt + h * 32;
            const __hip_bfloat16* Ap; long lda; int kl;
            if (kh < k0end)      { Ap = A0; lda = lda0; kl = kh; }
            else if (kh < k1end) { Ap = A1; lda = lda1; kl = kh - k0end; }
            else                 { Ap = A2; lda = lda2; kl = kh - k1end; }
#pragma unroll
            for (int i = 0; i < 2; ++i) {
                int cid = i * 256 + tid;
                int row = cid >> 2, kc = cid & 3;
                gload_lds16(Ap + (rowbase + row) * lda + kl + kc * 8, Asm + h * 4096 + cid * 8);
                gload_lds16(B + (long)(colbase + row) * K + kh + kc * 8, Bsm + h * 4096 + cid * 8);
            }
        }
        __syncthreads();
#pragma unroll
        for (int h = 0; h < 2; ++h) {
            if (TAIL && h == 1 && !has2) break;
            bf16x8 af[4], bv[4];
#pragma unroll
            for (int i = 0; i < 4; ++i)
                af[i] = *(const bf16x8*)(Asm + h * 4096 + ((wr * 64 + i * 16 + m16) * 32 + kg * 8));
#pragma unroll
            for (int j = 0; j < 4; ++j)
                bv[j] = *(const bf16x8*)(Bsm + h * 4096 + ((wc * 64 + j * 16 + m16) * 32 + kg * 8));
#pragma unroll
            for (int i = 0; i < 4; ++i)
#pragma unroll
                for (int j = 0; j < 4; ++j)
                    acc[i][j] = __builtin_amdgcn_mfma_f32_16x16x32_bf16(af[i], bv[j], acc[i][j], 0, 0, 0);
        }
        __syncthreads();
    }
}

__global__ __launch_bounds__(256) void gemm_nt(
    const __hip_bfloat16* __restrict__ A0, int lda0, int k0end,
    const __hip_bfloat16* __restrict__ A1, int lda1, int k1end,
    const __hip_bfloat16* __restrict__ A2, int lda2,
    const __hip_bfloat16* __restrict__ B, int K,
    const float* __restrict__ bias,
    __hip_bfloat16* __restrict__ C, int ldc)
{
    __shared__ __align__(16) u16 Asm[2 * 128 * 32];
    __shared__ __align__(16) u16 Bsm[2 * 128 * 32];
    const int tid = threadIdx.x;
    const long rowbase = (long)blockIdx.y * 128;
    const int colbase = blockIdx.x * 128;
    f32x4 acc[4][4] = {};
    gemm_core<true>(A0, lda0, k0end, A1, lda1, k1end, A2, lda2, B, K, Asm, Bsm, rowbase, colbase, tid, acc);
    const int lane = tid & 63, wave = tid >> 6;
    const int wr = wave >> 1, wc = wave & 1;
    const int m16 = lane & 15, q = lane >> 4;
#pragma unroll
    for (int j = 0; j < 4; ++j) {
        int col = colbase + wc * 64 + j * 16 + m16;
        float bvv = bias[col];
#pragma unroll
        for (int i = 0; i < 4; ++i)
#pragma unroll
            for (int r = 0; r < 4; ++r) {
                long rowg = rowbase + wr * 64 + i * 16 + q * 4 + r;
                C[rowg * ldc + col] = f2bf(acc[i][j][r] + bvv);
            }
    }
}

// max-GEMM, XCD-swizzled 1D grid (keeps A row-tile in one XCD's L2). K%64==0.
__global__ __launch_bounds__(256) void gemm_nt_max(
    const __hip_bfloat16* __restrict__ A0, int lda0, int k0end,
    const __hip_bfloat16* __restrict__ A1, int lda1, int k1end,
    const __hip_bfloat16* __restrict__ A2, int lda2,
    const __hip_bfloat16* __restrict__ B, int K,
    unsigned* __restrict__ g_enc)
{
    __shared__ __align__(16) u16 Asm[2 * 128 * 32];
    __shared__ __align__(16) u16 Bsm[2 * 128 * 32];
    __shared__ float red[2][128];
    const int id = blockIdx.x;
    const int c = id & 7, tt = id >> 3;
    const int j8 = tt & 7, rh = tt >> 3;
    const int r = rh * 8 + c;
    if (r >= NPAD / 128) return;
    const long rowbase = (long)r * 128;
    const int colbase = j8 * 128;
    const int tid = threadIdx.x;
    f32x4 acc[4][4] = {};
    gemm_core<false>(A0, lda0, k0end, A1, lda1, k1end, A2, lda2, B, K, Asm, Bsm, rowbase, colbase, tid, acc);
    const int lane = tid & 63, wave = tid >> 6;
    const int wr = wave >> 1, wc = wave & 1;
    const int m16 = lane & 15, q = lane >> 4;
#pragma unroll
    for (int j = 0; j < 4; ++j) {
        float m = -INFINITY;
#pragma unroll
        for (int i = 0; i < 4; ++i)
#pragma unroll
            for (int rr = 0; rr < 4; ++rr) {
                long rowg = rowbase + wr * 64 + i * 16 + q * 4 + rr;
                m = (rowg < NPTS) ? fmaxf(m, acc[i][j][rr]) : m;
            }
        m = fmaxf(m, __shfl_xor(m, 16));
        m = fmaxf(m, __shfl_xor(m, 32));
        if (lane < 16) red[wr][wc * 64 + j * 16 + m16] = m;
    }
    __syncthreads();
    if (tid < 128) {
        float v = fmaxf(red[0][tid], red[1][tid]);
        atomicMax(g_enc + colbase + tid, enc_f32(v));
    }
}

// ---------------------------------------------------------------------------
// head: layer 1 reads g on the fly from g_enc+cvec+b_m2; layers 2/3 generic
// ---------------------------------------------------------------------------
__global__ __launch_bounds__(256) void head_lin_g(
    const unsigned* __restrict__ g_enc, const float* __restrict__ cvec,
    const float* __restrict__ b_m2,
    const float* __restrict__ W, const float* __restrict__ b,
    float* __restrict__ out)
{
    int o = blockIdx.x * 4 + (threadIdx.x >> 6);
    int lane = threadIdx.x & 63;
    if (o >= 512) return;
    float a = 0.f;
    for (int k = lane; k < 1024; k += 64) {
        float g = dec_f32(g_enc[k]) + cvec[k] + b_m2[k];
        a += g * W[(long)o * 1024 + k];
    }
#pragma unroll
    for (int off = 32; off > 0; off >>= 1) a += __shfl_xor(a, off);
    if (lane == 0) out[o] = fmaxf(a + b[o], 0.f);
}

__global__ __launch_bounds__(256) void head_lin(
    const float* __restrict__ in, const float* __restrict__ W,
    const float* __restrict__ b, float* __restrict__ out,
    int In, int Out, int do_relu)
{
    int o = blockIdx.x * 4 + (threadIdx.x >> 6);
    int lane = threadIdx.x & 63;
    if (o >= Out) return;
    float a = 0.f;
    for (int k = lane; k < In; k += 64) a += in[k] * W[(long)o * In + k];
#pragma unroll
    for (int off = 32; off > 0; off >>= 1) a += __shfl_xor(a, off);
    if (lane == 0) {
        float v = a + b[o];
        out[o] = do_relu ? fmaxf(v, 0.f) : v;
    }
}

// ---------------------------------------------------------------------------
extern "C" void kernel_launch(void* const* d_in, const int* in_sizes, int n_in,
                              void* d_out, int out_size, void* d_ws, size_t ws_size,
                              hipStream_t stream)
{
    (void)in_sizes; (void)n_in; (void)out_size; (void)ws_size;
    const float* centre = (const float*)d_in[0];
    const float* corner = (const float*)d_in[1];
    const float* normal = (const float*)d_in[2];
    const int*   neighbour = (const int*)d_in[3];
    const float* W_sp2 = (const float*)d_in[4];
    const float* b_sp2 = (const float*)d_in[5];
    const float* W_sp1 = (const float*)d_in[6];
    const float* b_sp1 = (const float*)d_in[7];
    const float* conv_w = (const float*)d_in[8];
    const float* conv_b = (const float*)d_in[9];
    const float* W_fr3 = (const float*)d_in[10];
    const float* b_fr3 = (const float*)d_in[11];
    const float* W_fr4 = (const float*)d_in[12];
    const float* b_fr4 = (const float*)d_in[13];
    const float* theta = (const float*)d_in[14];
    const float* phi   = (const float*)d_in[15];
    const float* W_c1 = (const float*)d_in[16];
    const float* b_c1 = (const float*)d_in[17];
    const float* W_a1 = (const float*)d_in[18];
    const float* b_a1 = (const float*)d_in[19];
    const float* W_c2 = (const float*)d_in[20];
    const float* b_c2 = (const float*)d_in[21];
    const float* W_a2 = (const float*)d_in[22];
    const float* b_a2 = (const float*)d_in[23];
    const float* W_f  = (const float*)d_in[24];
    const float* b_f  = (const float*)d_in[25];
    const float* W_m2 = (const float*)d_in[26];
    const float* b_m2 = (const float*)d_in[27];
    const float* W_m31 = (const float*)d_in[28];
    const float* b_m31 = (const float*)d_in[29];
    const float* W_m32 = (const float*)d_in[30];
    const float* b_m32 = (const float*)d_in[31];
    const float* W_m33 = (const float*)d_in[32];
    const float* b_m33 = (const float*)d_in[33];

    char* ws = (char*)d_ws;
    size_t off = 0;
    auto alloc = [&](size_t bytes) { void* p = ws + off; off += (bytes + 255) & ~(size_t)255; return p; };
    __hip_bfloat16* cat1  = (__hip_bfloat16*)alloc((size_t)NPAD * 224 * 2);  // [h1r|h3r|kc|nrm+pad]
    __hip_bfloat16* agg1  = (__hip_bfloat16*)alloc((size_t)NPAD * 160 * 2);  // avg [h3r|kc|nrm+pad]
    __hip_bfloat16* out2  = (__hip_bfloat16*)alloc((size_t)NPAD * 256 * 2);
    __hip_bfloat16* agg2  = (__hip_bfloat16*)alloc((size_t)NPAD * 256 * 2);
    float* Wc1ff = (float*)alloc((size_t)65536 * 4);
    float* Wa1ff = (float*)alloc((size_t)65536 * 4);
    __hip_bfloat16* Wa1fb = (__hip_bfloat16*)alloc((size_t)256 * 160 * 2);   // ld 160
    __hip_bfloat16* Xw    = (__hip_bfloat16*)alloc((size_t)1024 * 640 * 2);  // [X1'(224)|X2'(160)|V(256)]
    float* T3f  = (float*)alloc((size_t)1024 * 512 * 4);
    float* Uf   = (float*)alloc((size_t)1024 * 512 * 4);                     // [U1|U2]
    float* B2f  = (float*)alloc((size_t)1024 * 256 * 4);
    float* bc1v = (float*)alloc(256 * 4);
    float* b_a1p = (float*)alloc(256 * 4);
    float* w2   = (float*)alloc(1024 * 4);
    float* cvec = (float*)alloc(1024 * 4);
    unsigned* g_enc = (unsigned*)alloc(1024 * 4);
    float* h1   = (float*)alloc(512 * 4);
    float* h2   = (float*)alloc(256 * 4);

    // 1) all fold work + g_enc init, one launch (reads raw W_c1/W_a1)
    foldcombo<<<644, 256, 0, stream>>>(W_c1, W_a1, W_sp1, W_fr4, W_f,
        b_sp1, b_fr4, b_c1, b_a1, b_f, b_a2,
        Wc1ff, Wa1ff, Wa1fb, bc1v, b_a1p, w2, g_enc);
    // 2) L1: T3 = M3@Wfa + M2 (K=1024, 8 col-blocks) || B2' = Wfb@W_a2 (K=512, 4)
    wgemm64b<<<dim3(12, 16), 256, 0, stream>>>(
        W_m2 + 768, 1792, W_f, 1024, W_m2 + 256, 1792, 512,
        T3f, (__hip_bfloat16*)nullptr, 512, 1024, 8, 512,
        W_f + 512, 1024, W_a2, 256, (const float*)nullptr, 0, 0,
        B2f, (__hip_bfloat16*)nullptr, 256, 512, 256);
    // 3) L2: U = T3@W_c2 + [M1|0] (K=512, 8) || V = M3@B2' -> Xw cols 384:640 (K=1024, 4)
    wgemm64b<<<dim3(12, 16), 256, 0, stream>>>(
        T3f, 512, W_c2, 512, W_m2, 1792, 256,
        Uf, (__hip_bfloat16*)nullptr, 512, 512, 8, 512,
        W_m2 + 768, 1792, B2f, 256, (const float*)nullptr, 0, 0,
        (float*)nullptr, Xw + 384, 640, 1024, 256);
    // 4) L3 (X1', X2') + cvec in one launch
    l3_cvec<<<dim3(23, 16), 256, 0, stream>>>(Uf, Wc1ff, Wa1ff, Xw,
        W_m2, T3f, w2, b_c2, bc1v, b_a1p, cvec);

    // ---- per-point path ----
    featurize<<<2048, 256, 0, stream>>>(centre, corner, normal, neighbour,
        W_sp2, b_sp2, conv_w, conv_b, W_fr3, b_fr3, theta, phi, cat1);
    gather_agg1<<<NPAD / 4, 256, 0, stream>>>(cat1, neighbour, agg1);
    // out2 = agg1 @ Wa1f^T + b_a1'  (K=160, TAIL)
    gemm_nt<<<dim3(2, NPAD / 128), 256, 0, stream>>>(agg1, 160, 160, agg1, 160, 160, agg1, 160,
                                                     Wa1fb, 160, b_a1p, out2, 256);
    gather_agg2<<<NPAD / 4, 256, 0, stream>>>(out2, neighbour, agg2);
    // g = max_n([cat1|agg1|agg2] @ Xw^T), K=640 (no tail), XCD-swizzled grid
    gemm_nt_max<<<3136, 256, 0, stream>>>(cat1, 224, 224, agg1, 160, 384, agg2, 256,
                                          Xw, 640, g_enc);
    // ---- head ----
    head_lin_g<<<128, 256, 0, stream>>>(g_enc, cvec, b_m2, W_m31, b_m31, h1);
    head_lin<<<64, 256, 0, stream>>>(h1, W_m32, b_m32, h2, 512, 256, 1);
    head_lin<<<10, 256, 0, stream>>>(h2, W_m33, b_m33, (float*)d_out, 256, 40, 0);
}

// Round 11
// 389.444 us; speedup vs baseline: 2.0817x; 1.1765x over previous
//
#include <hip/hip_runtime.h>
#include <hip/hip_bf16.h>
#include <stdint.h>

#define NPTS 50000
#define NPAD 50048   // 391 * 128 row tiles

typedef unsigned short u16;
typedef __attribute__((ext_vector_type(8))) __bf16 bf16x8;
typedef __attribute__((ext_vector_type(4))) float f32x4;

__device__ __forceinline__ float bf2f(__hip_bfloat16 v) { return __bfloat162float(v); }
__device__ __forceinline__ __hip_bfloat16 f2bf(float v) { return __float2bfloat16(v); }
__device__ __forceinline__ float bfbits2f(unsigned short u) { return __uint_as_float(((unsigned)u) << 16); }
__device__ __forceinline__ unsigned short f2bfbits(float f) {
    __hip_bfloat16 h = f2bf(f);
    return *(unsigned short*)&h;
}
__device__ __forceinline__ int clampi(int v) { return v < 0 ? 0 : (v >= NPTS ? NPTS - 1 : v); }

__device__ __forceinline__ unsigned enc_f32(float f) {
    unsigned b = __float_as_uint(f);
    return (b & 0x80000000u) ? ~b : (b | 0x80000000u);
}
__device__ __forceinline__ float dec_f32(unsigned u) {
    return (u & 0x80000000u) ? __uint_as_float(u & 0x7fffffffu) : __uint_as_float(~u);
}

__device__ __forceinline__ void gload_lds16(const void* g, void* l) {
    __builtin_amdgcn_global_load_lds((__attribute__((address_space(1))) void*)g,
                                     (__attribute__((address_space(3))) void*)l, 16, 0, 0);
}

// ---------------------------------------------------------------------------
// wg_body: 64x64-tile fp32 GEMM body. C = A@B (+ D on cols<dcols); stores
// guarded by cidx<ncols; zf=1 writes bf16 zero into cols >= ncols.
// ---------------------------------------------------------------------------
__device__ __forceinline__ void wg_body(
    const float* A, int lda, const float* B, int ldb,
    const float* D, int ldd, int dcols,
    float* Cf, __hip_bfloat16* Cb, int ldc, int K, int ncols, int zf,
    int bj, int bi, int t, float (*sA)[68], float (*sB)[68])
{
    const int tx = t & 15, ty = t >> 4;
    float acc[4][4] = {};
    for (int k0 = 0; k0 < K; k0 += 16) {
        {
            int k = t & 15, m = t >> 4;
#pragma unroll
            for (int q = 0; q < 4; ++q)
                sA[k][m + q * 16] = A[(long)(bi * 64 + m + q * 16) * lda + k0 + k];
            int n = t & 63, kk = t >> 6;
#pragma unroll
            for (int q = 0; q < 4; ++q)
                sB[kk + q * 4][n] = B[(long)(k0 + kk + q * 4) * ldb + bj * 64 + n];
        }
        __syncthreads();
#pragma unroll
        for (int k = 0; k < 16; ++k) {
            f32x4 av = *(const f32x4*)&sA[k][ty * 4];
            f32x4 bv = *(const f32x4*)&sB[k][tx * 4];
#pragma unroll
            for (int i = 0; i < 4; ++i)
#pragma unroll
                for (int j = 0; j < 4; ++j)
                    acc[i][j] += av[i] * bv[j];
        }
        __syncthreads();
    }
#pragma unroll
    for (int i = 0; i < 4; ++i) {
        int r = bi * 64 + ty * 4 + i;
#pragma unroll
        for (int j = 0; j < 4; ++j) {
            int cidx = bj * 64 + tx * 4 + j;
            if (cidx >= ncols) {
                if (zf && Cb) Cb[(long)r * ldc + cidx] = f2bf(0.f);
                continue;
            }
            float v = acc[i][j];
            if (D && cidx < dcols) v += D[(long)r * ldd + cidx];
            if (Cf) Cf[(long)r * ldc + cidx] = v;
            if (Cb) Cb[(long)r * ldc + cidx] = f2bf(v);
        }
    }
}

// ---------------------------------------------------------------------------
// gather bodies (one wave per point, ushort4)
// ---------------------------------------------------------------------------
__device__ __forceinline__ void gather1_body(
    const __hip_bfloat16* cat1, const int* neighbour, __hip_bfloat16* agg1,
    long p, int lane)
{
    if (p >= NPAD || lane >= 40) return;
    ushort4* o = (ushort4*)(agg1 + p * 160);
    if (p >= NPTS) { o[lane] = make_ushort4(0, 0, 0, 0); return; }
    int nb0 = clampi(neighbour[p * 3]), nb1 = clampi(neighbour[p * 3 + 1]), nb2 = clampi(neighbour[p * 3 + 2]);
    ushort4 a = ((const ushort4*)(cat1 + p * 224 + 64))[lane];
    ushort4 b = ((const ushort4*)(cat1 + (long)nb0 * 224 + 64))[lane];
    ushort4 c = ((const ushort4*)(cat1 + (long)nb1 * 224 + 64))[lane];
    ushort4 d = ((const ushort4*)(cat1 + (long)nb2 * 224 + 64))[lane];
    ushort4 r;
    r.x = f2bfbits((bfbits2f(a.x) + bfbits2f(b.x) + bfbits2f(c.x) + bfbits2f(d.x)) * 0.25f);
    r.y = f2bfbits((bfbits2f(a.y) + bfbits2f(b.y) + bfbits2f(c.y) + bfbits2f(d.y)) * 0.25f);
    r.z = f2bfbits((bfbits2f(a.z) + bfbits2f(b.z) + bfbits2f(c.z) + bfbits2f(d.z)) * 0.25f);
    r.w = f2bfbits((bfbits2f(a.w) + bfbits2f(b.w) + bfbits2f(c.w) + bfbits2f(d.w)) * 0.25f);
    o[lane] = r;
}

// agg1t (ld 192): 2-hop avg of agg1 (ld 160); lanes 40..47 zero the pad cols
__device__ __forceinline__ void gather1t_body(
    const __hip_bfloat16* agg1, const int* neighbour, __hip_bfloat16* agg1t,
    long p, int lane)
{
    if (p >= NPAD || lane >= 48) return;
    ushort4* o = (ushort4*)(agg1t + p * 192);
    if (lane >= 40 || p >= NPTS) { o[lane] = make_ushort4(0, 0, 0, 0); return; }
    int nb0 = clampi(neighbour[p * 3]), nb1 = clampi(neighbour[p * 3 + 1]), nb2 = clampi(neighbour[p * 3 + 2]);
    ushort4 a = ((const ushort4*)(agg1 + p * 160))[lane];
    ushort4 b = ((const ushort4*)(agg1 + (long)nb0 * 160))[lane];
    ushort4 c = ((const ushort4*)(agg1 + (long)nb1 * 160))[lane];
    ushort4 d = ((const ushort4*)(agg1 + (long)nb2 * 160))[lane];
    ushort4 r;
    r.x = f2bfbits((bfbits2f(a.x) + bfbits2f(b.x) + bfbits2f(c.x) + bfbits2f(d.x)) * 0.25f);
    r.y = f2bfbits((bfbits2f(a.y) + bfbits2f(b.y) + bfbits2f(c.y) + bfbits2f(d.y)) * 0.25f);
    r.z = f2bfbits((bfbits2f(a.z) + bfbits2f(b.z) + bfbits2f(c.z) + bfbits2f(d.z)) * 0.25f);
    r.w = f2bfbits((bfbits2f(a.w) + bfbits2f(b.w) + bfbits2f(c.w) + bfbits2f(d.w)) * 0.25f);
    o[lane] = r;
}

// ---------------------------------------------------------------------------
// featurize body: cat1 row (ld 224) = [h1r(64)|h3r(64)|kc(64)|nrm(3)+pad]
// ---------------------------------------------------------------------------
__device__ void featurize_body(
    const float* centre, const float* corner, const float* normal,
    const int* neighbour,
    const float* W_sp2, const float* b_sp2, const float* conv_w, const float* conv_b,
    const float* W_fr3, const float* b_fr3, const float* theta, const float* phi,
    __hip_bfloat16* cat1, int bid, int nblocks)
{
    __shared__ float sWsp2t[3][64];  __shared__ float sbsp2[64];
    __shared__ float sconvt[6][32];  __shared__ float sconvb[32];
    __shared__ float sWfr3t[32][64]; __shared__ float sbfr3[64];
    __shared__ float kt4x[4][64], kt4y[4][64], kt4z[4][64];

    const int tid = threadIdx.x;
    for (int i = tid; i < 2048; i += 256) { int j = i >> 5, k = i & 31; sWfr3t[k][j] = W_fr3[i]; }
    for (int i = tid; i < 192; i += 256) { int j = i / 3, k = i % 3; sWsp2t[k][j] = W_sp2[i]; }
    for (int i = tid; i < 192; i += 256) { int o = i / 6, k = i % 6; sconvt[k][o] = conv_w[i]; }
    if (tid < 64) { sbsp2[tid] = b_sp2[tid]; sbfr3[tid] = b_fr3[tid]; }
    if (tid < 32) sconvb[tid] = conv_b[tid];
    {
        int j = tid >> 2, s = tid & 3;
        float th = theta[tid], ph = phi[tid];
        float st = sinf(th), ct = cosf(th), sp = sinf(ph), cp = cosf(ph);
        kt4x[s][j] = st * sp; kt4y[s][j] = st * cp; kt4z[s][j] = ct;
    }
    __syncthreads();

    const int lane = tid & 63, wave = tid >> 6;
    for (long p = (long)bid * 4 + wave; p < NPAD; p += (long)nblocks * 4) {
        __hip_bfloat16* row = cat1 + p * 224;
        if (p >= NPTS) {
            __hip_bfloat16 z = f2bf(0.f);
            row[lane] = z; row[64 + lane] = z; row[128 + lane] = z;
            if (lane < 32) row[192 + lane] = z;
            continue;
        }
        float cx = centre[p * 3], cy = centre[p * 3 + 1], cz = centre[p * 3 + 2];
        float h1r = fmaxf(sbsp2[lane] + cx * sWsp2t[0][lane] + cy * sWsp2t[1][lane]
                          + cz * sWsp2t[2][lane], 0.f);
        float mval = 0.f;
        if (lane < 32) {
            float c0 = corner[p*9+0], c1 = corner[p*9+1], c2 = corner[p*9+2];
            float c3 = corner[p*9+3], c4 = corner[p*9+4], c5 = corner[p*9+5];
            float c6 = corner[p*9+6], c7 = corner[p*9+7], c8 = corner[p*9+8];
            float s0 = c0 + c3 + c6, s1 = c1 + c4 + c7, s2 = c2 + c5 + c8;
            mval = sconvb[lane] + (1.f / 3.f) *
                ((sconvt[0][lane] + sconvt[3][lane]) * s0 +
                 (sconvt[1][lane] + sconvt[4][lane]) * s1 +
                 (sconvt[2][lane] + sconvt[5][lane]) * s2);
        }
        float h3 = sbfr3[lane];
#pragma unroll 8
        for (int k = 0; k < 32; ++k) h3 += __shfl(mval, k) * sWfr3t[k][lane];
        float h3r = fmaxf(h3, 0.f);
        int nb0 = clampi(neighbour[p * 3]), nb1 = clampi(neighbour[p * 3 + 1]), nb2 = clampi(neighbour[p * 3 + 2]);
        float nx[4], ny[4], nz[4];
        nx[0] = normal[p * 3];          ny[0] = normal[p * 3 + 1];          nz[0] = normal[p * 3 + 2];
        nx[1] = normal[(long)nb0 * 3];  ny[1] = normal[(long)nb0 * 3 + 1];  nz[1] = normal[(long)nb0 * 3 + 2];
        nx[2] = normal[(long)nb1 * 3];  ny[2] = normal[(long)nb1 * 3 + 1];  nz[2] = normal[(long)nb1 * 3 + 2];
        nx[3] = normal[(long)nb2 * 3];  ny[3] = normal[(long)nb2 * 3 + 1];  nz[3] = normal[(long)nb2 * 3 + 2];
        float kcs = 0.f;
#pragma unroll
        for (int s = 0; s < 4; ++s) {
            float kx = kt4x[s][lane], ky = kt4y[s][lane], kz = kt4z[s][lane];
#pragma unroll
            for (int t = 0; t < 4; ++t) {
                float dx = nx[t] - kx, dy = ny[t] - ky, dz = nz[t] - kz;
                kcs += __expf(-12.5f * (dx * dx + dy * dy + dz * dz));
            }
        }
        float kcv = kcs * (1.f / 16.f);
        row[lane] = f2bf(h1r); row[64 + lane] = f2bf(h3r); row[128 + lane] = f2bf(kcv);
        if (lane < 32) {
            float nrmv = (lane == 0) ? nx[0] : (lane == 1) ? ny[0] : (lane == 2) ? nz[0] : 0.f;
            row[192 + lane] = f2bf(nrmv);
        }
    }
}

// ---------------------------------------------------------------------------
// combo1: b<644 fold work + g_enc init || b>=644 featurize (2048 blocks)
// ---------------------------------------------------------------------------
__global__ __launch_bounds__(256) void combo1(
    const float* __restrict__ W_c1, const float* __restrict__ W_a1,
    const float* __restrict__ W_sp1, const float* __restrict__ W_fr4,
    const float* __restrict__ W_f,
    const float* __restrict__ b_sp1, const float* __restrict__ b_fr4,
    const float* __restrict__ b_c1, const float* __restrict__ b_a1,
    const float* __restrict__ b_f, const float* __restrict__ b_a2,
    float* __restrict__ Wc1ff, float* __restrict__ Wa1ff,
    float* __restrict__ bc1v, float* __restrict__ b_a1p, float* __restrict__ w2,
    unsigned* __restrict__ g_enc,
    const float* __restrict__ centre, const float* __restrict__ corner,
    const float* __restrict__ normal, const int* __restrict__ neighbour,
    const float* __restrict__ W_sp2, const float* __restrict__ b_sp2,
    const float* __restrict__ conv_w, const float* __restrict__ conv_b,
    const float* __restrict__ W_fr3, const float* __restrict__ b_fr3,
    const float* __restrict__ theta, const float* __restrict__ phi,
    __hip_bfloat16* __restrict__ cat1)
{
    const int b = blockIdx.x, t = threadIdx.x;
    if (b >= 644) {
        featurize_body(centre, corner, normal, neighbour, W_sp2, b_sp2,
                       conv_w, conv_b, W_fr3, b_fr3, theta, phi, cat1, b - 644, 2048);
        return;
    }
    if (b < 256) {
        const int r = b;
        float vc, va;
        if (t < 64) {
            float s = 0.f;
            for (int k = 0; k < 64; ++k) s += W_c1[r * 195 + k] * W_sp1[k * 64 + t];
            vc = s;
            s = 0.f;
            for (int k = 0; k < 64; ++k) s += W_a1[r * 131 + k] * W_fr4[k * 64 + t];
            va = s;
        } else if (t < 128) {
            float s = 0.f;
            for (int k = 0; k < 64; ++k) s += W_c1[r * 195 + 64 + k] * W_fr4[k * 64 + (t - 64)];
            vc = s;
            va = W_a1[r * 131 + t];
        } else {
            vc = (t < 195) ? W_c1[r * 195 + t] : 0.f;
            va = (t < 131) ? W_a1[r * 131 + t] : 0.f;
        }
        Wc1ff[r * 256 + t] = vc;
        Wa1ff[r * 256 + t] = va;
    } else if (b < 640) {
        int o = (b - 256) * 4 + (t >> 6);
        int lane = t & 63;
        float a = 0.f;
        if (o < 256) {
            a = W_c1[o * 195 + lane] * b_sp1[lane] + W_c1[o * 195 + 64 + lane] * b_fr4[lane];
        } else if (o < 512) {
            a = W_a1[(o - 256) * 131 + lane] * b_fr4[lane];
        } else {
            for (int k = lane; k < 512; k += 64) a += W_f[(long)(o - 512) * 1024 + 512 + k] * b_a2[k];
        }
#pragma unroll
        for (int off = 32; off > 0; off >>= 1) a += __shfl_xor(a, off);
        if (lane == 0) {
            if (o < 256)      bc1v[o] = b_c1[o] + a;
            else if (o < 512) b_a1p[o - 256] = b_a1[o - 256] + a;
            else              w2[o - 512] = b_f[o - 512] + a;
        }
    } else {
        g_enc[(b - 640) * 256 + t] = 0x007FFFFFu;
    }
}

// ---------------------------------------------------------------------------
// combo2: id<192 -> L1 (T3 = M3@Wfa + M2 (8 colblk) || B2f = Wfb@W_a2 (4))
//         else   -> gather_agg1 (cat1 -> agg1)
// ---------------------------------------------------------------------------
__global__ __launch_bounds__(256) void combo2(
    const float* __restrict__ W_m2, const float* __restrict__ W_f,
    const float* __restrict__ W_a2,
    float* __restrict__ T3f, float* __restrict__ B2f,
    const __hip_bfloat16* __restrict__ cat1, const int* __restrict__ neighbour,
    __hip_bfloat16* __restrict__ agg1)
{
    const int id = blockIdx.x, t = threadIdx.x;
    if (id < 192) {
        __shared__ float sA[16][68], sB[16][68];
        int bj = id % 12, bi = id / 12;
        if (bj < 8)
            wg_body(W_m2 + 768, 1792, W_f, 1024, W_m2 + 256, 1792, 512,
                    T3f, (__hip_bfloat16*)nullptr, 512, 1024, 512, 0, bj, bi, t, sA, sB);
        else
            wg_body(W_f + 512, 1024, W_a2, 256, (const float*)nullptr, 0, 0,
                    B2f, (__hip_bfloat16*)nullptr, 256, 512, 256, 0, bj - 8, bi, t, sA, sB);
    } else {
        long p = (long)(id - 192) * 4 + (t >> 6);
        gather1_body(cat1, neighbour, agg1, p, t & 63);
    }
}

// ---------------------------------------------------------------------------
// combo3: id<192 -> L2 (U = T3@W_c2 + [M1|0] (8 colblk) || Vf = M3@B2f (4))
//         else   -> gather_agg1t (agg1 -> agg1t, ld 192)
// ---------------------------------------------------------------------------
__global__ __launch_bounds__(256) void combo3(
    const float* __restrict__ T3f, const float* __restrict__ W_c2,
    const float* __restrict__ W_m2, const float* __restrict__ B2f,
    float* __restrict__ Uf, float* __restrict__ Vf,
    const __hip_bfloat16* __restrict__ agg1, const int* __restrict__ neighbour,
    __hip_bfloat16* __restrict__ agg1t)
{
    const int id = blockIdx.x, t = threadIdx.x;
    if (id < 192) {
        __shared__ float sA[16][68], sB[16][68];
        int bj = id % 12, bi = id / 12;
        if (bj < 8)
            wg_body(T3f, 512, W_c2, 512, W_m2, 1792, 256,
                    Uf, (__hip_bfloat16*)nullptr, 512, 512, 512, 0, bj, bi, t, sA, sB);
        else
            wg_body(W_m2 + 768, 1792, B2f, 256, (const float*)nullptr, 0, 0,
                    Vf, (__hip_bfloat16*)nullptr, 256, 1024, 256, 0, bj - 8, bi, t, sA, sB);
    } else {
        long p = (long)(id - 192) * 4 + (t >> 6);
        gather1t_body(agg1, neighbour, agg1t, p, t & 63);
    }
}

// ---------------------------------------------------------------------------
// l3_cvec: grid (26,16):
//   bx<4:    X1' = U1@Wc1ff -> Xw cols 0:224   (K=256)
//   [4,7):   X2' = U2@Wa1ff -> Xw cols 224:384 (K=256)
//   [7,10):  V'  = Vf@Wa1ff -> Xw cols 384:576 (K=256, ncols 160, zero-fill pad)
//   [10,26): cvec rows
// ---------------------------------------------------------------------------
__global__ __launch_bounds__(256) void l3_cvec(
    const float* __restrict__ Uf, const float* __restrict__ Vf,
    const float* __restrict__ Wc1ff, const float* __restrict__ Wa1ff,
    __hip_bfloat16* __restrict__ Xw,
    const float* __restrict__ W_m2, const float* __restrict__ T3f,
    const float* __restrict__ w2, const float* __restrict__ b_c2,
    const float* __restrict__ bc1v, const float* __restrict__ b_a1p,
    float* __restrict__ cvec)
{
    __shared__ float sA[16][68], sB[16][68];
    const int bx = blockIdx.x, bi = blockIdx.y, t = threadIdx.x;
    if (bx < 4) {
        wg_body(Uf, 512, Wc1ff, 256, (const float*)nullptr, 0, 0,
                (float*)nullptr, Xw, 576, 256, 224, 0, bx, bi, t, sA, sB);
    } else if (bx < 7) {
        wg_body(Uf + 256, 512, Wa1ff, 256, (const float*)nullptr, 0, 0,
                (float*)nullptr, Xw + 224, 576, 256, 160, 0, bx - 4, bi, t, sA, sB);
    } else if (bx < 10) {
        wg_body(Vf, 256, Wa1ff, 256, (const float*)nullptr, 0, 0,
                (float*)nullptr, Xw + 384, 576, 256, 160, 1, bx - 7, bi, t, sA, sB);
    } else {
        int i = ((bx - 10) * 16 + bi) * 4 + (t >> 6);
        int lane = t & 63;
        const float* m3row = W_m2 + (long)i * 1792 + 768;
        float a = 0.f;
        for (int k = lane; k < 1024; k += 64) a += w2[k] * m3row[k];
        for (int k = lane; k < 512;  k += 64) a += b_c2[k] * T3f[(long)i * 512 + k];
        for (int k = lane; k < 256;  k += 64) a += bc1v[k] * Uf[(long)i * 512 + k];
        for (int k = lane; k < 256;  k += 64) a += b_a1p[k] * Uf[(long)i * 512 + 256 + k];
        for (int k = lane; k < 256;  k += 64) a += b_a1p[k] * Vf[(long)i * 256 + k];
#pragma unroll
        for (int off = 32; off > 0; off >>= 1) a += __shfl_xor(a, off);
        if (lane == 0) cvec[i] = a;
    }
}

// ---------------------------------------------------------------------------
// 128x128 bf16 MFMA GEMM core, BK=64, K multiple of 64 (branch-free).
// ---------------------------------------------------------------------------
__device__ __forceinline__ void gemm_core(
    const __hip_bfloat16* A0, int lda0, int k0end,
    const __hip_bfloat16* A1, int lda1, int k1end,
    const __hip_bfloat16* A2, int lda2,
    const __hip_bfloat16* B, int K,
    u16* Asm, u16* Bsm,   // each 2*128*32
    long rowbase, int colbase, int tid,
    f32x4 acc[4][4])
{
    const int lane = tid & 63, wave = tid >> 6;
    const int wr = wave >> 1, wc = wave & 1;
    const int m16 = lane & 15, kg = lane >> 4;
    for (int kt = 0; kt < K; kt += 64) {
#pragma unroll
        for (int h = 0; h < 2; ++h) {
            int kh = kt + h * 32;
            const __hip_bfloat16* Ap; long lda; int kl;
            if (kh < k0end)      { Ap = A0; lda = lda0; kl = kh; }
            else if (kh < k1end) { Ap = A1; lda = lda1; kl = kh - k0end; }
            else                 { Ap = A2; lda = lda2; kl = kh - k1end; }
#pragma unroll
            for (int i = 0; i < 2; ++i) {
                int cid = i * 256 + tid;
                int row = cid >> 2, kc = cid & 3;
                gload_lds16(Ap + (rowbase + row) * lda + kl + kc * 8, Asm + h * 4096 + cid * 8);
                gload_lds16(B + (long)(colbase + row) * K + kh + kc * 8, Bsm + h * 4096 + cid * 8);
            }
        }
        __syncthreads();
#pragma unroll
        for (int h = 0; h < 2; ++h) {
            bf16x8 af[4], bv[4];
#pragma unroll
            for (int i = 0; i < 4; ++i)
                af[i] = *(const bf16x8*)(Asm + h * 4096 + ((wr * 64 + i * 16 + m16) * 32 + kg * 8));
#pragma unroll
            for (int j = 0; j < 4; ++j)
                bv[j] = *(const bf16x8*)(Bsm + h * 4096 + ((wc * 64 + j * 16 + m16) * 32 + kg * 8));
#pragma unroll
            for (int i = 0; i < 4; ++i)
#pragma unroll
                for (int j = 0; j < 4; ++j)
                    acc[i][j] = __builtin_amdgcn_mfma_f32_16x16x32_bf16(af[i], bv[j], acc[i][j], 0, 0, 0);
        }
        __syncthreads();
    }
}

// max-GEMM, XCD-swizzled 1D grid (keeps A row-tile in one XCD's L2). K%64==0.
__global__ __launch_bounds__(256) void gemm_nt_max(
    const __hip_bfloat16* __restrict__ A0, int lda0, int k0end,
    const __hip_bfloat16* __restrict__ A1, int lda1, int k1end,
    const __hip_bfloat16* __restrict__ A2, int lda2,
    const __hip_bfloat16* __restrict__ B, int K,
    unsigned* __restrict__ g_enc)
{
    __shared__ __align__(16) u16 Asm[2 * 128 * 32];
    __shared__ __align__(16) u16 Bsm[2 * 128 * 32];
    __shared__ float red[2][128];
    const int id = blockIdx.x;
    const int c = id & 7, tt = id >> 3;
    const int j8 = tt & 7, rh = tt >> 3;
    const int r = rh * 8 + c;
    if (r >= NPAD / 128) return;
    const long rowbase = (long)r * 128;
    const int colbase = j8 * 128;
    const int tid = threadIdx.x;
    f32x4 acc[4][4] = {};
    gemm_core(A0, lda0, k0end, A1, lda1, k1end, A2, lda2, B, K, Asm, Bsm, rowbase, colbase, tid, acc);
    const int lane = tid & 63, wave = tid >> 6;
    const int wr = wave >> 1, wc = wave & 1;
    const int m16 = lane & 15, q = lane >> 4;
#pragma unroll
    for (int j = 0; j < 4; ++j) {
        float m = -INFINITY;
#pragma unroll
        for (int i = 0; i < 4; ++i)
#pragma unroll
            for (int rr = 0; rr < 4; ++rr) {
                long rowg = rowbase + wr * 64 + i * 16 + q * 4 + rr;
                m = (rowg < NPTS) ? fmaxf(m, acc[i][j][rr]) : m;
            }
        m = fmaxf(m, __shfl_xor(m, 16));
        m = fmaxf(m, __shfl_xor(m, 32));
        if (lane < 16) red[wr][wc * 64 + j * 16 + m16] = m;
    }
    __syncthreads();
    if (tid < 128) {
        float v = fmaxf(red[0][tid], red[1][tid]);
        atomicMax(g_enc + colbase + tid, enc_f32(v));
    }
}

// ---------------------------------------------------------------------------
// head
// ---------------------------------------------------------------------------
__global__ __launch_bounds__(256) void head_lin_g(
    const unsigned* __restrict__ g_enc, const float* __restrict__ cvec,
    const float* __restrict__ b_m2,
    const float* __restrict__ W, const float* __restrict__ b,
    float* __restrict__ out)
{
    int o = blockIdx.x * 4 + (threadIdx.x >> 6);
    int lane = threadIdx.x & 63;
    if (o >= 512) return;
    float a = 0.f;
    for (int k = lane; k < 1024; k += 64) {
        float g = dec_f32(g_enc[k]) + cvec[k] + b_m2[k];
        a += g * W[(long)o * 1024 + k];
    }
#pragma unroll
    for (int off = 32; off > 0; off >>= 1) a += __shfl_xor(a, off);
    if (lane == 0) out[o] = fmaxf(a + b[o], 0.f);
}

__global__ __launch_bounds__(256) void head_lin(
    const float* __restrict__ in, const float* __restrict__ W,
    const float* __restrict__ b, float* __restrict__ out,
    int In, int Out, int do_relu)
{
    int o = blockIdx.x * 4 + (threadIdx.x >> 6);
    int lane = threadIdx.x & 63;
    if (o >= Out) return;
    float a = 0.f;
    for (int k = lane; k < In; k += 64) a += in[k] * W[(long)o * In + k];
#pragma unroll
    for (int off = 32; off > 0; off >>= 1) a += __shfl_xor(a, off);
    if (lane == 0) {
        float v = a + b[o];
        out[o] = do_relu ? fmaxf(v, 0.f) : v;
    }
}

// ---------------------------------------------------------------------------
extern "C" void kernel_launch(void* const* d_in, const int* in_sizes, int n_in,
                              void* d_out, int out_size, void* d_ws, size_t ws_size,
                              hipStream_t stream)
{
    (void)in_sizes; (void)n_in; (void)out_size; (void)ws_size;
    const float* centre = (const float*)d_in[0];
    const float* corner = (const float*)d_in[1];
    const float* normal = (const float*)d_in[2];
    const int*   neighbour = (const int*)d_in[3];
    const float* W_sp2 = (const float*)d_in[4];
    const float* b_sp2 = (const float*)d_in[5];
    const float* W_sp1 = (const float*)d_in[6];
    const float* b_sp1 = (const float*)d_in[7];
    const float* conv_w = (const float*)d_in[8];
    const float* conv_b = (const float*)d_in[9];
    const float* W_fr3 = (const float*)d_in[10];
    const float* b_fr3 = (const float*)d_in[11];
    const float* W_fr4 = (const float*)d_in[12];
    const float* b_fr4 = (const float*)d_in[13];
    const float* theta = (const float*)d_in[14];
    const float* phi   = (const float*)d_in[15];
    const float* W_c1 = (const float*)d_in[16];
    const float* b_c1 = (const float*)d_in[17];
    const float* W_a1 = (const float*)d_in[18];
    const float* b_a1 = (const float*)d_in[19];
    const float* W_c2 = (const float*)d_in[20];
    const float* b_c2 = (const float*)d_in[21];
    const float* W_a2 = (const float*)d_in[22];
    const float* b_a2 = (const float*)d_in[23];
    const float* W_f  = (const float*)d_in[24];
    const float* b_f  = (const float*)d_in[25];
    const float* W_m2 = (const float*)d_in[26];
    const float* b_m2 = (const float*)d_in[27];
    const float* W_m31 = (const float*)d_in[28];
    const float* b_m31 = (const float*)d_in[29];
    const float* W_m32 = (const float*)d_in[30];
    const float* b_m32 = (const float*)d_in[31];
    const float* W_m33 = (const float*)d_in[32];
    const float* b_m33 = (const float*)d_in[33];

    char* ws = (char*)d_ws;
    size_t off = 0;
    auto alloc = [&](size_t bytes) { void* p = ws + off; off += (bytes + 255) & ~(size_t)255; return p; };
    __hip_bfloat16* cat1  = (__hip_bfloat16*)alloc((size_t)NPAD * 224 * 2);  // [h1r|h3r|kc|nrm+pad]
    __hip_bfloat16* agg1  = (__hip_bfloat16*)alloc((size_t)NPAD * 160 * 2);  // 1-hop avg
    __hip_bfloat16* agg1t = (__hip_bfloat16*)alloc((size_t)NPAD * 192 * 2);  // 2-hop avg + zero pad
    float* Wc1ff = (float*)alloc((size_t)65536 * 4);
    float* Wa1ff = (float*)alloc((size_t)65536 * 4);
    __hip_bfloat16* Xw = (__hip_bfloat16*)alloc((size_t)1024 * 576 * 2);     // [X1'(224)|X2'(160)|V'(160)|0(32)]
    float* T3f  = (float*)alloc((size_t)1024 * 512 * 4);
    float* Uf   = (float*)alloc((size_t)1024 * 512 * 4);                     // [U1|U2]
    float* B2f  = (float*)alloc((size_t)1024 * 256 * 4);
    float* Vf   = (float*)alloc((size_t)1024 * 256 * 4);
    float* bc1v = (float*)alloc(256 * 4);
    float* b_a1p = (float*)alloc(256 * 4);
    float* w2   = (float*)alloc(1024 * 4);
    float* cvec = (float*)alloc(1024 * 4);
    unsigned* g_enc = (unsigned*)alloc(1024 * 4);
    float* h1   = (float*)alloc(512 * 4);
    float* h2   = (float*)alloc(256 * 4);

    // 1) folds + g_enc init || featurize
    combo1<<<2692, 256, 0, stream>>>(W_c1, W_a1, W_sp1, W_fr4, W_f,
        b_sp1, b_fr4, b_c1, b_a1, b_f, b_a2,
        Wc1ff, Wa1ff, bc1v, b_a1p, w2, g_enc,
        centre, corner, normal, neighbour, W_sp2, b_sp2,
        conv_w, conv_b, W_fr3, b_fr3, theta, phi, cat1);
    // 2) L1 (T3, B2f) || gather1 (cat1 -> agg1)
    combo2<<<192 + NPAD / 4, 256, 0, stream>>>(W_m2, W_f, W_a2, T3f, B2f,
        cat1, neighbour, agg1);
    // 3) L2 (U, Vf) || gather1t (agg1 -> agg1t)
    combo3<<<192 + NPAD / 4, 256, 0, stream>>>(T3f, W_c2, W_m2, B2f, Uf, Vf,
        agg1, neighbour, agg1t);
    // 4) X1'/X2'/V' -> Xw + cvec
    l3_cvec<<<dim3(26, 16), 256, 0, stream>>>(Uf, Vf, Wc1ff, Wa1ff, Xw,
        W_m2, T3f, w2, b_c2, bc1v, b_a1p, cvec);
    // 5) g = max_n([cat1|agg1|agg1t] @ Xw^T), K=576, XCD-swizzled grid
    gemm_nt_max<<<3136, 256, 0, stream>>>(cat1, 224, 224, agg1, 160, 384, agg1t, 192,
                                          Xw, 576, g_enc);
    // 6-8) head
    head_lin_g<<<128, 256, 0, stream>>>(g_enc, cvec, b_m2, W_m31, b_m31, h1);
    head_lin<<<64, 256, 0, stream>>>(h1, W_m32, b_m32, h2, 512, 256, 1);
    head_lin<<<10, 256, 0, stream>>>(h2, W_m33, b_m33, (float*)d_out, 256, 40, 0);
}

// Round 12
// 386.432 us; speedup vs baseline: 2.0979x; 1.0078x over previous
//
#include <hip/hip_runtime.h>
#include <hip/hip_bf16.h>
#include <stdint.h>

#define NPTS 50000
#define NPAD 50048   // 391 * 128 row tiles

typedef unsigned short u16;
typedef __attribute__((ext_vector_type(8))) __bf16 bf16x8;
typedef __attribute__((ext_vector_type(4))) float f32x4;

__device__ __forceinline__ float bf2f(__hip_bfloat16 v) { return __bfloat162float(v); }
__device__ __forceinline__ __hip_bfloat16 f2bf(float v) { return __float2bfloat16(v); }
__device__ __forceinline__ float bfbits2f(unsigned short u) { return __uint_as_float(((unsigned)u) << 16); }
__device__ __forceinline__ unsigned short f2bfbits(float f) {
    __hip_bfloat16 h = f2bf(f);
    return *(unsigned short*)&h;
}
__device__ __forceinline__ int clampi(int v) { return v < 0 ? 0 : (v >= NPTS ? NPTS - 1 : v); }

__device__ __forceinline__ unsigned enc_f32(float f) {
    unsigned b = __float_as_uint(f);
    return (b & 0x80000000u) ? ~b : (b | 0x80000000u);
}
__device__ __forceinline__ float dec_f32(unsigned u) {
    return (u & 0x80000000u) ? __uint_as_float(u & 0x7fffffffu) : __uint_as_float(~u);
}

__device__ __forceinline__ void gload_lds16(const void* g, void* l) {
    __builtin_amdgcn_global_load_lds((__attribute__((address_space(1))) void*)g,
                                     (__attribute__((address_space(3))) void*)l, 16, 0, 0);
}

// ---------------------------------------------------------------------------
// wg_body: 64x64-tile fp32 GEMM body. C = A@B (+ D on cols<dcols); stores
// guarded by cidx<ncols; zf=1 writes bf16 zero into cols >= ncols.
// ---------------------------------------------------------------------------
__device__ __forceinline__ void wg_body(
    const float* A, int lda, const float* B, int ldb,
    const float* D, int ldd, int dcols,
    float* Cf, __hip_bfloat16* Cb, int ldc, int K, int ncols, int zf,
    int bj, int bi, int t, float (*sA)[68], float (*sB)[68])
{
    const int tx = t & 15, ty = t >> 4;
    float acc[4][4] = {};
    for (int k0 = 0; k0 < K; k0 += 16) {
        {
            int k = t & 15, m = t >> 4;
#pragma unroll
            for (int q = 0; q < 4; ++q)
                sA[k][m + q * 16] = A[(long)(bi * 64 + m + q * 16) * lda + k0 + k];
            int n = t & 63, kk = t >> 6;
#pragma unroll
            for (int q = 0; q < 4; ++q)
                sB[kk + q * 4][n] = B[(long)(k0 + kk + q * 4) * ldb + bj * 64 + n];
        }
        __syncthreads();
#pragma unroll
        for (int k = 0; k < 16; ++k) {
            f32x4 av = *(const f32x4*)&sA[k][ty * 4];
            f32x4 bv = *(const f32x4*)&sB[k][tx * 4];
#pragma unroll
            for (int i = 0; i < 4; ++i)
#pragma unroll
                for (int j = 0; j < 4; ++j)
                    acc[i][j] += av[i] * bv[j];
        }
        __syncthreads();
    }
#pragma unroll
    for (int i = 0; i < 4; ++i) {
        int r = bi * 64 + ty * 4 + i;
#pragma unroll
        for (int j = 0; j < 4; ++j) {
            int cidx = bj * 64 + tx * 4 + j;
            if (cidx >= ncols) {
                if (zf && Cb) Cb[(long)r * ldc + cidx] = f2bf(0.f);
                continue;
            }
            float v = acc[i][j];
            if (D && cidx < dcols) v += D[(long)r * ldd + cidx];
            if (Cf) Cf[(long)r * ldc + cidx] = v;
            if (Cb) Cb[(long)r * ldc + cidx] = f2bf(v);
        }
    }
}

// ---------------------------------------------------------------------------
// gather bodies (one wave per point, ushort4)
// ---------------------------------------------------------------------------
__device__ __forceinline__ void gather1_body(
    const __hip_bfloat16* cat1, const int* neighbour, __hip_bfloat16* agg1,
    long p, int lane)
{
    if (p >= NPAD || lane >= 40) return;
    ushort4* o = (ushort4*)(agg1 + p * 160);
    if (p >= NPTS) { o[lane] = make_ushort4(0, 0, 0, 0); return; }
    int nb0 = clampi(neighbour[p * 3]), nb1 = clampi(neighbour[p * 3 + 1]), nb2 = clampi(neighbour[p * 3 + 2]);
    ushort4 a = ((const ushort4*)(cat1 + p * 224 + 64))[lane];
    ushort4 b = ((const ushort4*)(cat1 + (long)nb0 * 224 + 64))[lane];
    ushort4 c = ((const ushort4*)(cat1 + (long)nb1 * 224 + 64))[lane];
    ushort4 d = ((const ushort4*)(cat1 + (long)nb2 * 224 + 64))[lane];
    ushort4 r;
    r.x = f2bfbits((bfbits2f(a.x) + bfbits2f(b.x) + bfbits2f(c.x) + bfbits2f(d.x)) * 0.25f);
    r.y = f2bfbits((bfbits2f(a.y) + bfbits2f(b.y) + bfbits2f(c.y) + bfbits2f(d.y)) * 0.25f);
    r.z = f2bfbits((bfbits2f(a.z) + bfbits2f(b.z) + bfbits2f(c.z) + bfbits2f(d.z)) * 0.25f);
    r.w = f2bfbits((bfbits2f(a.w) + bfbits2f(b.w) + bfbits2f(c.w) + bfbits2f(d.w)) * 0.25f);
    o[lane] = r;
}

// agg1t (ld 192): 2-hop avg of agg1 (ld 160); lanes 40..47 zero the pad cols
__device__ __forceinline__ void gather1t_body(
    const __hip_bfloat16* agg1, const int* neighbour, __hip_bfloat16* agg1t,
    long p, int lane)
{
    if (p >= NPAD || lane >= 48) return;
    ushort4* o = (ushort4*)(agg1t + p * 192);
    if (lane >= 40 || p >= NPTS) { o[lane] = make_ushort4(0, 0, 0, 0); return; }
    int nb0 = clampi(neighbour[p * 3]), nb1 = clampi(neighbour[p * 3 + 1]), nb2 = clampi(neighbour[p * 3 + 2]);
    ushort4 a = ((const ushort4*)(agg1 + p * 160))[lane];
    ushort4 b = ((const ushort4*)(agg1 + (long)nb0 * 160))[lane];
    ushort4 c = ((const ushort4*)(agg1 + (long)nb1 * 160))[lane];
    ushort4 d = ((const ushort4*)(agg1 + (long)nb2 * 160))[lane];
    ushort4 r;
    r.x = f2bfbits((bfbits2f(a.x) + bfbits2f(b.x) + bfbits2f(c.x) + bfbits2f(d.x)) * 0.25f);
    r.y = f2bfbits((bfbits2f(a.y) + bfbits2f(b.y) + bfbits2f(c.y) + bfbits2f(d.y)) * 0.25f);
    r.z = f2bfbits((bfbits2f(a.z) + bfbits2f(b.z) + bfbits2f(c.z) + bfbits2f(d.z)) * 0.25f);
    r.w = f2bfbits((bfbits2f(a.w) + bfbits2f(b.w) + bfbits2f(c.w) + bfbits2f(d.w)) * 0.25f);
    o[lane] = r;
}

// ---------------------------------------------------------------------------
// featurize body: cat1 row (ld 224) = [h1r(64)|h3r(64)|kc(64)|nrm(3)+pad]
// ---------------------------------------------------------------------------
__device__ void featurize_body(
    const float* centre, const float* corner, const float* normal,
    const int* neighbour,
    const float* W_sp2, const float* b_sp2, const float* conv_w, const float* conv_b,
    const float* W_fr3, const float* b_fr3, const float* theta, const float* phi,
    __hip_bfloat16* cat1, int bid, int nblocks)
{
    __shared__ float sWsp2t[3][64];  __shared__ float sbsp2[64];
    __shared__ float sconvt[6][32];  __shared__ float sconvb[32];
    __shared__ float sWfr3t[32][64]; __shared__ float sbfr3[64];
    __shared__ float kt4x[4][64], kt4y[4][64], kt4z[4][64];

    const int tid = threadIdx.x;
    for (int i = tid; i < 2048; i += 256) { int j = i >> 5, k = i & 31; sWfr3t[k][j] = W_fr3[i]; }
    for (int i = tid; i < 192; i += 256) { int j = i / 3, k = i % 3; sWsp2t[k][j] = W_sp2[i]; }
    for (int i = tid; i < 192; i += 256) { int o = i / 6, k = i % 6; sconvt[k][o] = conv_w[i]; }
    if (tid < 64) { sbsp2[tid] = b_sp2[tid]; sbfr3[tid] = b_fr3[tid]; }
    if (tid < 32) sconvb[tid] = conv_b[tid];
    {
        int j = tid >> 2, s = tid & 3;
        float th = theta[tid], ph = phi[tid];
        float st = sinf(th), ct = cosf(th), sp = sinf(ph), cp = cosf(ph);
        kt4x[s][j] = st * sp; kt4y[s][j] = st * cp; kt4z[s][j] = ct;
    }
    __syncthreads();

    const int lane = tid & 63, wave = tid >> 6;
    for (long p = (long)bid * 4 + wave; p < NPAD; p += (long)nblocks * 4) {
        __hip_bfloat16* row = cat1 + p * 224;
        if (p >= NPTS) {
            __hip_bfloat16 z = f2bf(0.f);
            row[lane] = z; row[64 + lane] = z; row[128 + lane] = z;
            if (lane < 32) row[192 + lane] = z;
            continue;
        }
        float cx = centre[p * 3], cy = centre[p * 3 + 1], cz = centre[p * 3 + 2];
        float h1r = fmaxf(sbsp2[lane] + cx * sWsp2t[0][lane] + cy * sWsp2t[1][lane]
                          + cz * sWsp2t[2][lane], 0.f);
        float mval = 0.f;
        if (lane < 32) {
            float c0 = corner[p*9+0], c1 = corner[p*9+1], c2 = corner[p*9+2];
            float c3 = corner[p*9+3], c4 = corner[p*9+4], c5 = corner[p*9+5];
            float c6 = corner[p*9+6], c7 = corner[p*9+7], c8 = corner[p*9+8];
            float s0 = c0 + c3 + c6, s1 = c1 + c4 + c7, s2 = c2 + c5 + c8;
            mval = sconvb[lane] + (1.f / 3.f) *
                ((sconvt[0][lane] + sconvt[3][lane]) * s0 +
                 (sconvt[1][lane] + sconvt[4][lane]) * s1 +
                 (sconvt[2][lane] + sconvt[5][lane]) * s2);
        }
        float h3 = sbfr3[lane];
#pragma unroll 8
        for (int k = 0; k < 32; ++k) h3 += __shfl(mval, k) * sWfr3t[k][lane];
        float h3r = fmaxf(h3, 0.f);
        int nb0 = clampi(neighbour[p * 3]), nb1 = clampi(neighbour[p * 3 + 1]), nb2 = clampi(neighbour[p * 3 + 2]);
        float nx[4], ny[4], nz[4];
        nx[0] = normal[p * 3];          ny[0] = normal[p * 3 + 1];          nz[0] = normal[p * 3 + 2];
        nx[1] = normal[(long)nb0 * 3];  ny[1] = normal[(long)nb0 * 3 + 1];  nz[1] = normal[(long)nb0 * 3 + 2];
        nx[2] = normal[(long)nb1 * 3];  ny[2] = normal[(long)nb1 * 3 + 1];  nz[2] = normal[(long)nb1 * 3 + 2];
        nx[3] = normal[(long)nb2 * 3];  ny[3] = normal[(long)nb2 * 3 + 1];  nz[3] = normal[(long)nb2 * 3 + 2];
        float kcs = 0.f;
#pragma unroll
        for (int s = 0; s < 4; ++s) {
            float kx = kt4x[s][lane], ky = kt4y[s][lane], kz = kt4z[s][lane];
#pragma unroll
            for (int t = 0; t < 4; ++t) {
                float dx = nx[t] - kx, dy = ny[t] - ky, dz = nz[t] - kz;
                kcs += __expf(-12.5f * (dx * dx + dy * dy + dz * dz));
            }
        }
        float kcv = kcs * (1.f / 16.f);
        row[lane] = f2bf(h1r); row[64 + lane] = f2bf(h3r); row[128 + lane] = f2bf(kcv);
        if (lane < 32) {
            float nrmv = (lane == 0) ? nx[0] : (lane == 1) ? ny[0] : (lane == 2) ? nz[0] : 0.f;
            row[192 + lane] = f2bf(nrmv);
        }
    }
}

// ---------------------------------------------------------------------------
// combo1: b<644 fold work + g_enc init || b>=644 featurize (2048 blocks)
// ---------------------------------------------------------------------------
__global__ __launch_bounds__(256) void combo1(
    const float* __restrict__ W_c1, const float* __restrict__ W_a1,
    const float* __restrict__ W_sp1, const float* __restrict__ W_fr4,
    const float* __restrict__ W_f,
    const float* __restrict__ b_sp1, const float* __restrict__ b_fr4,
    const float* __restrict__ b_c1, const float* __restrict__ b_a1,
    const float* __restrict__ b_f, const float* __restrict__ b_a2,
    float* __restrict__ Wc1ff, float* __restrict__ Wa1ff,
    float* __restrict__ bc1v, float* __restrict__ b_a1p, float* __restrict__ w2,
    unsigned* __restrict__ g_enc,
    const float* __restrict__ centre, const float* __restrict__ corner,
    const float* __restrict__ normal, const int* __restrict__ neighbour,
    const float* __restrict__ W_sp2, const float* __restrict__ b_sp2,
    const float* __restrict__ conv_w, const float* __restrict__ conv_b,
    const float* __restrict__ W_fr3, const float* __restrict__ b_fr3,
    const float* __restrict__ theta, const float* __restrict__ phi,
    __hip_bfloat16* __restrict__ cat1)
{
    const int b = blockIdx.x, t = threadIdx.x;
    if (b >= 644) {
        featurize_body(centre, corner, normal, neighbour, W_sp2, b_sp2,
                       conv_w, conv_b, W_fr3, b_fr3, theta, phi, cat1, b - 644, 2048);
        return;
    }
    if (b < 256) {
        const int r = b;
        float vc, va;
        if (t < 64) {
            float s = 0.f;
            for (int k = 0; k < 64; ++k) s += W_c1[r * 195 + k] * W_sp1[k * 64 + t];
            vc = s;
            s = 0.f;
            for (int k = 0; k < 64; ++k) s += W_a1[r * 131 + k] * W_fr4[k * 64 + t];
            va = s;
        } else if (t < 128) {
            float s = 0.f;
            for (int k = 0; k < 64; ++k) s += W_c1[r * 195 + 64 + k] * W_fr4[k * 64 + (t - 64)];
            vc = s;
            va = W_a1[r * 131 + t];
        } else {
            vc = (t < 195) ? W_c1[r * 195 + t] : 0.f;
            va = (t < 131) ? W_a1[r * 131 + t] : 0.f;
        }
        Wc1ff[r * 256 + t] = vc;
        Wa1ff[r * 256 + t] = va;
    } else if (b < 640) {
        int o = (b - 256) * 4 + (t >> 6);
        int lane = t & 63;
        float a = 0.f;
        if (o < 256) {
            a = W_c1[o * 195 + lane] * b_sp1[lane] + W_c1[o * 195 + 64 + lane] * b_fr4[lane];
        } else if (o < 512) {
            a = W_a1[(o - 256) * 131 + lane] * b_fr4[lane];
        } else {
            for (int k = lane; k < 512; k += 64) a += W_f[(long)(o - 512) * 1024 + 512 + k] * b_a2[k];
        }
#pragma unroll
        for (int off = 32; off > 0; off >>= 1) a += __shfl_xor(a, off);
        if (lane == 0) {
            if (o < 256)      bc1v[o] = b_c1[o] + a;
            else if (o < 512) b_a1p[o - 256] = b_a1[o - 256] + a;
            else              w2[o - 512] = b_f[o - 512] + a;
        }
    } else {
        g_enc[(b - 640) * 256 + t] = 0x007FFFFFu;
    }
}

// ---------------------------------------------------------------------------
// combo2: id<192 -> L1 (T3 = M3@Wfa + M2 (8 colblk) || B2f = Wfb@W_a2 (4))
//         else   -> gather_agg1 (cat1 -> agg1)
// ---------------------------------------------------------------------------
__global__ __launch_bounds__(256) void combo2(
    const float* __restrict__ W_m2, const float* __restrict__ W_f,
    const float* __restrict__ W_a2,
    float* __restrict__ T3f, float* __restrict__ B2f,
    const __hip_bfloat16* __restrict__ cat1, const int* __restrict__ neighbour,
    __hip_bfloat16* __restrict__ agg1)
{
    const int id = blockIdx.x, t = threadIdx.x;
    if (id < 192) {
        __shared__ float sA[16][68], sB[16][68];
        int bj = id % 12, bi = id / 12;
        if (bj < 8)
            wg_body(W_m2 + 768, 1792, W_f, 1024, W_m2 + 256, 1792, 512,
                    T3f, (__hip_bfloat16*)nullptr, 512, 1024, 512, 0, bj, bi, t, sA, sB);
        else
            wg_body(W_f + 512, 1024, W_a2, 256, (const float*)nullptr, 0, 0,
                    B2f, (__hip_bfloat16*)nullptr, 256, 512, 256, 0, bj - 8, bi, t, sA, sB);
    } else {
        long p = (long)(id - 192) * 4 + (t >> 6);
        gather1_body(cat1, neighbour, agg1, p, t & 63);
    }
}

// ---------------------------------------------------------------------------
// combo3: id<192 -> L2 (U = T3@W_c2 + [M1|0] (8 colblk) || Vf = M3@B2f (4))
//         else   -> gather_agg1t for points [0, 32768)
// ---------------------------------------------------------------------------
__global__ __launch_bounds__(256) void combo3(
    const float* __restrict__ T3f, const float* __restrict__ W_c2,
    const float* __restrict__ W_m2, const float* __restrict__ B2f,
    float* __restrict__ Uf, float* __restrict__ Vf,
    const __hip_bfloat16* __restrict__ agg1, const int* __restrict__ neighbour,
    __hip_bfloat16* __restrict__ agg1t)
{
    const int id = blockIdx.x, t = threadIdx.x;
    if (id < 192) {
        __shared__ float sA[16][68], sB[16][68];
        int bj = id % 12, bi = id / 12;
        if (bj < 8)
            wg_body(T3f, 512, W_c2, 512, W_m2, 1792, 256,
                    Uf, (__hip_bfloat16*)nullptr, 512, 512, 512, 0, bj, bi, t, sA, sB);
        else
            wg_body(W_m2 + 768, 1792, B2f, 256, (const float*)nullptr, 0, 0,
                    Vf, (__hip_bfloat16*)nullptr, 256, 1024, 256, 0, bj - 8, bi, t, sA, sB);
    } else {
        long p = (long)(id - 192) * 4 + (t >> 6);
        gather1t_body(agg1, neighbour, agg1t, p, t & 63);
    }
}

// ---------------------------------------------------------------------------
// l4: id<416 -> l3 work (X1'/X2'/V' -> Xw, cvec); else gather_agg1t for
// points [32768, NPAD)  (gather part depends only on agg1 from combo2)
// ---------------------------------------------------------------------------
__global__ __launch_bounds__(256) void l4(
    const float* __restrict__ Uf, const float* __restrict__ Vf,
    const float* __restrict__ Wc1ff, const float* __restrict__ Wa1ff,
    __hip_bfloat16* __restrict__ Xw,
    const float* __restrict__ W_m2, const float* __restrict__ T3f,
    const float* __restrict__ w2, const float* __restrict__ b_c2,
    const float* __restrict__ bc1v, const float* __restrict__ b_a1p,
    float* __restrict__ cvec,
    const __hip_bfloat16* __restrict__ agg1, const int* __restrict__ neighbour,
    __hip_bfloat16* __restrict__ agg1t)
{
    const int id = blockIdx.x, t = threadIdx.x;
    if (id >= 416) {
        long p = 32768 + (long)(id - 416) * 4 + (t >> 6);
        gather1t_body(agg1, neighbour, agg1t, p, t & 63);
        return;
    }
    __shared__ float sA[16][68], sB[16][68];
    const int bx = id % 26, bi = id / 26;
    if (bx < 4) {
        wg_body(Uf, 512, Wc1ff, 256, (const float*)nullptr, 0, 0,
                (float*)nullptr, Xw, 576, 256, 224, 0, bx, bi, t, sA, sB);
    } else if (bx < 7) {
        wg_body(Uf + 256, 512, Wa1ff, 256, (const float*)nullptr, 0, 0,
                (float*)nullptr, Xw + 224, 576, 256, 160, 0, bx - 4, bi, t, sA, sB);
    } else if (bx < 10) {
        wg_body(Vf, 256, Wa1ff, 256, (const float*)nullptr, 0, 0,
                (float*)nullptr, Xw + 384, 576, 256, 160, 1, bx - 7, bi, t, sA, sB);
    } else {
        int i = ((bx - 10) * 16 + bi) * 4 + (t >> 6);
        int lane = t & 63;
        const float* m3row = W_m2 + (long)i * 1792 + 768;
        float a = 0.f;
        for (int k = lane; k < 1024; k += 64) a += w2[k] * m3row[k];
        for (int k = lane; k < 512;  k += 64) a += b_c2[k] * T3f[(long)i * 512 + k];
        for (int k = lane; k < 256;  k += 64) a += bc1v[k] * Uf[(long)i * 512 + k];
        for (int k = lane; k < 256;  k += 64) a += b_a1p[k] * Uf[(long)i * 512 + 256 + k];
        for (int k = lane; k < 256;  k += 64) a += b_a1p[k] * Vf[(long)i * 256 + k];
#pragma unroll
        for (int off = 32; off > 0; off >>= 1) a += __shfl_xor(a, off);
        if (lane == 0) cvec[i] = a;
    }
}

// ---------------------------------------------------------------------------
// max-GEMM, fully specialized: A0=cat1(ld224, k<224), A1=agg1(ld160, k<384),
// A2=agg1t(ld192), B=Xw(ld576), K=576. XCD-swizzled 1D grid. All layout
// constants compile-time; K-loop fully unrolled (branch-free codegen).
// ---------------------------------------------------------------------------
__global__ __launch_bounds__(256) void gemm_nt_max576(
    const __hip_bfloat16* __restrict__ A0,
    const __hip_bfloat16* __restrict__ A1,
    const __hip_bfloat16* __restrict__ A2,
    const __hip_bfloat16* __restrict__ B,
    unsigned* __restrict__ g_enc)
{
    __shared__ __align__(16) u16 Asm[2 * 128 * 32];
    __shared__ __align__(16) u16 Bsm[2 * 128 * 32];
    __shared__ float red[2][128];
    const int id = blockIdx.x;
    const int c = id & 7, tt = id >> 3;
    const int j8 = tt & 7, rh = tt >> 3;
    const int r = rh * 8 + c;
    if (r >= NPAD / 128) return;
    const long rowbase = (long)r * 128;
    const int colbase = j8 * 128;
    const int tid = threadIdx.x;
    const int lane = tid & 63, wave = tid >> 6;
    const int wr = wave >> 1, wc = wave & 1;
    const int m16 = lane & 15, kg = lane >> 4;
    const int srow = tid >> 2, skc = tid & 3;          // staging row/chunk
    f32x4 acc[4][4] = {};
#pragma unroll
    for (int kt = 0; kt < 576; kt += 64) {
#pragma unroll
        for (int h = 0; h < 2; ++h) {
            const int kh = kt + h * 32;
#pragma unroll
            for (int i = 0; i < 2; ++i) {
                const int cid = i * 256 + tid;
                const int row = srow + i * 64, kc = skc;
                const __hip_bfloat16* Ap; long lda; int kl;
                if (kh < 224)      { Ap = A0; lda = 224; kl = kh; }
                else if (kh < 384) { Ap = A1; lda = 160; kl = kh - 224; }
                else               { Ap = A2; lda = 192; kl = kh - 384; }
                gload_lds16(Ap + (rowbase + row) * lda + kl + kc * 8, Asm + h * 4096 + cid * 8);
                gload_lds16(B + (long)(colbase + row) * 576 + kh + kc * 8, Bsm + h * 4096 + cid * 8);
            }
        }
        __syncthreads();
#pragma unroll
        for (int h = 0; h < 2; ++h) {
            bf16x8 af[4], bv[4];
#pragma unroll
            for (int i = 0; i < 4; ++i)
                af[i] = *(const bf16x8*)(Asm + h * 4096 + ((wr * 64 + i * 16 + m16) * 32 + kg * 8));
#pragma unroll
            for (int j = 0; j < 4; ++j)
                bv[j] = *(const bf16x8*)(Bsm + h * 4096 + ((wc * 64 + j * 16 + m16) * 32 + kg * 8));
#pragma unroll
            for (int i = 0; i < 4; ++i)
#pragma unroll
                for (int j = 0; j < 4; ++j)
                    acc[i][j] = __builtin_amdgcn_mfma_f32_16x16x32_bf16(af[i], bv[j], acc[i][j], 0, 0, 0);
        }
        __syncthreads();
    }
    const int q = lane >> 4;
#pragma unroll
    for (int j = 0; j < 4; ++j) {
        float m = -INFINITY;
#pragma unroll
        for (int i = 0; i < 4; ++i)
#pragma unroll
            for (int rr = 0; rr < 4; ++rr) {
                long rowg = rowbase + wr * 64 + i * 16 + q * 4 + rr;
                m = (rowg < NPTS) ? fmaxf(m, acc[i][j][rr]) : m;
            }
        m = fmaxf(m, __shfl_xor(m, 16));
        m = fmaxf(m, __shfl_xor(m, 32));
        if (lane < 16) red[wr][wc * 64 + j * 16 + m16] = m;
    }
    __syncthreads();
    if (tid < 128) {
        float v = fmaxf(red[0][tid], red[1][tid]);
        atomicMax(g_enc + colbase + tid, enc_f32(v));
    }
}

// ---------------------------------------------------------------------------
// head
// ---------------------------------------------------------------------------
__global__ __launch_bounds__(256) void head_lin_g(
    const unsigned* __restrict__ g_enc, const float* __restrict__ cvec,
    const float* __restrict__ b_m2,
    const float* __restrict__ W, const float* __restrict__ b,
    float* __restrict__ out)
{
    int o = blockIdx.x * 4 + (threadIdx.x >> 6);
    int lane = threadIdx.x & 63;
    if (o >= 512) return;
    float a = 0.f;
    for (int k = lane; k < 1024; k += 64) {
        float g = dec_f32(g_enc[k]) + cvec[k] + b_m2[k];
        a += g * W[(long)o * 1024 + k];
    }
#pragma unroll
    for (int off = 32; off > 0; off >>= 1) a += __shfl_xor(a, off);
    if (lane == 0) out[o] = fmaxf(a + b[o], 0.f);
}

__global__ __launch_bounds__(256) void head_lin(
    const float* __restrict__ in, const float* __restrict__ W,
    const float* __restrict__ b, float* __restrict__ out,
    int In, int Out, int do_relu)
{
    int o = blockIdx.x * 4 + (threadIdx.x >> 6);
    int lane = threadIdx.x & 63;
    if (o >= Out) return;
    float a = 0.f;
    for (int k = lane; k < In; k += 64) a += in[k] * W[(long)o * In + k];
#pragma unroll
    for (int off = 32; off > 0; off >>= 1) a += __shfl_xor(a, off);
    if (lane == 0) {
        float v = a + b[o];
        out[o] = do_relu ? fmaxf(v, 0.f) : v;
    }
}

// ---------------------------------------------------------------------------
extern "C" void kernel_launch(void* const* d_in, const int* in_sizes, int n_in,
                              void* d_out, int out_size, void* d_ws, size_t ws_size,
                              hipStream_t stream)
{
    (void)in_sizes; (void)n_in; (void)out_size; (void)ws_size;
    const float* centre = (const float*)d_in[0];
    const float* corner = (const float*)d_in[1];
    const float* normal = (const float*)d_in[2];
    const int*   neighbour = (const int*)d_in[3];
    const float* W_sp2 = (const float*)d_in[4];
    const float* b_sp2 = (const float*)d_in[5];
    const float* W_sp1 = (const float*)d_in[6];
    const float* b_sp1 = (const float*)d_in[7];
    const float* conv_w = (const float*)d_in[8];
    const float* conv_b = (const float*)d_in[9];
    const float* W_fr3 = (const float*)d_in[10];
    const float* b_fr3 = (const float*)d_in[11];
    const float* W_fr4 = (const float*)d_in[12];
    const float* b_fr4 = (const float*)d_in[13];
    const float* theta = (const float*)d_in[14];
    const float* phi   = (const float*)d_in[15];
    const float* W_c1 = (const float*)d_in[16];
    const float* b_c1 = (const float*)d_in[17];
    const float* W_a1 = (const float*)d_in[18];
    const float* b_a1 = (const float*)d_in[19];
    const float* W_c2 = (const float*)d_in[20];
    const float* b_c2 = (const float*)d_in[21];
    const float* W_a2 = (const float*)d_in[22];
    const float* b_a2 = (const float*)d_in[23];
    const float* W_f  = (const float*)d_in[24];
    const float* b_f  = (const float*)d_in[25];
    const float* W_m2 = (const float*)d_in[26];
    const float* b_m2 = (const float*)d_in[27];
    const float* W_m31 = (const float*)d_in[28];
    const float* b_m31 = (const float*)d_in[29];
    const float* W_m32 = (const float*)d_in[30];
    const float* b_m32 = (const float*)d_in[31];
    const float* W_m33 = (const float*)d_in[32];
    const float* b_m33 = (const float*)d_in[33];

    char* ws = (char*)d_ws;
    size_t off = 0;
    auto alloc = [&](size_t bytes) { void* p = ws + off; off += (bytes + 255) & ~(size_t)255; return p; };
    __hip_bfloat16* cat1  = (__hip_bfloat16*)alloc((size_t)NPAD * 224 * 2);  // [h1r|h3r|kc|nrm+pad]
    __hip_bfloat16* agg1  = (__hip_bfloat16*)alloc((size_t)NPAD * 160 * 2);  // 1-hop avg
    __hip_bfloat16* agg1t = (__hip_bfloat16*)alloc((size_t)NPAD * 192 * 2);  // 2-hop avg + zero pad
    float* Wc1ff = (float*)alloc((size_t)65536 * 4);
    float* Wa1ff = (float*)alloc((size_t)65536 * 4);
    __hip_bfloat16* Xw = (__hip_bfloat16*)alloc((size_t)1024 * 576 * 2);     // [X1'(224)|X2'(160)|V'(160)|0(32)]
    float* T3f  = (float*)alloc((size_t)1024 * 512 * 4);
    float* Uf   = (float*)alloc((size_t)1024 * 512 * 4);                     // [U1|U2]
    float* B2f  = (float*)alloc((size_t)1024 * 256 * 4);
    float* Vf   = (float*)alloc((size_t)1024 * 256 * 4);
    float* bc1v = (float*)alloc(256 * 4);
    float* b_a1p = (float*)alloc(256 * 4);
    float* w2   = (float*)alloc(1024 * 4);
    float* cvec = (float*)alloc(1024 * 4);
    unsigned* g_enc = (unsigned*)alloc(1024 * 4);
    float* h1   = (float*)alloc(512 * 4);
    float* h2   = (float*)alloc(256 * 4);

    // 1) folds + g_enc init || featurize
    combo1<<<2692, 256, 0, stream>>>(W_c1, W_a1, W_sp1, W_fr4, W_f,
        b_sp1, b_fr4, b_c1, b_a1, b_f, b_a2,
        Wc1ff, Wa1ff, bc1v, b_a1p, w2, g_enc,
        centre, corner, normal, neighbour, W_sp2, b_sp2,
        conv_w, conv_b, W_fr3, b_fr3, theta, phi, cat1);
    // 2) L1 (T3, B2f) || gather1 (cat1 -> agg1)
    combo2<<<192 + NPAD / 4, 256, 0, stream>>>(W_m2, W_f, W_a2, T3f, B2f,
        cat1, neighbour, agg1);
    // 3) L2 (U, Vf) || gather1t points [0, 32768)
    combo3<<<192 + 8192, 256, 0, stream>>>(T3f, W_c2, W_m2, B2f, Uf, Vf,
        agg1, neighbour, agg1t);
    // 4) X1'/X2'/V' -> Xw + cvec || gather1t points [32768, NPAD)
    l4<<<416 + 4320, 256, 0, stream>>>(Uf, Vf, Wc1ff, Wa1ff, Xw,
        W_m2, T3f, w2, b_c2, bc1v, b_a1p, cvec,
        agg1, neighbour, agg1t);
    // 5) g = max_n([cat1|agg1|agg1t] @ Xw^T), K=576, XCD-swizzled grid
    gemm_nt_max576<<<3136, 256, 0, stream>>>(cat1, agg1, agg1t, Xw, g_enc);
    // 6-8) head
    head_lin_g<<<128, 256, 0, stream>>>(g_enc, cvec, b_m2, W_m31, b_m31, h1);
    head_lin<<<64, 256, 0, stream>>>(h1, W_m32, b_m32, h2, 512, 256, 1);
    head_lin<<<10, 256, 0, stream>>>(h2, W_m33, b_m33, (float*)d_out, 256, 40, 0);
}